// Round 10
// baseline (373.831 us; speedup 1.0000x reference)
//
#include <hip/hip_runtime.h>
#include <math.h>

#define BB 4
#define SS 1024
#define DD 1024
#define HH 16
#define HDD 64
#define MTOT (BB*SS)   // 4096
#define QKS 2048       // fused QK buffer row stride
#define MB (1024*1024)

typedef float  f32x4  __attribute__((ext_vector_type(4)));
typedef __bf16 bf16x8 __attribute__((ext_vector_type(8)));
typedef unsigned short u16;
typedef unsigned short u16x8 __attribute__((ext_vector_type(8)));

__device__ __forceinline__ unsigned short f2bf(float f) {
    union { float f; unsigned u; } v; v.f = f;
    unsigned r = v.u + 0x7FFFu + ((v.u >> 16) & 1u);
    return (unsigned short)(r >> 16);
}
__device__ __forceinline__ float bf2f(unsigned short u) {
    union { unsigned u; float f; } v; v.u = ((unsigned)u) << 16;
    return v.f;
}
__device__ __forceinline__ f32x4 mfma16(bf16x8 a, bf16x8 b, f32x4 c) {
    return __builtin_amdgcn_mfma_f32_16x16x32_bf16(a, b, c, 0, 0, 0);
}
__device__ __forceinline__ void gload16(const void* g, void* l) {
    __builtin_amdgcn_global_load_lds(
        (const __attribute__((address_space(1))) void*)g,
        (__attribute__((address_space(3))) void*)l, 16, 0, 0);
}
__device__ __forceinline__ void lds_fence() {
    asm volatile("s_waitcnt lgkmcnt(0)" ::: "memory");
    __builtin_amdgcn_sched_barrier(0);
}

// ---------------- split: fp32 -> bf16 hi/lo ----------------
__global__ void split_kernel(const float* __restrict__ in, u16* __restrict__ hi,
                             u16* __restrict__ lo, int n4)
{
    for (int i = blockIdx.x*blockDim.x + threadIdx.x; i < n4; i += gridDim.x*blockDim.x) {
        f32x4 v = ((const f32x4*)in)[i];
        ushort4 h4, l4;
        h4.x = f2bf(v[0]); l4.x = f2bf(v[0] - bf2f(h4.x));
        h4.y = f2bf(v[1]); l4.y = f2bf(v[1] - bf2f(h4.y));
        h4.z = f2bf(v[2]); l4.z = f2bf(v[2] - bf2f(h4.z));
        h4.w = f2bf(v[3]); l4.w = f2bf(v[3] - bf2f(h4.w));
        ((ushort4*)hi)[i] = h4; ((ushort4*)lo)[i] = l4;
    }
}

// ------- fused transpose+split for all 5 weights: W[k][n] -> WT hi (+opt lo) [n][k] -------
__global__ __launch_bounds__(256)
void tsplit5_kernel(const float* W0, u16* h0,
                    const float* W1, u16* h1,
                    const float* W2, u16* h2,
                    const float* W3, u16* h3,
                    const float* W4, u16* h4, u16* l4T)
{
    const float* W; u16* hT; u16* lT = nullptr;
    switch (blockIdx.z) {
        case 0: W = W0; hT = h0; break;
        case 1: W = W1; hT = h1; break;
        case 2: W = W2; hT = h2; break;
        case 3: W = W3; hT = h3; break;
        default: W = W4; hT = h4; lT = l4T; break;
    }
    __shared__ float tile[64][65];
    const int t  = threadIdx.x;
    const int k0 = blockIdx.y * 64, n0 = blockIdx.x * 64;
    const int r  = t >> 4, c4 = (t & 15) * 4;
    #pragma unroll
    for (int rr = 0; rr < 4; ++rr) {
        const int k = r + rr*16;
        f32x4 v = *(const f32x4*)&W[(size_t)(k0 + k)*1024 + n0 + c4];
        tile[k][c4+0] = v[0]; tile[k][c4+1] = v[1]; tile[k][c4+2] = v[2]; tile[k][c4+3] = v[3];
    }
    __syncthreads();
    #pragma unroll
    for (int rr = 0; rr < 4; ++rr) {
        const int nl = r + rr*16;
        ushort4 hh, ll;
        {
            float v;
            v = tile[c4+0][nl]; hh.x = f2bf(v); ll.x = f2bf(v - bf2f(hh.x));
            v = tile[c4+1][nl]; hh.y = f2bf(v); ll.y = f2bf(v - bf2f(hh.y));
            v = tile[c4+2][nl]; hh.z = f2bf(v); ll.z = f2bf(v - bf2f(hh.z));
            v = tile[c4+3][nl]; hh.w = f2bf(v); ll.w = f2bf(v - bf2f(hh.w));
        }
        *(ushort4*)&hT[(size_t)(n0 + nl)*1024 + k0 + c4] = hh;
        if (lT) *(ushort4*)&lT[(size_t)(n0 + nl)*1024 + k0 + c4] = ll;
    }
}

// ---------------- trust-affinity rank-1 constants ----------------
__global__ void tconst_kernel(const float* __restrict__ Wtp, const float* __restrict__ btp,
                              float* __restrict__ out3)
{
    const int l = threadIdx.x;   // 64 threads
    const float w = Wtp[l], b = btp[l];
    float a = w*w, m = w*b, c = b*b;
    #pragma unroll
    for (int s = 32; s; s >>= 1) {
        a += __shfl_down(a, s);
        m += __shfl_down(m, s);
        c += __shfl_down(c, s);
    }
    if (l == 0) { out3[0] = a; out3[1] = m; out3[2] = c; }
}

// ---------------- trust bias table: T[b][q][k] = bf16(0.1*sigmoid(ta)) ----------------
__global__ __launch_bounds__(256)
void tbias_kernel(const float* __restrict__ trust, const float* __restrict__ tconst,
                  u16* __restrict__ T)
{
    const int b = blockIdx.y;
    const int q = blockIdx.x;
    const float tq = trust[b*SS + q];
    const float c1 = tconst[0], c2 = tconst[1], c3 = tconst[2];
    const int k0 = threadIdx.x * 4;
    f32x4 tk = *(const f32x4*)&trust[b*SS + k0];
    ushort4 o;
    #pragma unroll
    for (int j = 0; j < 4; ++j) {
        const float ta = c1*tq*tk[j] + c2*(tq + tk[j]) + c3;
        const float v  = 0.1f/(1.f + __expf(-ta));
        ((u16*)&o)[j] = f2bf(v);
    }
    *(ushort4*)&T[((size_t)b*SS + q)*SS + k0] = o;
}

// ---------------- split-bf16 MFMA GEMM ----------------
// PASSES=3: AhBh + AhBl + AlBh ; PASSES=2: AhBh + AlBh ; PASSES=1: AhBh
template<int MODE, int PASSES>
__global__ __launch_bounds__(256)
void mgemm(const u16* __restrict__ Ah, const u16* __restrict__ Al,
           const u16* __restrict__ Bh, const u16* __restrict__ Bl,
           const float* __restrict__ bias,
           float* __restrict__ outF, u16* __restrict__ outH, u16* __restrict__ outL,
           int M, int N,
           const float* __restrict__ trust, const float* __restrict__ wlast,
           const u16* __restrict__ attH, const u16* __restrict__ attL)
{
    constexpr int NT   = (PASSES == 3) ? 4 : (PASSES == 2) ? 3 : 2;
    constexpr int BIDX = (PASSES == 1) ? 1 : 2;
    __shared__ u16 lds[2][NT][128*64];

    const int t    = threadIdx.x;
    const int lane = t & 63, wave = t >> 6;
    const int l15  = lane & 15, l4 = lane >> 4;
    const int wr   = wave >> 1, wc = wave & 1;
    const int w64  = wave << 6;
    const int m0   = blockIdx.y * 128, n0 = blockIdx.x * 128;

    const u16* srcs[NT];
    srcs[0] = Ah + (size_t)m0*1024;
    if (PASSES >= 2) srcs[1] = Al + (size_t)m0*1024;
    srcs[BIDX] = Bh + (size_t)n0*1024;
    if (PASSES == 3) srcs[3] = Bl + (size_t)n0*1024;

    f32x4 acc[4][4];
    #pragma unroll
    for (int i = 0; i < 4; ++i)
        #pragma unroll
        for (int j = 0; j < 4; ++j) acc[i][j] = (f32x4){0.f,0.f,0.f,0.f};

#define STAGE(BUF, KOFF) do {                                                  \
    _Pragma("unroll")                                                          \
    for (int tl_ = 0; tl_ < NT; ++tl_) {                                       \
        _Pragma("unroll")                                                      \
        for (int it_ = 0; it_ < 4; ++it_) {                                    \
            const int idx_ = it_*256 + t;                                      \
            const int row_ = idx_ >> 3;                                        \
            const int c_   = (idx_ & 7) ^ (row_ & 7);                          \
            gload16(srcs[tl_] + (KOFF) + (size_t)row_*1024 + c_*8,             \
                    &lds[BUF][tl_][(it_*256 + w64)*8]);                        \
        }                                                                      \
    }                                                                          \
} while(0)

#define COMPUTE(BUF) do {                                                      \
    _Pragma("unroll")                                                          \
    for (int kk_ = 0; kk_ < 2; ++kk_) {                                        \
        const int cb_ = (kk_<<2) + l4;                                         \
        bf16x8 ah_[4], al_[4];                                                 \
        _Pragma("unroll")                                                      \
        for (int i_ = 0; i_ < 4; ++i_) {                                       \
            const int row_ = (wr<<6) + (i_<<4) + l15;                          \
            const int off_ = (row_<<6) + ((cb_ ^ (row_&7)) << 3);              \
            ah_[i_] = *(const bf16x8*)&lds[BUF][0][off_];                      \
            if (PASSES >= 2) al_[i_] = *(const bf16x8*)&lds[BUF][1][off_];     \
        }                                                                      \
        _Pragma("unroll")                                                      \
        for (int j_ = 0; j_ < 4; ++j_) {                                       \
            const int row_ = (wc<<6) + (j_<<4) + l15;                          \
            const int off_ = (row_<<6) + ((cb_ ^ (row_&7)) << 3);              \
            bf16x8 bh_ = *(const bf16x8*)&lds[BUF][BIDX][off_];                \
            bf16x8 bl_;                                                        \
            if (PASSES == 3) bl_ = *(const bf16x8*)&lds[BUF][3][off_];         \
            _Pragma("unroll")                                                  \
            for (int i_ = 0; i_ < 4; ++i_) {                                   \
                acc[i_][j_] = mfma16(ah_[i_], bh_, acc[i_][j_]);               \
                if (PASSES == 3) acc[i_][j_] = mfma16(ah_[i_], bl_, acc[i_][j_]); \
                if (PASSES >= 2) acc[i_][j_] = mfma16(al_[i_], bh_, acc[i_][j_]); \
            }                                                                  \
        }                                                                      \
    }                                                                          \
} while(0)

    STAGE(0, 0);
    __syncthreads();
    int cur = 0;
    for (int s = 0; s < 15; ++s) {
        if (cur == 0) STAGE(1, (s+1)*64);
        else          STAGE(0, (s+1)*64);
        COMPUTE(cur);
        __syncthreads();
        cur ^= 1;
    }
    COMPUTE(cur);
#undef STAGE
#undef COMPUTE

    // ---- epilogue ----
    #pragma unroll
    for (int i = 0; i < 4; ++i)
        #pragma unroll
        for (int j = 0; j < 4; ++j)
            #pragma unroll
            for (int r = 0; r < 4; ++r) {
                const int m = m0 + (wr<<6) + (i<<4) + (l4<<2) + r;
                const int n = n0 + (wc<<6) + (j<<4) + l15;
                const float v = acc[i][j][r];
                if (MODE == 0) {
                    outF[(size_t)m*N + n] = v + bias[n];
                } else if (MODE == 2) {
                    outH[(size_t)m*N + n] = f2bf(v + bias[n]);
                } else if (MODE == 3) {
                    outH[(size_t)m*N + n] = f2bf(v + bias[m]);
                } else {
                    const float pre = v + bias[n] + trust[m]*wlast[n];
                    const float g = 1.f/(1.f + __expf(-pre));
                    const float att = bf2f(attH[(size_t)m*N + n]) + bf2f(attL[(size_t)m*N + n]);
                    const float gated = att*g;
                    const unsigned short hb = f2bf(gated);
                    outH[(size_t)m*N + n] = hb;
                    outL[(size_t)m*N + n] = f2bf(gated - bf2f(hb));
                }
            }
}

// ---------------- Attention v7: barrier-free waves, two-pass exact softmax ----------------
// Each wave independently owns 16 q-rows x ALL 1024 keys for one (b,h).
// Pass 1: online (max,sum) per lane over its 64-key slice, shfl_xor merge over 16 lanes.
// Pass 2: per 64-key chunk, recompute QK^T, normalize, stage fp32 P in a private 4.3KB
// wave-LDS scratch (XOR-swizzled), stream coalesced attn writes, PV-accumulate.
// Zero block barriers; wave-private LDS ordering via s_waitcnt lgkmcnt(0)+sched_barrier.
__global__ __launch_bounds__(256)
void attn_kernel(const u16* __restrict__ QK, const u16* __restrict__ Vt,
                 const u16* __restrict__ T, const int* __restrict__ mask,
                 float* __restrict__ attnOut, u16* __restrict__ attH, u16* __restrict__ attL)
{
    __shared__ float scr_all[4][1088];    // 4 waves x 4352 B private scratch

    const int t    = threadIdx.x;
    const int lane = t & 63, wave = t >> 6;   // 4 waves
    const int l15  = lane & 15, l4 = lane >> 4;
    const int h    = blockIdx.y, b = blockIdx.z;
    const int q0w  = (blockIdx.x*4 + wave)*16;
    float* scw = scr_all[wave];

    int mrow[4];
    #pragma unroll
    for (int r = 0; r < 4; ++r) mrow[r] = mask[b*SS + q0w + l4*4 + r];

    const u16* Qp = QK + ((size_t)(b*SS + q0w + l15))*QKS + h*HDD + l4*8;
    bf16x8 qf0 = *(const bf16x8*)Qp;
    bf16x8 qf1 = *(const bf16x8*)(Qp + 32);

    const u16* Kb = QK + 1024 + ((size_t)(b*SS + l15))*QKS + h*HDD + l4*8;
    const u16* Tb = T + ((size_t)b*SS + q0w + l4*4)*SS + l15;

    // ---- pass 1: online max/sum over all 64 key-tiles ----
    float m[4]  = {-3e38f, -3e38f, -3e38f, -3e38f};
    float lsum[4] = {0.f, 0.f, 0.f, 0.f};
    #pragma unroll 4
    for (int tt = 0; tt < 64; ++tt) {
        const u16* Kp = Kb + (size_t)tt*(16*QKS);
        bf16x8 kf0 = *(const bf16x8*)Kp;
        bf16x8 kf1 = *(const bf16x8*)(Kp + 32);
        f32x4 s4 = mfma16(qf0, kf0, (f32x4){0.f,0.f,0.f,0.f});
        s4 = mfma16(qf1, kf1, s4);
        #pragma unroll
        for (int r = 0; r < 4; ++r) {
            const float bias = bf2f(Tb[(size_t)r*SS + tt*16]);
            float s = s4[r]*0.125f + bias;
            s = mrow[r] ? s : -1e9f;
            const float nm = fmaxf(m[r], s);
            lsum[r] = lsum[r]*__expf(m[r] - nm) + __expf(s - nm);
            m[r] = nm;
        }
    }
    // merge (m,l) across the 16 l15 lanes
    #pragma unroll
    for (int xm = 1; xm < 16; xm <<= 1) {
        #pragma unroll
        for (int r = 0; r < 4; ++r) {
            const float mo = __shfl_xor(m[r], xm);
            const float lo = __shfl_xor(lsum[r], xm);
            const float nm = fmaxf(m[r], mo);
            lsum[r] = lsum[r]*__expf(m[r] - nm) + lo*__expf(mo - nm);
            m[r] = nm;
        }
    }
    float inv[4];
    #pragma unroll
    for (int r = 0; r < 4; ++r) inv[r] = 1.f / lsum[r];

    // ---- pass 2: per 64-key chunk -> normalize, write attn, PV ----
    const u16* Vw = Vt + ((size_t)(h*HDD + l15))*MTOT + b*SS;
    float* gBase = attnOut + (((size_t)(b*HH + h))*SS + q0w)*SS;
    f32x4 pv[4];
    #pragma unroll
    for (int nt = 0; nt < 4; ++nt) pv[nt] = (f32x4){0.f,0.f,0.f,0.f};

    for (int chunk = 0; chunk < 16; ++chunk) {
        // recompute scores for this chunk, normalize, store to wave scratch
        #pragma unroll
        for (int t2 = 0; t2 < 4; ++t2) {
            const int tt = chunk*4 + t2;
            const u16* Kp = Kb + (size_t)tt*(16*QKS);
            bf16x8 kf0 = *(const bf16x8*)Kp;
            bf16x8 kf1 = *(const bf16x8*)(Kp + 32);
            f32x4 s4 = mfma16(qf0, kf0, (f32x4){0.f,0.f,0.f,0.f});
            s4 = mfma16(qf1, kf1, s4);
            const int kk = t2*16 + l15;
            const int c = kk >> 2, jj = kk & 3;
            #pragma unroll
            for (int r = 0; r < 4; ++r) {
                const float bias = bf2f(Tb[(size_t)r*SS + tt*16]);
                float s = s4[r]*0.125f + bias;
                s = mrow[r] ? s : -1e9f;
                const float p = __expf(s - m[r]) * inv[r];
                const int row = l4*4 + r;
                scw[row*64 + ((c ^ (row & 7)) << 2) + jj] = p;
            }
        }
        lds_fence();

        // coalesced attn write (4 rows x 256B per instruction)
        #pragma unroll
        for (int it = 0; it < 4; ++it) {
            const int row = it*4 + (lane >> 4);
            const int c   = lane & 15;
            f32x4 v = *(f32x4*)&scw[row*64 + ((c ^ (row & 7)) << 2)];
            *(f32x4*)&gBase[(size_t)row*SS + chunk*64 + c*4] = v;
        }

        // PV over the chunk (2 k-groups of 32)
        #pragma unroll
        for (int t2 = 0; t2 < 2; ++t2) {
            const int c0 = t2*8 + l4*2;
            f32x4 a0 = *(f32x4*)&scw[l15*64 + (((c0    ) ^ (l15 & 7)) << 2)];
            f32x4 a1 = *(f32x4*)&scw[l15*64 + (((c0 + 1) ^ (l15 & 7)) << 2)];
            bf16x8 af;
            af[0] = (__bf16)a0[0]; af[1] = (__bf16)a0[1]; af[2] = (__bf16)a0[2]; af[3] = (__bf16)a0[3];
            af[4] = (__bf16)a1[0]; af[5] = (__bf16)a1[1]; af[6] = (__bf16)a1[2]; af[7] = (__bf16)a1[3];
            const u16* Vp = Vw + chunk*64 + t2*32 + l4*8;
            #pragma unroll
            for (int nt = 0; nt < 4; ++nt) {
                bf16x8 bf = *(const bf16x8*)(Vp + (size_t)nt*16*MTOT);
                pv[nt] = mfma16(af, bf, pv[nt]);
            }
        }
        lds_fence();   // PV reads retired before next chunk's stores
    }

    // ---- O transpose through scratch (stride 68) + hi/lo write ----
    #pragma unroll
    for (int nt = 0; nt < 4; ++nt)
        #pragma unroll
        for (int r = 0; r < 4; ++r)
            scw[(l4*4 + r)*68 + nt*16 + l15] = pv[nt][r];
    lds_fence();
    {
        const int row = lane >> 2, part = lane & 3;
        float vals[16];
        #pragma unroll
        for (int i = 0; i < 4; ++i) {
            f32x4 v = *(f32x4*)&scw[row*68 + part*16 + i*4];
            vals[i*4+0] = v[0]; vals[i*4+1] = v[1]; vals[i*4+2] = v[2]; vals[i*4+3] = v[3];
        }
        u16x8 hA, hB, lA, lB;
        #pragma unroll
        for (int k = 0; k < 8; ++k) {
            unsigned short hh = f2bf(vals[k]);
            hA[k] = hh; lA[k] = f2bf(vals[k] - bf2f(hh));
        }
        #pragma unroll
        for (int k = 0; k < 8; ++k) {
            unsigned short hh = f2bf(vals[8+k]);
            hB[k] = hh; lB[k] = f2bf(vals[8+k] - bf2f(hh));
        }
        const size_t off = ((size_t)(b*SS + q0w + row))*DD + h*HDD + part*16;
        *(u16x8*)&attH[off]     = hA;
        *(u16x8*)&attH[off + 8] = hB;
        *(u16x8*)&attL[off]     = lA;
        *(u16x8*)&attL[off + 8] = lB;
    }
}

extern "C" void kernel_launch(void* const* d_in, const int* in_sizes, int n_in,
                              void* d_out, int out_size, void* d_ws, size_t ws_size,
                              hipStream_t stream) {
    const float* x     = (const float*)d_in[0];
    const float* trust = (const float*)d_in[1];
    const int*   mask  = (const int*)  d_in[2];
    const float* Wq    = (const float*)d_in[3];
    const float* bq    = (const float*)d_in[4];
    const float* Wk    = (const float*)d_in[5];
    const float* bk    = (const float*)d_in[6];
    const float* Wv    = (const float*)d_in[7];
    const float* bv    = (const float*)d_in[8];
    const float* Wtp   = (const float*)d_in[9];
    const float* btp   = (const float*)d_in[10];
    const float* Wg    = (const float*)d_in[11];
    const float* bg    = (const float*)d_in[12];
    const float* Wo    = (const float*)d_in[13];
    const float* bo    = (const float*)d_in[14];

    float* out     = (float*)d_out;
    float* attnOut = out + (size_t)MTOT * DD;

    char* ws = (char*)d_ws;
    u16* xh    = (u16*)(ws + (size_t)0*MB);    // 8 MB -> attH later
    u16* xl    = (u16*)(ws + (size_t)8*MB);    // 8 MB -> attL later
    u16* WqkTh = (u16*)(ws + (size_t)16*MB);   // 4 MB: Wq^T rows 0-1023, Wk^T rows 1024-2047
    u16* WvTh  = (u16*)(ws + (size_t)20*MB);
    u16* WgTh  = (u16*)(ws + (size_t)22*MB);
    u16* WoTh  = (u16*)(ws + (size_t)24*MB);
    u16* WoTl  = (u16*)(ws + (size_t)26*MB);
    u16* QKbf  = (u16*)(ws + (size_t)28*MB);   // 16 MB [4096][2048] -> Gh/Gl later
    u16* Vt    = (u16*)(ws + (size_t)44*MB);   // 8 MB
    u16* Tb    = (u16*)(ws + (size_t)52*MB);   // 8 MB bf16 trust-bias table
    float* tconst = (float*)(ws + (size_t)60*MB);
    float* bqk    = (float*)(ws + (size_t)60*MB + 4096);  // 2048 floats
    u16* attH = xh;
    u16* attL = xl;
    u16* Gh   = (u16*)(ws + (size_t)28*MB);
    u16* Gl   = (u16*)(ws + (size_t)36*MB);

    const dim3 blk(256);

    tconst_kernel<<<1, 64, 0, stream>>>(Wtp, btp, tconst);
    tbias_kernel<<<dim3(SS, BB), blk, 0, stream>>>(trust, tconst, Tb);
    split_kernel<<<2048, blk, 0, stream>>>(x, xh, xl, MTOT*DD/4);
    tsplit5_kernel<<<dim3(16, 16, 5), blk, 0, stream>>>(
        Wq, WqkTh, Wk, WqkTh + (size_t)1024*1024, Wv, WvTh, Wg, WgTh, Wo, WoTh, WoTl);
    hipMemcpyAsync(bqk,        bq, 1024*sizeof(float), hipMemcpyDeviceToDevice, stream);
    hipMemcpyAsync(bqk + 1024, bk, 1024*sizeof(float), hipMemcpyDeviceToDevice, stream);

    // fused Q+K: C[m][0..2048) = x @ [Wq | Wk]  (2-pass, bf16 out)
    mgemm<2,2><<<dim3(QKS/128, MTOT/128), blk, 0, stream>>>(
        xh, xl, WqkTh, nullptr, bqk, nullptr, QKbf, nullptr, MTOT, QKS,
        nullptr, nullptr, nullptr, nullptr);
    // V^T: 1-pass, C[d_glob][m] = WvT @ x^T (bias by row)
    mgemm<3,1><<<dim3(MTOT/128, DD/128), blk, 0, stream>>>(
        WvTh, nullptr, xh, nullptr, bv, nullptr, Vt, nullptr, DD, MTOT,
        nullptr, nullptr, nullptr, nullptr);

    attn_kernel<<<dim3(SS/64, HH, BB), blk, 0, stream>>>(
        QKbf, Vt, Tb, mask, attnOut, attH, attL);

    // gate: 1-pass; gated = attended * sigmoid(attended@Wg[0:1024] + bg + trust*wlast)
    mgemm<1,1><<<dim3(DD/128, MTOT/128), blk, 0, stream>>>(
        attH, nullptr, WgTh, nullptr, bg, nullptr, Gh, Gl, MTOT, DD,
        trust, Wg + (size_t)DD*DD, attH, attL);
    // out = gated @ Wo + bo (fp32, 3-pass)
    mgemm<0,3><<<dim3(DD/128, MTOT/128), blk, 0, stream>>>(
        Gh, Gl, WoTh, WoTl, bo, out, nullptr, nullptr, MTOT, DD,
        nullptr, nullptr, nullptr, nullptr);
}

// Round 11
// 301.732 us; speedup vs baseline: 1.2390x; 1.2390x over previous
//
#include <hip/hip_runtime.h>
#include <math.h>

#define BB 4
#define SS 1024
#define DD 1024
#define HH 16
#define HDD 64
#define MTOT (BB*SS)   // 4096
#define QKS 2048       // fused QK buffer row stride
#define MB (1024*1024)

typedef float  f32x4  __attribute__((ext_vector_type(4)));
typedef __bf16 bf16x8 __attribute__((ext_vector_type(8)));
typedef unsigned short u16;

__device__ __forceinline__ unsigned short f2bf(float f) {
    union { float f; unsigned u; } v; v.f = f;
    unsigned r = v.u + 0x7FFFu + ((v.u >> 16) & 1u);
    return (unsigned short)(r >> 16);
}
__device__ __forceinline__ float bf2f(unsigned short u) {
    union { unsigned u; float f; } v; v.u = ((unsigned)u) << 16;
    return v.f;
}
__device__ __forceinline__ f32x4 mfma16(bf16x8 a, bf16x8 b, f32x4 c) {
    return __builtin_amdgcn_mfma_f32_16x16x32_bf16(a, b, c, 0, 0, 0);
}
__device__ __forceinline__ void gload16(const void* g, void* l) {
    __builtin_amdgcn_global_load_lds(
        (const __attribute__((address_space(1))) void*)g,
        (__attribute__((address_space(3))) void*)l, 16, 0, 0);
}

// ---------------- split: fp32 -> bf16 hi/lo ----------------
__global__ void split_kernel(const float* __restrict__ in, u16* __restrict__ hi,
                             u16* __restrict__ lo, int n4)
{
    for (int i = blockIdx.x*blockDim.x + threadIdx.x; i < n4; i += gridDim.x*blockDim.x) {
        f32x4 v = ((const f32x4*)in)[i];
        ushort4 h4, l4;
        h4.x = f2bf(v[0]); l4.x = f2bf(v[0] - bf2f(h4.x));
        h4.y = f2bf(v[1]); l4.y = f2bf(v[1] - bf2f(h4.y));
        h4.z = f2bf(v[2]); l4.z = f2bf(v[2] - bf2f(h4.z));
        h4.w = f2bf(v[3]); l4.w = f2bf(v[3] - bf2f(h4.w));
        ((ushort4*)hi)[i] = h4; ((ushort4*)lo)[i] = l4;
    }
}

// ------- fused transpose+split for all 5 weights: W[k][n] -> WT hi (+opt lo) [n][k] -------
__global__ __launch_bounds__(256)
void tsplit5_kernel(const float* W0, u16* h0,
                    const float* W1, u16* h1,
                    const float* W2, u16* h2,
                    const float* W3, u16* h3,
                    const float* W4, u16* h4, u16* l4T)
{
    const float* W; u16* hT; u16* lT = nullptr;
    switch (blockIdx.z) {
        case 0: W = W0; hT = h0; break;
        case 1: W = W1; hT = h1; break;
        case 2: W = W2; hT = h2; break;
        case 3: W = W3; hT = h3; break;
        default: W = W4; hT = h4; lT = l4T; break;
    }
    __shared__ float tile[64][65];
    const int t  = threadIdx.x;
    const int k0 = blockIdx.y * 64, n0 = blockIdx.x * 64;
    const int r  = t >> 4, c4 = (t & 15) * 4;
    #pragma unroll
    for (int rr = 0; rr < 4; ++rr) {
        const int k = r + rr*16;
        f32x4 v = *(const f32x4*)&W[(size_t)(k0 + k)*1024 + n0 + c4];
        tile[k][c4+0] = v[0]; tile[k][c4+1] = v[1]; tile[k][c4+2] = v[2]; tile[k][c4+3] = v[3];
    }
    __syncthreads();
    #pragma unroll
    for (int rr = 0; rr < 4; ++rr) {
        const int nl = r + rr*16;
        ushort4 hh, ll;
        {
            float v;
            v = tile[c4+0][nl]; hh.x = f2bf(v); ll.x = f2bf(v - bf2f(hh.x));
            v = tile[c4+1][nl]; hh.y = f2bf(v); ll.y = f2bf(v - bf2f(hh.y));
            v = tile[c4+2][nl]; hh.z = f2bf(v); ll.z = f2bf(v - bf2f(hh.z));
            v = tile[c4+3][nl]; hh.w = f2bf(v); ll.w = f2bf(v - bf2f(hh.w));
        }
        *(ushort4*)&hT[(size_t)(n0 + nl)*1024 + k0 + c4] = hh;
        if (lT) *(ushort4*)&lT[(size_t)(n0 + nl)*1024 + k0 + c4] = ll;
    }
}

// ---------------- trust-affinity rank-1 constants ----------------
__global__ void tconst_kernel(const float* __restrict__ Wtp, const float* __restrict__ btp,
                              float* __restrict__ out3)
{
    const int l = threadIdx.x;   // 64 threads
    const float w = Wtp[l], b = btp[l];
    float a = w*w, m = w*b, c = b*b;
    #pragma unroll
    for (int s = 32; s; s >>= 1) {
        a += __shfl_down(a, s);
        m += __shfl_down(m, s);
        c += __shfl_down(c, s);
    }
    if (l == 0) { out3[0] = a; out3[1] = m; out3[2] = c; }
}

// ---------------- trust bias table: T[b][q][k] = bf16(0.1*sigmoid(ta)) ----------------
__global__ __launch_bounds__(256)
void tbias_kernel(const float* __restrict__ trust, const float* __restrict__ tconst,
                  u16* __restrict__ T)
{
    const int b = blockIdx.y;
    const int q = blockIdx.x;
    const float tq = trust[b*SS + q];
    const float c1 = tconst[0], c2 = tconst[1], c3 = tconst[2];
    const int k0 = threadIdx.x * 4;
    f32x4 tk = *(const f32x4*)&trust[b*SS + k0];
    ushort4 o;
    #pragma unroll
    for (int j = 0; j < 4; ++j) {
        const float ta = c1*tq*tk[j] + c2*(tq + tk[j]) + c3;
        const float v  = 0.1f/(1.f + __expf(-ta));
        ((u16*)&o)[j] = f2bf(v);
    }
    *(ushort4*)&T[((size_t)b*SS + q)*SS + k0] = o;
}

// ---------------- split-bf16 MFMA GEMM ----------------
// PASSES=3: AhBh + AhBl + AlBh ; PASSES=2: AhBh + AlBh ; PASSES=1: AhBh
template<int MODE, int PASSES>
__global__ __launch_bounds__(256)
void mgemm(const u16* __restrict__ Ah, const u16* __restrict__ Al,
           const u16* __restrict__ Bh, const u16* __restrict__ Bl,
           const float* __restrict__ bias,
           float* __restrict__ outF, u16* __restrict__ outH, u16* __restrict__ outL,
           int M, int N,
           const float* __restrict__ trust, const float* __restrict__ wlast,
           const u16* __restrict__ attH, const u16* __restrict__ attL)
{
    constexpr int NT   = (PASSES == 3) ? 4 : (PASSES == 2) ? 3 : 2;
    constexpr int BIDX = (PASSES == 1) ? 1 : 2;
    __shared__ u16 lds[2][NT][128*64];

    const int t    = threadIdx.x;
    const int lane = t & 63, wave = t >> 6;
    const int l15  = lane & 15, l4 = lane >> 4;
    const int wr   = wave >> 1, wc = wave & 1;
    const int w64  = wave << 6;
    const int m0   = blockIdx.y * 128, n0 = blockIdx.x * 128;

    const u16* srcs[NT];
    srcs[0] = Ah + (size_t)m0*1024;
    if (PASSES >= 2) srcs[1] = Al + (size_t)m0*1024;
    srcs[BIDX] = Bh + (size_t)n0*1024;
    if (PASSES == 3) srcs[3] = Bl + (size_t)n0*1024;

    f32x4 acc[4][4];
    #pragma unroll
    for (int i = 0; i < 4; ++i)
        #pragma unroll
        for (int j = 0; j < 4; ++j) acc[i][j] = (f32x4){0.f,0.f,0.f,0.f};

#define STAGE(BUF, KOFF) do {                                                  \
    _Pragma("unroll")                                                          \
    for (int tl_ = 0; tl_ < NT; ++tl_) {                                       \
        _Pragma("unroll")                                                      \
        for (int it_ = 0; it_ < 4; ++it_) {                                    \
            const int idx_ = it_*256 + t;                                      \
            const int row_ = idx_ >> 3;                                        \
            const int c_   = (idx_ & 7) ^ (row_ & 7);                          \
            gload16(srcs[tl_] + (KOFF) + (size_t)row_*1024 + c_*8,             \
                    &lds[BUF][tl_][(it_*256 + w64)*8]);                        \
        }                                                                      \
    }                                                                          \
} while(0)

#define COMPUTE(BUF) do {                                                      \
    _Pragma("unroll")                                                          \
    for (int kk_ = 0; kk_ < 2; ++kk_) {                                        \
        const int cb_ = (kk_<<2) + l4;                                         \
        bf16x8 ah_[4], al_[4];                                                 \
        _Pragma("unroll")                                                      \
        for (int i_ = 0; i_ < 4; ++i_) {                                       \
            const int row_ = (wr<<6) + (i_<<4) + l15;                          \
            const int off_ = (row_<<6) + ((cb_ ^ (row_&7)) << 3);              \
            ah_[i_] = *(const bf16x8*)&lds[BUF][0][off_];                      \
            if (PASSES >= 2) al_[i_] = *(const bf16x8*)&lds[BUF][1][off_];     \
        }                                                                      \
        _Pragma("unroll")                                                      \
        for (int j_ = 0; j_ < 4; ++j_) {                                       \
            const int row_ = (wc<<6) + (j_<<4) + l15;                          \
            const int off_ = (row_<<6) + ((cb_ ^ (row_&7)) << 3);              \
            bf16x8 bh_ = *(const bf16x8*)&lds[BUF][BIDX][off_];                \
            bf16x8 bl_;                                                        \
            if (PASSES == 3) bl_ = *(const bf16x8*)&lds[BUF][3][off_];         \
            _Pragma("unroll")                                                  \
            for (int i_ = 0; i_ < 4; ++i_) {                                   \
                acc[i_][j_] = mfma16(ah_[i_], bh_, acc[i_][j_]);               \
                if (PASSES == 3) acc[i_][j_] = mfma16(ah_[i_], bl_, acc[i_][j_]); \
                if (PASSES >= 2) acc[i_][j_] = mfma16(al_[i_], bh_, acc[i_][j_]); \
            }                                                                  \
        }                                                                      \
    }                                                                          \
} while(0)

    STAGE(0, 0);
    __syncthreads();
    int cur = 0;
    for (int s = 0; s < 15; ++s) {
        if (cur == 0) STAGE(1, (s+1)*64);
        else          STAGE(0, (s+1)*64);
        COMPUTE(cur);
        __syncthreads();
        cur ^= 1;
    }
    COMPUTE(cur);
#undef STAGE
#undef COMPUTE

    // ---- epilogue ----
    #pragma unroll
    for (int i = 0; i < 4; ++i)
        #pragma unroll
        for (int j = 0; j < 4; ++j)
            #pragma unroll
            for (int r = 0; r < 4; ++r) {
                const int m = m0 + (wr<<6) + (i<<4) + (l4<<2) + r;
                const int n = n0 + (wc<<6) + (j<<4) + l15;
                const float v = acc[i][j][r];
                if (MODE == 0) {
                    outF[(size_t)m*N + n] = v + bias[n];
                } else if (MODE == 2) {
                    outH[(size_t)m*N + n] = f2bf(v + bias[n]);
                } else if (MODE == 3) {
                    outH[(size_t)m*N + n] = f2bf(v + bias[m]);
                } else {
                    const float pre = v + bias[n] + trust[m]*wlast[n];
                    const float g = 1.f/(1.f + __expf(-pre));
                    const float att = bf2f(attH[(size_t)m*N + n]) + bf2f(attL[(size_t)m*N + n]);
                    const float gated = att*g;
                    const unsigned short hb = f2bf(gated);
                    outH[(size_t)m*N + n] = hb;
                    outL[(size_t)m*N + n] = f2bf(gated - bf2f(hb));
                }
            }
}

// ---------------- Attention v8: r9 structure + XCD panel-locality swizzle ----------------
// 1-D grid 4096, bid = (P%8) + 8*q6 + 512*(P/8): all 64 q-blocks of panel P=(b,h) land
// on XCD P%8 in a contiguous window -> K/V/T panels stay in that XCD's 4MB L2.
// Block: 16 q rows x (b,h), 512 threads / 8 waves; wave w owns keys [w*128, w*128+128).
// Two K-half phases through a 32KB fp32 strip (store -> coalesced attn write -> PV).
__global__ __launch_bounds__(512, 4)
void attn_kernel(const u16* __restrict__ QK, const u16* __restrict__ Vt,
                 const u16* __restrict__ T, const int* __restrict__ mask,
                 float* __restrict__ attnOut, u16* __restrict__ attH, u16* __restrict__ attL)
{
    __shared__ float P[16*512];       // 32 KB strip (aliased for O reduce at the end)
    __shared__ float redA[8][16];
    __shared__ float redB[8][16];
    __shared__ int   mqv[16];

    const int t    = threadIdx.x;
    const int lane = t & 63, wave = t >> 6;     // 8 waves
    const int l15  = lane & 15, l4 = lane >> 4;

    // decode panel swizzle
    const int bid = blockIdx.x;
    const int xcd = bid & 7;
    const int idx = bid >> 3;
    const int q0  = (idx & 63) * 16;
    const int Pn  = ((idx >> 6) << 3) + xcd;   // panel 0..63
    const int h   = Pn & 15;
    const int b   = Pn >> 4;

    const int wk0  = wave * 128;

    if (t < 16) mqv[t] = mask[b*SS + q0 + t];

    const u16* Qp = QK + ((size_t)(b*SS + q0 + l15))*QKS + h*HDD + l4*8;
    bf16x8 qf0 = *(const bf16x8*)Qp;
    bf16x8 qf1 = *(const bf16x8*)(Qp + 32);

    const u16* Tbase = T + ((size_t)b*SS + q0 + l4*4)*SS + wk0 + l15;
    __syncthreads();

    // ---- QK^T: 8 key tiles of 16 per wave ----
    f32x4 sacc[8];
    #pragma unroll
    for (int tt = 0; tt < 8; ++tt) sacc[tt] = (f32x4){0.f,0.f,0.f,0.f};

    const u16* Kbase = QK + 1024 + ((size_t)(b*SS + wk0 + l15))*QKS + h*HDD + l4*8;
    #pragma unroll
    for (int tt = 0; tt < 8; ++tt) {
        const u16* Kp = Kbase + (size_t)tt*(16*QKS);
        bf16x8 kf0 = *(const bf16x8*)Kp;
        bf16x8 kf1 = *(const bf16x8*)(Kp + 32);
        sacc[tt] = mfma16(qf0, kf0, sacc[tt]);
        sacc[tt] = mfma16(qf1, kf1, sacc[tt]);
    }

    // ---- bias + mask + wave-local row-max ----
    int mrow[4];
    #pragma unroll
    for (int r = 0; r < 4; ++r) mrow[r] = mqv[l4*4 + r];

    float mx[4] = {-3e38f, -3e38f, -3e38f, -3e38f};
    #pragma unroll
    for (int tt = 0; tt < 8; ++tt) {
        #pragma unroll
        for (int r = 0; r < 4; ++r) {
            const float bias = bf2f(Tbase[(size_t)r*SS + tt*16]);
            float s = sacc[tt][r]*0.125f + bias;
            s = mrow[r] ? s : -1e9f;
            sacc[tt][r] = s;
            mx[r] = fmaxf(mx[r], s);
        }
    }
    #pragma unroll
    for (int r = 0; r < 4; ++r)
        #pragma unroll
        for (int xm = 1; xm < 16; xm <<= 1) mx[r] = fmaxf(mx[r], __shfl_xor(mx[r], xm));
    if (l15 == 0) {
        #pragma unroll
        for (int r = 0; r < 4; ++r) redA[wave][l4*4 + r] = mx[r];
    }
    __syncthreads();

    float mxa[4];
    #pragma unroll
    for (int r = 0; r < 4; ++r) {
        const int row = l4*4 + r;
        float m = redA[0][row];
        #pragma unroll
        for (int w = 1; w < 8; ++w) m = fmaxf(m, redA[w][row]);
        mxa[r] = m;
    }

    // ---- exp in regs + row-sum ----
    float sum[4] = {0.f, 0.f, 0.f, 0.f};
    #pragma unroll
    for (int tt = 0; tt < 8; ++tt)
        #pragma unroll
        for (int r = 0; r < 4; ++r) {
            const float p = __expf(sacc[tt][r] - mxa[r]);
            sacc[tt][r] = p;
            sum[r] += p;
        }
    #pragma unroll
    for (int r = 0; r < 4; ++r)
        #pragma unroll
        for (int xm = 1; xm < 16; xm <<= 1) sum[r] += __shfl_xor(sum[r], xm);
    if (l15 == 0) {
        #pragma unroll
        for (int r = 0; r < 4; ++r) redB[wave][l4*4 + r] = sum[r];
    }
    __syncthreads();

    // row inverse sums
    float inv4[4];
    #pragma unroll
    for (int r = 0; r < 4; ++r) {
        const int row = l4*4 + r;
        float s8 = 0.f;
        #pragma unroll
        for (int w = 0; w < 8; ++w) s8 += redB[w][row];
        inv4[r] = 1.f / s8;
    }
    const int wrow = t >> 5;              // attn-write row (16 rows, 32 threads each)
    const int wcl  = t & 31;
    float wiv;
    {
        float s8 = 0.f;
        #pragma unroll
        for (int w = 0; w < 8; ++w) s8 += redB[w][wrow];
        wiv = 1.f / s8;
    }
    float* gRow = attnOut + ((size_t)(b*HH + h))*SS*SS + (size_t)(q0 + wrow)*SS;

    const u16* Vw = Vt + ((size_t)(h*HDD + l15))*MTOT + b*SS + wk0;
    f32x4 pv[4];
    #pragma unroll
    for (int nt = 0; nt < 4; ++nt) pv[nt] = (f32x4){0.f,0.f,0.f,0.f};

    // ================= two K-half phases (all waves active in both) =================
    #pragma unroll
    for (int ph = 0; ph < 2; ++ph) {
        // store sacc[4ph .. 4ph+4): wave's keys w*128 + ph*64 + [0,64) -> slots w*64 + j
        #pragma unroll
        for (int t2 = 0; t2 < 4; ++t2) {
            const int slot = wave*64 + t2*16 + l15;
            const int c = slot >> 2, jj = slot & 3;
            #pragma unroll
            for (int r = 0; r < 4; ++r) {
                const int row = l4*4 + r;
                P[row*512 + ((c ^ (row & 7)) << 2) + jj] = sacc[4*ph + t2][r];
            }
        }
        __syncthreads();

        // stream this phase's attn columns (normalized), 256B-contiguous runs
        #pragma unroll
        for (int i = 0; i < 4; ++i) {
            const int c  = wcl + i*32;          // chunk 0..127
            const int sb = c*4;                 // slot base
            f32x4 v = *(f32x4*)&P[wrow*512 + ((c ^ (wrow & 7)) << 2)];
            v *= wiv;
            const int kg = (sb >> 6)*128 + ph*64 + (sb & 63);
            *(f32x4*)&gRow[kg] = v;
        }

        // PV over this phase's 64-key segment (2 k-groups of 32)
        #pragma unroll
        for (int t2 = 0; t2 < 2; ++t2) {
            const int c0 = wave*16 + t2*8 + l4*2;
            f32x4 a0 = *(f32x4*)&P[l15*512 + (((c0    ) ^ (l15 & 7)) << 2)];
            f32x4 a1 = *(f32x4*)&P[l15*512 + (((c0 + 1) ^ (l15 & 7)) << 2)];
            bf16x8 af;
            af[0] = (__bf16)a0[0]; af[1] = (__bf16)a0[1]; af[2] = (__bf16)a0[2]; af[3] = (__bf16)a0[3];
            af[4] = (__bf16)a1[0]; af[5] = (__bf16)a1[1]; af[6] = (__bf16)a1[2]; af[7] = (__bf16)a1[3];
            const u16* Vp = Vw + ph*64 + t2*32 + l4*8;
            #pragma unroll
            for (int nt = 0; nt < 4; ++nt) {
                bf16x8 bf = *(const bf16x8*)(Vp + (size_t)nt*16*MTOT);
                pv[nt] = mfma16(af, bf, pv[nt]);
            }
        }
        __syncthreads();   // strip consumed before overwrite / final alias
    }

    // ---- cross-wave reduce through LDS (alias P = 8192 floats), scaled by 1/sum ----
    float* pw = P + wave*1024;
    #pragma unroll
    for (int nt = 0; nt < 4; ++nt)
        #pragma unroll
        for (int r = 0; r < 4; ++r)
            pw[(l4*4 + r)*64 + nt*16 + l15] = pv[nt][r] * inv4[r];
    __syncthreads();

    {
        const int q = t >> 5, d0 = (t & 31)*2;
        float sx = 0.f, sy = 0.f;
        #pragma unroll
        for (int w = 0; w < 8; ++w) {
            float2 v = *(float2*)&P[w*1024 + q*64 + d0];
            sx += v.x; sy += v.y;
        }
        const size_t off = ((size_t)(b*SS + q0 + q))*DD + h*HDD + d0;
        const unsigned short h0 = f2bf(sx), h1 = f2bf(sy);
        ushort2 hh = {h0, h1};
        ushort2 ll = {f2bf(sx - bf2f(h0)), f2bf(sy - bf2f(h1))};
        *(ushort2*)&attH[off] = hh;
        *(ushort2*)&attL[off] = ll;
    }
}

extern "C" void kernel_launch(void* const* d_in, const int* in_sizes, int n_in,
                              void* d_out, int out_size, void* d_ws, size_t ws_size,
                              hipStream_t stream) {
    const float* x     = (const float*)d_in[0];
    const float* trust = (const float*)d_in[1];
    const int*   mask  = (const int*)  d_in[2];
    const float* Wq    = (const float*)d_in[3];
    const float* bq    = (const float*)d_in[4];
    const float* Wk    = (const float*)d_in[5];
    const float* bk    = (const float*)d_in[6];
    const float* Wv    = (const float*)d_in[7];
    const float* bv    = (const float*)d_in[8];
    const float* Wtp   = (const float*)d_in[9];
    const float* btp   = (const float*)d_in[10];
    const float* Wg    = (const float*)d_in[11];
    const float* bg    = (const float*)d_in[12];
    const float* Wo    = (const float*)d_in[13];
    const float* bo    = (const float*)d_in[14];

    float* out     = (float*)d_out;
    float* attnOut = out + (size_t)MTOT * DD;

    char* ws = (char*)d_ws;
    u16* xh    = (u16*)(ws + (size_t)0*MB);    // 8 MB -> attH later
    u16* xl    = (u16*)(ws + (size_t)8*MB);    // 8 MB -> attL later
    u16* WqkTh = (u16*)(ws + (size_t)16*MB);   // 4 MB: Wq^T rows 0-1023, Wk^T rows 1024-2047
    u16* WvTh  = (u16*)(ws + (size_t)20*MB);
    u16* WgTh  = (u16*)(ws + (size_t)22*MB);
    u16* WoTh  = (u16*)(ws + (size_t)24*MB);
    u16* WoTl  = (u16*)(ws + (size_t)26*MB);
    u16* QKbf  = (u16*)(ws + (size_t)28*MB);   // 16 MB [4096][2048] -> Gh/Gl later
    u16* Vt    = (u16*)(ws + (size_t)44*MB);   // 8 MB
    u16* Tb    = (u16*)(ws + (size_t)52*MB);   // 8 MB bf16 trust-bias table
    float* tconst = (float*)(ws + (size_t)60*MB);
    float* bqk    = (float*)(ws + (size_t)60*MB + 4096);  // 2048 floats
    u16* attH = xh;
    u16* attL = xl;
    u16* Gh   = (u16*)(ws + (size_t)28*MB);
    u16* Gl   = (u16*)(ws + (size_t)36*MB);

    const dim3 blk(256);

    tconst_kernel<<<1, 64, 0, stream>>>(Wtp, btp, tconst);
    tbias_kernel<<<dim3(SS, BB), blk, 0, stream>>>(trust, tconst, Tb);
    split_kernel<<<2048, blk, 0, stream>>>(x, xh, xl, MTOT*DD/4);
    tsplit5_kernel<<<dim3(16, 16, 5), blk, 0, stream>>>(
        Wq, WqkTh, Wk, WqkTh + (size_t)1024*1024, Wv, WvTh, Wg, WgTh, Wo, WoTh, WoTl);
    hipMemcpyAsync(bqk,        bq, 1024*sizeof(float), hipMemcpyDeviceToDevice, stream);
    hipMemcpyAsync(bqk + 1024, bk, 1024*sizeof(float), hipMemcpyDeviceToDevice, stream);

    // fused Q+K: C[m][0..2048) = x @ [Wq | Wk]  (2-pass, bf16 out)
    mgemm<2,2><<<dim3(QKS/128, MTOT/128), blk, 0, stream>>>(
        xh, xl, WqkTh, nullptr, bqk, nullptr, QKbf, nullptr, MTOT, QKS,
        nullptr, nullptr, nullptr, nullptr);
    // V^T: 1-pass, C[d_glob][m] = WvT @ x^T (bias by row)
    mgemm<3,1><<<dim3(MTOT/128, DD/128), blk, 0, stream>>>(
        WvTh, nullptr, xh, nullptr, bv, nullptr, Vt, nullptr, DD, MTOT,
        nullptr, nullptr, nullptr, nullptr);

    attn_kernel<<<dim3(4096), dim3(512), 0, stream>>>(
        QKbf, Vt, Tb, mask, attnOut, attH, attL);

    // gate: 1-pass; gated = attended * sigmoid(attended@Wg[0:1024] + bg + trust*wlast)
    mgemm<1,1><<<dim3(DD/128, MTOT/128), blk, 0, stream>>>(
        attH, nullptr, WgTh, nullptr, bg, nullptr, Gh, Gl, MTOT, DD,
        trust, Wg + (size_t)DD*DD, attH, attL);
    // out = gated @ Wo + bo (fp32, 3-pass)
    mgemm<0,3><<<dim3(DD/128, MTOT/128), blk, 0, stream>>>(
        Gh, Gl, WoTh, WoTl, bo, out, nullptr, nullptr, MTOT, DD,
        nullptr, nullptr, nullptr, nullptr);
}

// Round 12
// 270.964 us; speedup vs baseline: 1.3796x; 1.1136x over previous
//
#include <hip/hip_runtime.h>
#include <math.h>

#define BB 4
#define SS 1024
#define DD 1024
#define HH 16
#define HDD 64
#define MTOT (BB*SS)   // 4096
#define QKS 2048       // fused QK buffer row stride
#define MB (1024*1024)

typedef float  f32x4  __attribute__((ext_vector_type(4)));
typedef __bf16 bf16x8 __attribute__((ext_vector_type(8)));
typedef unsigned short u16;

__device__ __forceinline__ unsigned short f2bf(float f) {
    union { float f; unsigned u; } v; v.f = f;
    unsigned r = v.u + 0x7FFFu + ((v.u >> 16) & 1u);
    return (unsigned short)(r >> 16);
}
__device__ __forceinline__ float bf2f(unsigned short u) {
    union { unsigned u; float f; } v; v.u = ((unsigned)u) << 16;
    return v.f;
}
__device__ __forceinline__ f32x4 mfma16(bf16x8 a, bf16x8 b, f32x4 c) {
    return __builtin_amdgcn_mfma_f32_16x16x32_bf16(a, b, c, 0, 0, 0);
}
__device__ __forceinline__ void gload16(const void* g, void* l) {
    __builtin_amdgcn_global_load_lds(
        (const __attribute__((address_space(1))) void*)g,
        (__attribute__((address_space(3))) void*)l, 16, 0, 0);
}

// ---------------- split: fp32 -> bf16 hi/lo ----------------
__global__ void split_kernel(const float* __restrict__ in, u16* __restrict__ hi,
                             u16* __restrict__ lo, int n4)
{
    for (int i = blockIdx.x*blockDim.x + threadIdx.x; i < n4; i += gridDim.x*blockDim.x) {
        f32x4 v = ((const f32x4*)in)[i];
        ushort4 h4, l4;
        h4.x = f2bf(v[0]); l4.x = f2bf(v[0] - bf2f(h4.x));
        h4.y = f2bf(v[1]); l4.y = f2bf(v[1] - bf2f(h4.y));
        h4.z = f2bf(v[2]); l4.z = f2bf(v[2] - bf2f(h4.z));
        h4.w = f2bf(v[3]); l4.w = f2bf(v[3] - bf2f(h4.w));
        ((ushort4*)hi)[i] = h4; ((ushort4*)lo)[i] = l4;
    }
}

// ------- fused transpose+split for all 5 weights: W[k][n] -> WT hi (+opt lo) [n][k] -------
__global__ __launch_bounds__(256)
void tsplit5_kernel(const float* W0, u16* h0,
                    const float* W1, u16* h1,
                    const float* W2, u16* h2,
                    const float* W3, u16* h3,
                    const float* W4, u16* h4, u16* l4T)
{
    const float* W; u16* hT; u16* lT = nullptr;
    switch (blockIdx.z) {
        case 0: W = W0; hT = h0; break;
        case 1: W = W1; hT = h1; break;
        case 2: W = W2; hT = h2; break;
        case 3: W = W3; hT = h3; break;
        default: W = W4; hT = h4; lT = l4T; break;
    }
    __shared__ float tile[64][65];
    const int t  = threadIdx.x;
    const int k0 = blockIdx.y * 64, n0 = blockIdx.x * 64;
    const int r  = t >> 4, c4 = (t & 15) * 4;
    #pragma unroll
    for (int rr = 0; rr < 4; ++rr) {
        const int k = r + rr*16;
        f32x4 v = *(const f32x4*)&W[(size_t)(k0 + k)*1024 + n0 + c4];
        tile[k][c4+0] = v[0]; tile[k][c4+1] = v[1]; tile[k][c4+2] = v[2]; tile[k][c4+3] = v[3];
    }
    __syncthreads();
    #pragma unroll
    for (int rr = 0; rr < 4; ++rr) {
        const int nl = r + rr*16;
        ushort4 hh, ll;
        {
            float v;
            v = tile[c4+0][nl]; hh.x = f2bf(v); ll.x = f2bf(v - bf2f(hh.x));
            v = tile[c4+1][nl]; hh.y = f2bf(v); ll.y = f2bf(v - bf2f(hh.y));
            v = tile[c4+2][nl]; hh.z = f2bf(v); ll.z = f2bf(v - bf2f(hh.z));
            v = tile[c4+3][nl]; hh.w = f2bf(v); ll.w = f2bf(v - bf2f(hh.w));
        }
        *(ushort4*)&hT[(size_t)(n0 + nl)*1024 + k0 + c4] = hh;
        if (lT) *(ushort4*)&lT[(size_t)(n0 + nl)*1024 + k0 + c4] = ll;
    }
}

// ---------------- trust-affinity rank-1 constants ----------------
__global__ void tconst_kernel(const float* __restrict__ Wtp, const float* __restrict__ btp,
                              float* __restrict__ out3)
{
    const int l = threadIdx.x;   // 64 threads
    const float w = Wtp[l], b = btp[l];
    float a = w*w, m = w*b, c = b*b;
    #pragma unroll
    for (int s = 32; s; s >>= 1) {
        a += __shfl_down(a, s);
        m += __shfl_down(m, s);
        c += __shfl_down(c, s);
    }
    if (l == 0) { out3[0] = a; out3[1] = m; out3[2] = c; }
}

// ---------------- trust bias table: T[b][q][k] = bf16(0.1*sigmoid(ta)) ----------------
__global__ __launch_bounds__(256)
void tbias_kernel(const float* __restrict__ trust, const float* __restrict__ tconst,
                  u16* __restrict__ T)
{
    const int b = blockIdx.y;
    const int q = blockIdx.x;
    const float tq = trust[b*SS + q];
    const float c1 = tconst[0], c2 = tconst[1], c3 = tconst[2];
    const int k0 = threadIdx.x * 4;
    f32x4 tk = *(const f32x4*)&trust[b*SS + k0];
    ushort4 o;
    #pragma unroll
    for (int j = 0; j < 4; ++j) {
        const float ta = c1*tq*tk[j] + c2*(tq + tk[j]) + c3;
        const float v  = 0.1f/(1.f + __expf(-ta));
        ((u16*)&o)[j] = f2bf(v);
    }
    *(ushort4*)&T[((size_t)b*SS + q)*SS + k0] = o;
}

// ---------------- split-bf16 MFMA GEMM ----------------
// PASSES=3: AhBh + AhBl + AlBh ; PASSES=2: AhBh + AlBh ; PASSES=1: AhBh
template<int MODE, int PASSES>
__global__ __launch_bounds__(256)
void mgemm(const u16* __restrict__ Ah, const u16* __restrict__ Al,
           const u16* __restrict__ Bh, const u16* __restrict__ Bl,
           const float* __restrict__ bias,
           float* __restrict__ outF, u16* __restrict__ outH, u16* __restrict__ outL,
           int M, int N,
           const float* __restrict__ trust, const float* __restrict__ wlast,
           const u16* __restrict__ attH, const u16* __restrict__ attL)
{
    constexpr int NT   = (PASSES == 3) ? 4 : (PASSES == 2) ? 3 : 2;
    constexpr int BIDX = (PASSES == 1) ? 1 : 2;
    __shared__ u16 lds[2][NT][128*64];

    const int t    = threadIdx.x;
    const int lane = t & 63, wave = t >> 6;
    const int l15  = lane & 15, l4 = lane >> 4;
    const int wr   = wave >> 1, wc = wave & 1;
    const int w64  = wave << 6;
    const int m0   = blockIdx.y * 128, n0 = blockIdx.x * 128;

    const u16* srcs[NT];
    srcs[0] = Ah + (size_t)m0*1024;
    if (PASSES >= 2) srcs[1] = Al + (size_t)m0*1024;
    srcs[BIDX] = Bh + (size_t)n0*1024;
    if (PASSES == 3) srcs[3] = Bl + (size_t)n0*1024;

    f32x4 acc[4][4];
    #pragma unroll
    for (int i = 0; i < 4; ++i)
        #pragma unroll
        for (int j = 0; j < 4; ++j) acc[i][j] = (f32x4){0.f,0.f,0.f,0.f};

#define STAGE(BUF, KOFF) do {                                                  \
    _Pragma("unroll")                                                          \
    for (int tl_ = 0; tl_ < NT; ++tl_) {                                       \
        _Pragma("unroll")                                                      \
        for (int it_ = 0; it_ < 4; ++it_) {                                    \
            const int idx_ = it_*256 + t;                                      \
            const int row_ = idx_ >> 3;                                        \
            const int c_   = (idx_ & 7) ^ (row_ & 7);                          \
            gload16(srcs[tl_] + (KOFF) + (size_t)row_*1024 + c_*8,             \
                    &lds[BUF][tl_][(it_*256 + w64)*8]);                        \
        }                                                                      \
    }                                                                          \
} while(0)

#define COMPUTE(BUF) do {                                                      \
    _Pragma("unroll")                                                          \
    for (int kk_ = 0; kk_ < 2; ++kk_) {                                        \
        const int cb_ = (kk_<<2) + l4;                                         \
        bf16x8 ah_[4], al_[4];                                                 \
        _Pragma("unroll")                                                      \
        for (int i_ = 0; i_ < 4; ++i_) {                                       \
            const int row_ = (wr<<6) + (i_<<4) + l15;                          \
            const int off_ = (row_<<6) + ((cb_ ^ (row_&7)) << 3);              \
            ah_[i_] = *(const bf16x8*)&lds[BUF][0][off_];                      \
            if (PASSES >= 2) al_[i_] = *(const bf16x8*)&lds[BUF][1][off_];     \
        }                                                                      \
        _Pragma("unroll")                                                      \
        for (int j_ = 0; j_ < 4; ++j_) {                                       \
            const int row_ = (wc<<6) + (j_<<4) + l15;                          \
            const int off_ = (row_<<6) + ((cb_ ^ (row_&7)) << 3);              \
            bf16x8 bh_ = *(const bf16x8*)&lds[BUF][BIDX][off_];                \
            bf16x8 bl_;                                                        \
            if (PASSES == 3) bl_ = *(const bf16x8*)&lds[BUF][3][off_];         \
            _Pragma("unroll")                                                  \
            for (int i_ = 0; i_ < 4; ++i_) {                                   \
                acc[i_][j_] = mfma16(ah_[i_], bh_, acc[i_][j_]);               \
                if (PASSES == 3) acc[i_][j_] = mfma16(ah_[i_], bl_, acc[i_][j_]); \
                if (PASSES >= 2) acc[i_][j_] = mfma16(al_[i_], bh_, acc[i_][j_]); \
            }                                                                  \
        }                                                                      \
    }                                                                          \
} while(0)

    STAGE(0, 0);
    __syncthreads();
    int cur = 0;
    for (int s = 0; s < 15; ++s) {
        if (cur == 0) STAGE(1, (s+1)*64);
        else          STAGE(0, (s+1)*64);
        COMPUTE(cur);
        __syncthreads();
        cur ^= 1;
    }
    COMPUTE(cur);
#undef STAGE
#undef COMPUTE

    // ---- epilogue ----
    #pragma unroll
    for (int i = 0; i < 4; ++i)
        #pragma unroll
        for (int j = 0; j < 4; ++j)
            #pragma unroll
            for (int r = 0; r < 4; ++r) {
                const int m = m0 + (wr<<6) + (i<<4) + (l4<<2) + r;
                const int n = n0 + (wc<<6) + (j<<4) + l15;
                const float v = acc[i][j][r];
                if (MODE == 0) {
                    outF[(size_t)m*N + n] = v + bias[n];
                } else if (MODE == 2) {
                    outH[(size_t)m*N + n] = f2bf(v + bias[n]);
                } else if (MODE == 3) {
                    outH[(size_t)m*N + n] = f2bf(v + bias[m]);
                } else {
                    const float pre = v + bias[n] + trust[m]*wlast[n];
                    const float g = 1.f/(1.f + __expf(-pre));
                    const float att = bf2f(attH[(size_t)m*N + n]) + bf2f(attL[(size_t)m*N + n]);
                    const float gated = att*g;
                    const unsigned short hb = f2bf(gated);
                    outH[(size_t)m*N + n] = hb;
                    outL[(size_t)m*N + n] = f2bf(gated - bf2f(hb));
                }
            }
}

// ---------------- Attention v9: LDS-staged K/V (mgemm pattern) ----------------
// Fix for the TA line-transaction bottleneck: direct-global bf16x8 fragment loads touch
// 64 cache lines/instr (16 rows apart). Now K is staged per 128-key chunk (16KB dbuf,
// global_load_lds, inverse-swizzled source) and V per 256-key slab (32KB), both read
// back as LDS fragments with XOR-swizzle (<=2-way conflicts). Wave w owns keys w*16
// within each chunk -> each phase's 512 keys are CONTIGUOUS -> attn writes are 2KB/row.
__global__ __launch_bounds__(512, 2)
void attn_kernel(const u16* __restrict__ QK, const u16* __restrict__ Vt,
                 const u16* __restrict__ T, const int* __restrict__ mask,
                 float* __restrict__ attnOut, u16* __restrict__ attH, u16* __restrict__ attL)
{
    __shared__ float P[16*512];       // 32 KB strip (aliased for O reduce at the end)
    __shared__ u16   kv[2][8192];     // 2x16KB K dbuf; reused as one 32KB V slab
    __shared__ float redA[8][16];
    __shared__ float redB[8][16];
    __shared__ int   mqv[16];

    const int t    = threadIdx.x;
    const int lane = t & 63, wave = t >> 6;     // 8 waves
    const int l15  = lane & 15, l4 = lane >> 4;

    // panel swizzle: all 64 q-blocks of panel P=(b,h) on one XCD window
    const int bid  = blockIdx.x;
    const int xcd  = bid & 7;
    const int idx0 = bid >> 3;
    const int q0   = (idx0 & 63) * 16;
    const int Pn   = ((idx0 >> 6) << 3) + xcd;
    const int h    = Pn & 15;
    const int b    = Pn >> 4;

    if (t < 16) mqv[t] = mask[b*SS + q0 + t];

    const u16* Qp = QK + ((size_t)(b*SS + q0 + l15))*QKS + h*HDD + l4*8;
    bf16x8 qf0 = *(const bf16x8*)Qp;
    bf16x8 qf1 = *(const bf16x8*)(Qp + 32);

    const u16* Ksrc = QK + 1024 + ((size_t)(b*SS))*QKS + h*HDD;

    // ---- K chunks of 128 keys, double-buffered LDS staging + QK^T ----
    f32x4 sacc[8];
    #pragma unroll
    for (int c = 0; c < 8; ++c) sacc[c] = (f32x4){0.f,0.f,0.f,0.f};

#define KSTAGE(BUF, CH) do {                                                   \
    _Pragma("unroll")                                                          \
    for (int it_ = 0; it_ < 2; ++it_) {                                        \
        const int idx_ = it_*512 + t;                                          \
        const int row_ = idx_ >> 3;                                            \
        const int ch_  = (idx_ & 7) ^ (row_ & 7);                              \
        gload16(Ksrc + ((size_t)((CH)*128 + row_))*QKS + ch_*8,                \
                &kv[BUF][idx_*8]);                                             \
    }                                                                          \
} while(0)

    KSTAGE(0, 0);
    __syncthreads();
    #pragma unroll
    for (int c = 0; c < 8; ++c) {
        if (c < 7) { if (c & 1) KSTAGE(0, c + 1); else KSTAGE(1, c + 1); }
        const u16* kb = kv[c & 1];
        const int kr = wave*16 + l15;
        bf16x8 kf0 = *(const bf16x8*)&kb[kr*64 + (((l4    ) ^ (kr & 7)) << 3)];
        bf16x8 kf1 = *(const bf16x8*)&kb[kr*64 + (((l4 + 4) ^ (kr & 7)) << 3)];
        sacc[c] = mfma16(qf0, kf0, sacc[c]);
        sacc[c] = mfma16(qf1, kf1, sacc[c]);
        __syncthreads();
    }
#undef KSTAGE

    // wave's keys for tile tt: tt*128 + wave*16 + l15
    const u16* Tb = T + ((size_t)(b*SS) + q0 + l4*4)*SS + wave*16 + l15;

    // ---- bias + mask + wave-local row-max ----
    int mrow[4];
    #pragma unroll
    for (int r = 0; r < 4; ++r) mrow[r] = mqv[l4*4 + r];

    float mx[4] = {-3e38f, -3e38f, -3e38f, -3e38f};
    #pragma unroll
    for (int tt = 0; tt < 8; ++tt) {
        #pragma unroll
        for (int r = 0; r < 4; ++r) {
            const float bias = bf2f(Tb[(size_t)r*SS + tt*128]);
            float s = sacc[tt][r]*0.125f + bias;
            s = mrow[r] ? s : -1e9f;
            sacc[tt][r] = s;
            mx[r] = fmaxf(mx[r], s);
        }
    }
    #pragma unroll
    for (int r = 0; r < 4; ++r)
        #pragma unroll
        for (int xm = 1; xm < 16; xm <<= 1) mx[r] = fmaxf(mx[r], __shfl_xor(mx[r], xm));
    if (l15 == 0) {
        #pragma unroll
        for (int r = 0; r < 4; ++r) redA[wave][l4*4 + r] = mx[r];
    }
    __syncthreads();

    float mxa[4];
    #pragma unroll
    for (int r = 0; r < 4; ++r) {
        const int row = l4*4 + r;
        float m = redA[0][row];
        #pragma unroll
        for (int w = 1; w < 8; ++w) m = fmaxf(m, redA[w][row]);
        mxa[r] = m;
    }

    // ---- exp in regs + row-sum ----
    float sum[4] = {0.f, 0.f, 0.f, 0.f};
    #pragma unroll
    for (int tt = 0; tt < 8; ++tt)
        #pragma unroll
        for (int r = 0; r < 4; ++r) {
            const float p = __expf(sacc[tt][r] - mxa[r]);
            sacc[tt][r] = p;
            sum[r] += p;
        }
    #pragma unroll
    for (int r = 0; r < 4; ++r)
        #pragma unroll
        for (int xm = 1; xm < 16; xm <<= 1) sum[r] += __shfl_xor(sum[r], xm);
    if (l15 == 0) {
        #pragma unroll
        for (int r = 0; r < 4; ++r) redB[wave][l4*4 + r] = sum[r];
    }
    __syncthreads();

    // row inverse sums
    float inv4[4];
    #pragma unroll
    for (int r = 0; r < 4; ++r) {
        const int row = l4*4 + r;
        float s8 = 0.f;
        #pragma unroll
        for (int w = 0; w < 8; ++w) s8 += redB[w][row];
        inv4[r] = 1.f / s8;
    }
    const int wrow = t >> 5;              // attn-write row (16 rows, 32 threads each)
    const int wcl  = t & 31;
    float wiv;
    {
        float s8 = 0.f;
        #pragma unroll
        for (int w = 0; w < 8; ++w) s8 += redB[w][wrow];
        wiv = 1.f / s8;
    }
    float* gRow = attnOut + ((size_t)(b*HH + h))*SS*SS + (size_t)(q0 + wrow)*SS;

    const u16* Vsrc = Vt + ((size_t)(h*HDD))*MTOT + b*SS;
    u16* vslab = &kv[0][0];               // 32 KB, K data dead
    f32x4 pv[4];
    #pragma unroll
    for (int nt = 0; nt < 4; ++nt) pv[nt] = (f32x4){0.f,0.f,0.f,0.f};

    // ================= two K-half phases; phase ph = keys [ph*512, ph*512+512) ==========
    #pragma unroll
    for (int ph = 0; ph < 2; ++ph) {
        // store sacc[4ph..4ph+4): slot = t2*128 + wave*16 + l15 (contiguous key block)
        #pragma unroll
        for (int t2 = 0; t2 < 4; ++t2) {
            const int slot = t2*128 + wave*16 + l15;
            const int c = slot >> 2, jj = slot & 3;
            #pragma unroll
            for (int r = 0; r < 4; ++r) {
                const int row = l4*4 + r;
                P[row*512 + ((c ^ (row & 7)) << 2) + jj] = sacc[4*ph + t2][r];
            }
        }
        __syncthreads();

        // stream attn (normalized): 2KB contiguous per row per phase
        #pragma unroll
        for (int i = 0; i < 4; ++i) {
            const int c = wcl + i*32;
            f32x4 v = *(f32x4*)&P[wrow*512 + ((c ^ (wrow & 7)) << 2)];
            v *= wiv;
            *(f32x4*)&gRow[ph*512 + c*4] = v;
        }

        // PV via two 256-key V slabs staged in LDS
        #pragma unroll
        for (int p = 0; p < 2; ++p) {
            #pragma unroll
            for (int it_ = 0; it_ < 4; ++it_) {
                const int idx_ = it_*512 + t;
                const int row_ = idx_ >> 5;
                const int ch_  = (idx_ & 31) ^ (row_ & 7);
                gload16(Vsrc + (size_t)row_*MTOT + ph*512 + p*256 + ch_*8,
                        &vslab[idx_*8]);
            }
            __syncthreads();

            // A fragment (P): k-block = (l4>>1)*128 + wave*16 + (l4&1)*8 within slab
            const int c0 = p*64 + (l4 >> 1)*32 + wave*4 + (l4 & 1)*2;
            f32x4 a0 = *(f32x4*)&P[l15*512 + (((c0    ) ^ (l15 & 7)) << 2)];
            f32x4 a1 = *(f32x4*)&P[l15*512 + (((c0 + 1) ^ (l15 & 7)) << 2)];
            bf16x8 af;
            af[0] = (__bf16)a0[0]; af[1] = (__bf16)a0[1]; af[2] = (__bf16)a0[2]; af[3] = (__bf16)a0[3];
            af[4] = (__bf16)a1[0]; af[5] = (__bf16)a1[1]; af[6] = (__bf16)a1[2]; af[7] = (__bf16)a1[3];
            const int kch = (l4 >> 1)*16 + wave*2 + (l4 & 1);   // same k-block for B
            #pragma unroll
            for (int nt = 0; nt < 4; ++nt) {
                const int vrow = nt*16 + l15;
                bf16x8 bf = *(const bf16x8*)&vslab[vrow*256 + ((kch ^ (vrow & 7)) << 3)];
                pv[nt] = mfma16(af, bf, pv[nt]);
            }
            __syncthreads();
        }
    }

    // ---- cross-wave reduce through LDS (alias P = 8192 floats), scaled by 1/sum ----
    float* pw = P + wave*1024;
    #pragma unroll
    for (int nt = 0; nt < 4; ++nt)
        #pragma unroll
        for (int r = 0; r < 4; ++r)
            pw[(l4*4 + r)*64 + nt*16 + l15] = pv[nt][r] * inv4[r];
    __syncthreads();

    {
        const int q = t >> 5, d0 = (t & 31)*2;
        float sx = 0.f, sy = 0.f;
        #pragma unroll
        for (int w = 0; w < 8; ++w) {
            float2 v = *(float2*)&P[w*1024 + q*64 + d0];
            sx += v.x; sy += v.y;
        }
        const size_t off = ((size_t)(b*SS + q0 + q))*DD + h*HDD + d0;
        const unsigned short h0 = f2bf(sx), h1 = f2bf(sy);
        ushort2 hh = {h0, h1};
        ushort2 ll = {f2bf(sx - bf2f(h0)), f2bf(sy - bf2f(h1))};
        *(ushort2*)&attH[off] = hh;
        *(ushort2*)&attL[off] = ll;
    }
}

extern "C" void kernel_launch(void* const* d_in, const int* in_sizes, int n_in,
                              void* d_out, int out_size, void* d_ws, size_t ws_size,
                              hipStream_t stream) {
    const float* x     = (const float*)d_in[0];
    const float* trust = (const float*)d_in[1];
    const int*   mask  = (const int*)  d_in[2];
    const float* Wq    = (const float*)d_in[3];
    const float* bq    = (const float*)d_in[4];
    const float* Wk    = (const float*)d_in[5];
    const float* bk    = (const float*)d_in[6];
    const float* Wv    = (const float*)d_in[7];
    const float* bv    = (const float*)d_in[8];
    const float* Wtp   = (const float*)d_in[9];
    const float* btp   = (const float*)d_in[10];
    const float* Wg    = (const float*)d_in[11];
    const float* bg    = (const float*)d_in[12];
    const float* Wo    = (const float*)d_in[13];
    const float* bo    = (const float*)d_in[14];

    float* out     = (float*)d_out;
    float* attnOut = out + (size_t)MTOT * DD;

    char* ws = (char*)d_ws;
    u16* xh    = (u16*)(ws + (size_t)0*MB);    // 8 MB -> attH later
    u16* xl    = (u16*)(ws + (size_t)8*MB);    // 8 MB -> attL later
    u16* WqkTh = (u16*)(ws + (size_t)16*MB);   // 4 MB: Wq^T rows 0-1023, Wk^T rows 1024-2047
    u16* WvTh  = (u16*)(ws + (size_t)20*MB);
    u16* WgTh  = (u16*)(ws + (size_t)22*MB);
    u16* WoTh  = (u16*)(ws + (size_t)24*MB);
    u16* WoTl  = (u16*)(ws + (size_t)26*MB);
    u16* QKbf  = (u16*)(ws + (size_t)28*MB);   // 16 MB [4096][2048] -> Gh/Gl later
    u16* Vt    = (u16*)(ws + (size_t)44*MB);   // 8 MB
    u16* Tb    = (u16*)(ws + (size_t)52*MB);   // 8 MB bf16 trust-bias table
    float* tconst = (float*)(ws + (size_t)60*MB);
    float* bqk    = (float*)(ws + (size_t)60*MB + 4096);  // 2048 floats
    u16* attH = xh;
    u16* attL = xl;
    u16* Gh   = (u16*)(ws + (size_t)28*MB);
    u16* Gl   = (u16*)(ws + (size_t)36*MB);

    const dim3 blk(256);

    tconst_kernel<<<1, 64, 0, stream>>>(Wtp, btp, tconst);
    tbias_kernel<<<dim3(SS, BB), blk, 0, stream>>>(trust, tconst, Tb);
    split_kernel<<<2048, blk, 0, stream>>>(x, xh, xl, MTOT*DD/4);
    tsplit5_kernel<<<dim3(16, 16, 5), blk, 0, stream>>>(
        Wq, WqkTh, Wk, WqkTh + (size_t)1024*1024, Wv, WvTh, Wg, WgTh, Wo, WoTh, WoTl);
    hipMemcpyAsync(bqk,        bq, 1024*sizeof(float), hipMemcpyDeviceToDevice, stream);
    hipMemcpyAsync(bqk + 1024, bk, 1024*sizeof(float), hipMemcpyDeviceToDevice, stream);

    // fused Q+K: C[m][0..2048) = x @ [Wq | Wk]  (2-pass, bf16 out)
    mgemm<2,2><<<dim3(QKS/128, MTOT/128), blk, 0, stream>>>(
        xh, xl, WqkTh, nullptr, bqk, nullptr, QKbf, nullptr, MTOT, QKS,
        nullptr, nullptr, nullptr, nullptr);
    // V^T: 1-pass, C[d_glob][m] = WvT @ x^T (bias by row)
    mgemm<3,1><<<dim3(MTOT/128, DD/128), blk, 0, stream>>>(
        WvTh, nullptr, xh, nullptr, bv, nullptr, Vt, nullptr, DD, MTOT,
        nullptr, nullptr, nullptr, nullptr);

    attn_kernel<<<dim3(4096), dim3(512), 0, stream>>>(
        QKbf, Vt, Tb, mask, attnOut, attH, attL);

    // gate: 1-pass; gated = attended * sigmoid(attended@Wg[0:1024] + bg + trust*wlast)
    mgemm<1,1><<<dim3(DD/128, MTOT/128), blk, 0, stream>>>(
        attH, nullptr, WgTh, nullptr, bg, nullptr, Gh, Gl, MTOT, DD,
        trust, Wg + (size_t)DD*DD, attH, attL);
    // out = gated @ Wo + bo (fp32, 3-pass)
    mgemm<0,3><<<dim3(DD/128, MTOT/128), blk, 0, stream>>>(
        Gh, Gl, WoTh, WoTl, bo, out, nullptr, nullptr, MTOT, DD,
        nullptr, nullptr, nullptr, nullptr);
}

// Round 13
// 247.377 us; speedup vs baseline: 1.5112x; 1.0953x over previous
//
#include <hip/hip_runtime.h>
#include <math.h>

#define BB 4
#define SS 1024
#define DD 1024
#define HH 16
#define HDD 64
#define MTOT (BB*SS)   // 4096
#define MB (1024*1024)

typedef float  f32x4  __attribute__((ext_vector_type(4)));
typedef __bf16 bf16x8 __attribute__((ext_vector_type(8)));
typedef unsigned short u16;

__device__ __forceinline__ unsigned short f2bf(float f) {
    union { float f; unsigned u; } v; v.f = f;
    unsigned r = v.u + 0x7FFFu + ((v.u >> 16) & 1u);
    return (unsigned short)(r >> 16);
}
__device__ __forceinline__ float bf2f(unsigned short u) {
    union { unsigned u; float f; } v; v.u = ((unsigned)u) << 16;
    return v.f;
}
__device__ __forceinline__ f32x4 mfma16(bf16x8 a, bf16x8 b, f32x4 c) {
    return __builtin_amdgcn_mfma_f32_16x16x32_bf16(a, b, c, 0, 0, 0);
}
__device__ __forceinline__ void gload16(const void* g, void* l) {
    __builtin_amdgcn_global_load_lds(
        (const __attribute__((address_space(1))) void*)g,
        (__attribute__((address_space(3))) void*)l, 16, 0, 0);
}
__device__ __forceinline__ void lds_fence() {
    asm volatile("s_waitcnt lgkmcnt(0)" ::: "memory");
    __builtin_amdgcn_sched_barrier(0);
}

// ---------------- split: fp32 -> bf16 hi/lo ----------------
__global__ void split_kernel(const float* __restrict__ in, u16* __restrict__ hi,
                             u16* __restrict__ lo, int n4)
{
    for (int i = blockIdx.x*blockDim.x + threadIdx.x; i < n4; i += gridDim.x*blockDim.x) {
        f32x4 v = ((const f32x4*)in)[i];
        ushort4 h4, l4;
        h4.x = f2bf(v[0]); l4.x = f2bf(v[0] - bf2f(h4.x));
        h4.y = f2bf(v[1]); l4.y = f2bf(v[1] - bf2f(h4.y));
        h4.z = f2bf(v[2]); l4.z = f2bf(v[2] - bf2f(h4.z));
        h4.w = f2bf(v[3]); l4.w = f2bf(v[3] - bf2f(h4.w));
        ((ushort4*)hi)[i] = h4; ((ushort4*)lo)[i] = l4;
    }
}

// ------- fused transpose+split for all 5 weights: W[k][n] -> WT hi (+opt lo) [n][k] -------
__global__ __launch_bounds__(256)
void tsplit5_kernel(const float* W0, u16* h0,
                    const float* W1, u16* h1,
                    const float* W2, u16* h2,
                    const float* W3, u16* h3,
                    const float* W4, u16* h4, u16* l4T)
{
    const float* W; u16* hT; u16* lT = nullptr;
    switch (blockIdx.z) {
        case 0: W = W0; hT = h0; break;
        case 1: W = W1; hT = h1; break;
        case 2: W = W2; hT = h2; break;
        case 3: W = W3; hT = h3; break;
        default: W = W4; hT = h4; lT = l4T; break;
    }
    __shared__ float tile[64][65];
    const int t  = threadIdx.x;
    const int k0 = blockIdx.y * 64, n0 = blockIdx.x * 64;
    const int r  = t >> 4, c4 = (t & 15) * 4;
    #pragma unroll
    for (int rr = 0; rr < 4; ++rr) {
        const int k = r + rr*16;
        f32x4 v = *(const f32x4*)&W[(size_t)(k0 + k)*1024 + n0 + c4];
        tile[k][c4+0] = v[0]; tile[k][c4+1] = v[1]; tile[k][c4+2] = v[2]; tile[k][c4+3] = v[3];
    }
    __syncthreads();
    #pragma unroll
    for (int rr = 0; rr < 4; ++rr) {
        const int nl = r + rr*16;
        ushort4 hh, ll;
        {
            float v;
            v = tile[c4+0][nl]; hh.x = f2bf(v); ll.x = f2bf(v - bf2f(hh.x));
            v = tile[c4+1][nl]; hh.y = f2bf(v); ll.y = f2bf(v - bf2f(hh.y));
            v = tile[c4+2][nl]; hh.z = f2bf(v); ll.z = f2bf(v - bf2f(hh.z));
            v = tile[c4+3][nl]; hh.w = f2bf(v); ll.w = f2bf(v - bf2f(hh.w));
        }
        *(ushort4*)&hT[(size_t)(n0 + nl)*1024 + k0 + c4] = hh;
        if (lT) *(ushort4*)&lT[(size_t)(n0 + nl)*1024 + k0 + c4] = ll;
    }
}

// ---------------- trust-affinity rank-1 constants ----------------
__global__ void tconst_kernel(const float* __restrict__ Wtp, const float* __restrict__ btp,
                              float* __restrict__ out3)
{
    const int l = threadIdx.x;   // 64 threads
    const float w = Wtp[l], b = btp[l];
    float a = w*w, m = w*b, c = b*b;
    #pragma unroll
    for (int s = 32; s; s >>= 1) {
        a += __shfl_down(a, s);
        m += __shfl_down(m, s);
        c += __shfl_down(c, s);
    }
    if (l == 0) { out3[0] = a; out3[1] = m; out3[2] = c; }
}

// ---------------- trust bias table: T[b][q][k] = bf16(0.1*sigmoid(ta)) ----------------
__global__ __launch_bounds__(256)
void tbias_kernel(const float* __restrict__ trust, const float* __restrict__ tconst,
                  u16* __restrict__ T)
{
    const int b = blockIdx.y;
    const int q = blockIdx.x;
    const float tq = trust[b*SS + q];
    const float c1 = tconst[0], c2 = tconst[1], c3 = tconst[2];
    const int k0 = threadIdx.x * 4;
    f32x4 tk = *(const f32x4*)&trust[b*SS + k0];
    ushort4 o;
    #pragma unroll
    for (int j = 0; j < 4; ++j) {
        const float ta = c1*tq*tk[j] + c2*(tq + tk[j]) + c3;
        const float v  = 0.1f/(1.f + __expf(-ta));
        ((u16*)&o)[j] = f2bf(v);
    }
    *(ushort4*)&T[((size_t)b*SS + q)*SS + k0] = o;
}

// ---------------- split-bf16 MFMA GEMM ----------------
// PASSES=3: AhBh + AhBl + AlBh ; PASSES=2: AhBh + AlBh ; PASSES=1: AhBh
// MODE 0: fp32 + bias[n].  MODE 1: gate fusion.  MODE 2: bf16 + bias[n].
// MODE 4: K fragment-major (Kf) + bias[n].  MODE 5: V fragment-major (Vf) + bias[m].
template<int MODE, int PASSES>
__global__ __launch_bounds__(256)
void mgemm(const u16* __restrict__ Ah, const u16* __restrict__ Al,
           const u16* __restrict__ Bh, const u16* __restrict__ Bl,
           const float* __restrict__ bias,
           float* __restrict__ outF, u16* __restrict__ outH, u16* __restrict__ outL,
           int M, int N,
           const float* __restrict__ trust, const float* __restrict__ wlast,
           const u16* __restrict__ attH, const u16* __restrict__ attL)
{
    constexpr int NT   = (PASSES == 3) ? 4 : (PASSES == 2) ? 3 : 2;
    constexpr int BIDX = (PASSES == 1) ? 1 : 2;
    __shared__ u16 lds[2][NT][128*64];

    const int t    = threadIdx.x;
    const int lane = t & 63, wave = t >> 6;
    const int l15  = lane & 15, l4 = lane >> 4;
    const int wr   = wave >> 1, wc = wave & 1;
    const int w64  = wave << 6;
    const int m0   = blockIdx.y * 128, n0 = blockIdx.x * 128;

    const u16* srcs[NT];
    srcs[0] = Ah + (size_t)m0*1024;
    if (PASSES >= 2) srcs[1] = Al + (size_t)m0*1024;
    srcs[BIDX] = Bh + (size_t)n0*1024;
    if (PASSES == 3) srcs[3] = Bl + (size_t)n0*1024;

    f32x4 acc[4][4];
    #pragma unroll
    for (int i = 0; i < 4; ++i)
        #pragma unroll
        for (int j = 0; j < 4; ++j) acc[i][j] = (f32x4){0.f,0.f,0.f,0.f};

#define STAGE(BUF, KOFF) do {                                                  \
    _Pragma("unroll")                                                          \
    for (int tl_ = 0; tl_ < NT; ++tl_) {                                       \
        _Pragma("unroll")                                                      \
        for (int it_ = 0; it_ < 4; ++it_) {                                    \
            const int idx_ = it_*256 + t;                                      \
            const int row_ = idx_ >> 3;                                        \
            const int c_   = (idx_ & 7) ^ (row_ & 7);                          \
            gload16(srcs[tl_] + (KOFF) + (size_t)row_*1024 + c_*8,             \
                    &lds[BUF][tl_][(it_*256 + w64)*8]);                        \
        }                                                                      \
    }                                                                          \
} while(0)

#define COMPUTE(BUF) do {                                                      \
    _Pragma("unroll")                                                          \
    for (int kk_ = 0; kk_ < 2; ++kk_) {                                        \
        const int cb_ = (kk_<<2) + l4;                                         \
        bf16x8 ah_[4], al_[4];                                                 \
        _Pragma("unroll")                                                      \
        for (int i_ = 0; i_ < 4; ++i_) {                                       \
            const int row_ = (wr<<6) + (i_<<4) + l15;                          \
            const int off_ = (row_<<6) + ((cb_ ^ (row_&7)) << 3);              \
            ah_[i_] = *(const bf16x8*)&lds[BUF][0][off_];                      \
            if (PASSES >= 2) al_[i_] = *(const bf16x8*)&lds[BUF][1][off_];     \
        }                                                                      \
        _Pragma("unroll")                                                      \
        for (int j_ = 0; j_ < 4; ++j_) {                                       \
            const int row_ = (wc<<6) + (j_<<4) + l15;                          \
            const int off_ = (row_<<6) + ((cb_ ^ (row_&7)) << 3);              \
            bf16x8 bh_ = *(const bf16x8*)&lds[BUF][BIDX][off_];                \
            bf16x8 bl_;                                                        \
            if (PASSES == 3) bl_ = *(const bf16x8*)&lds[BUF][3][off_];         \
            _Pragma("unroll")                                                  \
            for (int i_ = 0; i_ < 4; ++i_) {                                   \
                acc[i_][j_] = mfma16(ah_[i_], bh_, acc[i_][j_]);               \
                if (PASSES == 3) acc[i_][j_] = mfma16(ah_[i_], bl_, acc[i_][j_]); \
                if (PASSES >= 2) acc[i_][j_] = mfma16(al_[i_], bh_, acc[i_][j_]); \
            }                                                                  \
        }                                                                      \
    }                                                                          \
} while(0)

    STAGE(0, 0);
    __syncthreads();
    int cur = 0;
    for (int s = 0; s < 15; ++s) {
        if (cur == 0) STAGE(1, (s+1)*64);
        else          STAGE(0, (s+1)*64);
        COMPUTE(cur);
        __syncthreads();
        cur ^= 1;
    }
    COMPUTE(cur);
#undef STAGE
#undef COMPUTE

    // ---- epilogue ----
    #pragma unroll
    for (int i = 0; i < 4; ++i)
        #pragma unroll
        for (int j = 0; j < 4; ++j)
            #pragma unroll
            for (int r = 0; r < 4; ++r) {
                const int m = m0 + (wr<<6) + (i<<4) + (l4<<2) + r;
                const int n = n0 + (wc<<6) + (j<<4) + l15;
                const float v = acc[i][j][r];
                if (MODE == 0) {
                    outF[(size_t)m*N + n] = v + bias[n];
                } else if (MODE == 2) {
                    outH[(size_t)m*N + n] = f2bf(v + bias[n]);
                } else if (MODE == 4) {
                    // Kf fragment-major: m = key, n = d_glob = h*64+d
                    const size_t blk = (((size_t)((m >> 10)*16 + (n >> 6)))*64
                                        + ((m >> 4) & 63))*1024;
                    outH[blk + ((n & 63) >> 3)*128 + (m & 15)*8 + (n & 7)]
                        = f2bf(v + bias[n]);
                } else if (MODE == 5) {
                    // Vf fragment-major: m = d_glob, n = key
                    const size_t blk = ((((size_t)((n >> 10)*16 + (m >> 6)))*32
                                        + ((n & 1023) >> 5))*4 + ((m & 63) >> 4))*512;
                    outH[blk + ((n & 31) >> 3)*128 + (m & 15)*8 + (n & 7)]
                        = f2bf(v + bias[m]);
                } else { // MODE 1: gate fusion
                    const float pre = v + bias[n] + trust[m]*wlast[n];
                    const float g = 1.f/(1.f + __expf(-pre));
                    const float att = bf2f(attH[(size_t)m*N + n]) + bf2f(attL[(size_t)m*N + n]);
                    const float gated = att*g;
                    const unsigned short hb = f2bf(gated);
                    outH[(size_t)m*N + n] = hb;
                    outL[(size_t)m*N + n] = f2bf(gated - bf2f(hb));
                }
            }
}

// ---------------- Attention v10: fragment-major K/V, 3 block barriers ----------------
// Kf/Vf pre-packed so every fragment load is 64 lanes x 16B = 1KB contiguous (16 lines,
// the minimum) -- no K/V LDS staging, no staging barriers. Wave w owns contiguous keys
// [w*128, w*128+128); P transposes through a wave-PRIVATE padded strip [16][68]
// (wave-local lgkmcnt fences, no s_barrier). Barriers: 2 softmax merge + 1 O-reduce.
__global__ __launch_bounds__(512, 4)
void attn_kernel(const u16* __restrict__ Qb, const u16* __restrict__ Kf,
                 const u16* __restrict__ Vf, const u16* __restrict__ T,
                 const int* __restrict__ mask,
                 float* __restrict__ attnOut, u16* __restrict__ attH, u16* __restrict__ attL)
{
    __shared__ float Pw[8][16*68 + 16];   // 8 wave-private strips (also O-reduce alias)
    __shared__ float redA[8][16];
    __shared__ float redB[8][16];

    const int t    = threadIdx.x;
    const int lane = t & 63, wave = t >> 6;     // 8 waves
    const int l15  = lane & 15, l4 = lane >> 4;

    // panel swizzle: all 64 q-blocks of panel P=(b,h) in one XCD window
    const int bid  = blockIdx.x;
    const int xcd  = bid & 7;
    const int idx0 = bid >> 3;
    const int q0   = (idx0 & 63) * 16;
    const int Pn   = ((idx0 >> 6) << 3) + xcd;
    const int h    = Pn & 15;
    const int b    = Pn >> 4;

    float* myP = Pw[wave];

    int mrow[4];
    #pragma unroll
    for (int r = 0; r < 4; ++r) mrow[r] = mask[b*SS + q0 + l4*4 + r];

    const u16* Qp = Qb + ((size_t)(b*SS + q0 + l15))*DD + h*HDD + l4*8;
    bf16x8 qf0 = *(const bf16x8*)Qp;
    bf16x8 qf1 = *(const bf16x8*)(Qp + 32);

    // ---- QK^T: wave's keys w*128 + tt*16 + l15, fragments straight from Kf ----
    f32x4 sacc[8];
    #pragma unroll
    for (int tt = 0; tt < 8; ++tt) sacc[tt] = (f32x4){0.f,0.f,0.f,0.f};

    const u16* Kbase = Kf + (((size_t)(b*16 + h))*64 + wave*8)*1024 + l4*128 + l15*8;
    #pragma unroll
    for (int tt = 0; tt < 8; ++tt) {
        bf16x8 kf0 = *(const bf16x8*)(Kbase + tt*1024);
        bf16x8 kf1 = *(const bf16x8*)(Kbase + tt*1024 + 512);
        sacc[tt] = mfma16(qf0, kf0, sacc[tt]);
        sacc[tt] = mfma16(qf1, kf1, sacc[tt]);
    }

    // ---- bias + mask + wave-local row-max ----
    const u16* Tb = T + ((size_t)b*SS + q0 + l4*4)*SS + wave*128 + l15;
    float mx[4] = {-3e38f, -3e38f, -3e38f, -3e38f};
    #pragma unroll
    for (int tt = 0; tt < 8; ++tt) {
        #pragma unroll
        for (int r = 0; r < 4; ++r) {
            const float bias = bf2f(Tb[(size_t)r*SS + tt*16]);
            float s = sacc[tt][r]*0.125f + bias;
            s = mrow[r] ? s : -1e9f;
            sacc[tt][r] = s;
            mx[r] = fmaxf(mx[r], s);
        }
    }
    #pragma unroll
    for (int r = 0; r < 4; ++r)
        #pragma unroll
        for (int xm = 1; xm < 16; xm <<= 1) mx[r] = fmaxf(mx[r], __shfl_xor(mx[r], xm));
    if (l15 == 0) {
        #pragma unroll
        for (int r = 0; r < 4; ++r) redA[wave][l4*4 + r] = mx[r];
    }
    __syncthreads();                                   // barrier 1

    float mxa[4];
    #pragma unroll
    for (int r = 0; r < 4; ++r) {
        const int row = l4*4 + r;
        float m = redA[0][row];
        #pragma unroll
        for (int w = 1; w < 8; ++w) m = fmaxf(m, redA[w][row]);
        mxa[r] = m;
    }

    // ---- exp in regs + row-sum ----
    float sum[4] = {0.f, 0.f, 0.f, 0.f};
    #pragma unroll
    for (int tt = 0; tt < 8; ++tt)
        #pragma unroll
        for (int r = 0; r < 4; ++r) {
            const float p = __expf(sacc[tt][r] - mxa[r]);
            sacc[tt][r] = p;
            sum[r] += p;
        }
    #pragma unroll
    for (int r = 0; r < 4; ++r)
        #pragma unroll
        for (int xm = 1; xm < 16; xm <<= 1) sum[r] += __shfl_xor(sum[r], xm);
    if (l15 == 0) {
        #pragma unroll
        for (int r = 0; r < 4; ++r) redB[wave][l4*4 + r] = sum[r];
    }
    __syncthreads();                                   // barrier 2

    float inv4[4];                                     // PV rows (l4*4+r)
    #pragma unroll
    for (int r = 0; r < 4; ++r) {
        const int row = l4*4 + r;
        float s8 = 0.f;
        #pragma unroll
        for (int w = 0; w < 8; ++w) s8 += redB[w][row];
        inv4[r] = 1.f / s8;
    }
    float wiv4[4];                                     // write rows (it*4 + l4)
    #pragma unroll
    for (int it = 0; it < 4; ++it) {
        const int row = it*4 + l4;
        float s8 = 0.f;
        #pragma unroll
        for (int w = 0; w < 8; ++w) s8 += redB[w][row];
        wiv4[it] = 1.f / s8;
    }

    float* gBase = attnOut + (((size_t)(b*HH + h))*SS + q0)*SS + wave*128;
    f32x4 pv[4];
    #pragma unroll
    for (int nt = 0; nt < 4; ++nt) pv[nt] = (f32x4){0.f,0.f,0.f,0.f};

    // ---- two wave-private halves: store P -> write attn -> PV, no s_barrier ----
    #pragma unroll
    for (int half = 0; half < 2; ++half) {
        #pragma unroll
        for (int t2 = 0; t2 < 4; ++t2)
            #pragma unroll
            for (int r = 0; r < 4; ++r)
                myP[(l4*4 + r)*68 + t2*16 + l15] = sacc[half*4 + t2][r];
        lds_fence();

        // attn write: rows it*4+l4, cols (lane&15)*4 -> aligned 64B full-line runs
        #pragma unroll
        for (int it = 0; it < 4; ++it) {
            const int row = it*4 + l4;
            f32x4 v = *(f32x4*)&myP[row*68 + l15*4];
            v *= wiv4[it];
            *(f32x4*)&gBase[(size_t)row*SS + half*64 + l15*4] = v;
        }

        // PV over this half's 64 keys (2 k-groups of 32)
        #pragma unroll
        for (int kg = 0; kg < 2; ++kg) {
            const int c0 = kg*32 + l4*8;
            f32x4 a0 = *(f32x4*)&myP[l15*68 + c0];
            f32x4 a1 = *(f32x4*)&myP[l15*68 + c0 + 4];
            bf16x8 af;
            af[0] = (__bf16)a0[0]; af[1] = (__bf16)a0[1]; af[2] = (__bf16)a0[2]; af[3] = (__bf16)a0[3];
            af[4] = (__bf16)a1[0]; af[5] = (__bf16)a1[1]; af[6] = (__bf16)a1[2]; af[7] = (__bf16)a1[3];
            const int kc = wave*4 + half*2 + kg;
            const u16* Vp = Vf + (((size_t)(b*16 + h))*32 + kc)*2048 + l4*128 + l15*8;
            #pragma unroll
            for (int nt = 0; nt < 4; ++nt) {
                bf16x8 bf = *(const bf16x8*)(Vp + nt*512);
                pv[nt] = mfma16(af, bf, pv[nt]);
            }
        }
        lds_fence();   // PV reads retired before next half / O-reduce overwrite
    }

    // ---- cross-wave O reduce (alias own strip, flat 1024 floats) ----
    #pragma unroll
    for (int nt = 0; nt < 4; ++nt)
        #pragma unroll
        for (int r = 0; r < 4; ++r)
            myP[(l4*4 + r)*64 + nt*16 + l15] = pv[nt][r] * inv4[r];
    __syncthreads();                                   // barrier 3

    {
        const int q = t >> 5, d0 = (t & 31)*2;
        float sx = 0.f, sy = 0.f;
        #pragma unroll
        for (int w = 0; w < 8; ++w) {
            float2 v = *(float2*)&Pw[w][q*64 + d0];
            sx += v.x; sy += v.y;
        }
        const size_t off = ((size_t)(b*SS + q0 + q))*DD + h*HDD + d0;
        const unsigned short h0 = f2bf(sx), h1 = f2bf(sy);
        ushort2 hh = {h0, h1};
        ushort2 ll = {f2bf(sx - bf2f(h0)), f2bf(sy - bf2f(h1))};
        *(ushort2*)&attH[off] = hh;
        *(ushort2*)&attL[off] = ll;
    }
}

extern "C" void kernel_launch(void* const* d_in, const int* in_sizes, int n_in,
                              void* d_out, int out_size, void* d_ws, size_t ws_size,
                              hipStream_t stream) {
    const float* x     = (const float*)d_in[0];
    const float* trust = (const float*)d_in[1];
    const int*   mask  = (const int*)  d_in[2];
    const float* Wq    = (const float*)d_in[3];
    const float* bq    = (const float*)d_in[4];
    const float* Wk    = (const float*)d_in[5];
    const float* bk    = (const float*)d_in[6];
    const float* Wv    = (const float*)d_in[7];
    const float* bv    = (const float*)d_in[8];
    const float* Wtp   = (const float*)d_in[9];
    const float* btp   = (const float*)d_in[10];
    const float* Wg    = (const float*)d_in[11];
    const float* bg    = (const float*)d_in[12];
    const float* Wo    = (const float*)d_in[13];
    const float* bo    = (const float*)d_in[14];

    float* out     = (float*)d_out;
    float* attnOut = out + (size_t)MTOT * DD;

    char* ws = (char*)d_ws;
    u16* xh   = (u16*)(ws + (size_t)0*MB);    // 8 MB -> attH later
    u16* xl   = (u16*)(ws + (size_t)8*MB);    // 8 MB -> attL later
    u16* WqTh = (u16*)(ws + (size_t)16*MB);
    u16* WkTh = (u16*)(ws + (size_t)18*MB);
    u16* WvTh = (u16*)(ws + (size_t)20*MB);
    u16* WgTh = (u16*)(ws + (size_t)22*MB);
    u16* WoTh = (u16*)(ws + (size_t)24*MB);
    u16* WoTl = (u16*)(ws + (size_t)26*MB);
    u16* Qbf  = (u16*)(ws + (size_t)28*MB);   // 8 MB -> Gh later
    u16* Kfb  = (u16*)(ws + (size_t)36*MB);   // 8 MB fragment-major K -> Gl later
    u16* Vfb  = (u16*)(ws + (size_t)44*MB);   // 8 MB fragment-major V
    u16* Tb   = (u16*)(ws + (size_t)52*MB);   // 8 MB bf16 trust-bias table
    float* tconst = (float*)(ws + (size_t)60*MB);
    u16* attH = xh;
    u16* attL = xl;
    u16* Gh   = Qbf;
    u16* Gl   = Kfb;

    const dim3 blk(256);

    tconst_kernel<<<1, 64, 0, stream>>>(Wtp, btp, tconst);
    tbias_kernel<<<dim3(SS, BB), blk, 0, stream>>>(trust, tconst, Tb);
    split_kernel<<<2048, blk, 0, stream>>>(x, xh, xl, MTOT*DD/4);
    tsplit5_kernel<<<dim3(16, 16, 5), blk, 0, stream>>>(
        Wq, WqTh, Wk, WkTh, Wv, WvTh, Wg, WgTh, Wo, WoTh, WoTl);

    // Q: 2-pass, row-major bf16
    mgemm<2,2><<<dim3(DD/128, MTOT/128), blk, 0, stream>>>(
        xh, xl, WqTh, nullptr, bq, nullptr, Qbf, nullptr, MTOT, DD,
        nullptr, nullptr, nullptr, nullptr);
    // K: 2-pass, fragment-major Kf
    mgemm<4,2><<<dim3(DD/128, MTOT/128), blk, 0, stream>>>(
        xh, xl, WkTh, nullptr, bk, nullptr, Kfb, nullptr, MTOT, DD,
        nullptr, nullptr, nullptr, nullptr);
    // V: 1-pass, fragment-major Vf (C = V^T, bias by m=d_glob)
    mgemm<5,1><<<dim3(MTOT/128, DD/128), blk, 0, stream>>>(
        WvTh, nullptr, xh, nullptr, bv, nullptr, Vfb, nullptr, DD, MTOT,
        nullptr, nullptr, nullptr, nullptr);

    attn_kernel<<<dim3(4096), dim3(512), 0, stream>>>(
        Qbf, Kfb, Vfb, Tb, mask, attnOut, attH, attL);

    // gate: 1-pass; gated = attended * sigmoid(attended@Wg[0:1024] + bg + trust*wlast)
    mgemm<1,1><<<dim3(DD/128, MTOT/128), blk, 0, stream>>>(
        attH, nullptr, WgTh, nullptr, bg, nullptr, Gh, Gl, MTOT, DD,
        trust, Wg + (size_t)DD*DD, attH, attL);
    // out = gated @ Wo + bo (fp32, 3-pass)
    mgemm<0,3><<<dim3(DD/128, MTOT/128), blk, 0, stream>>>(
        Gh, Gl, WoTh, WoTl, bo, out, nullptr, nullptr, MTOT, DD,
        nullptr, nullptr, nullptr, nullptr);
}

// Round 14
// 241.693 us; speedup vs baseline: 1.5467x; 1.0235x over previous
//
#include <hip/hip_runtime.h>
#include <math.h>

#define BB 4
#define SS 1024
#define DD 1024
#define HH 16
#define HDD 64
#define MTOT (BB*SS)   // 4096
#define MB (1024*1024)

typedef float  f32x4  __attribute__((ext_vector_type(4)));
typedef __bf16 bf16x8 __attribute__((ext_vector_type(8)));
typedef unsigned short u16;

__device__ __forceinline__ unsigned short f2bf(float f) {
    union { float f; unsigned u; } v; v.f = f;
    unsigned r = v.u + 0x7FFFu + ((v.u >> 16) & 1u);
    return (unsigned short)(r >> 16);
}
__device__ __forceinline__ float bf2f(unsigned short u) {
    union { unsigned u; float f; } v; v.u = ((unsigned)u) << 16;
    return v.f;
}
__device__ __forceinline__ f32x4 mfma16(bf16x8 a, bf16x8 b, f32x4 c) {
    return __builtin_amdgcn_mfma_f32_16x16x32_bf16(a, b, c, 0, 0, 0);
}
__device__ __forceinline__ void gload16(const void* g, void* l) {
    __builtin_amdgcn_global_load_lds(
        (const __attribute__((address_space(1))) void*)g,
        (__attribute__((address_space(3))) void*)l, 16, 0, 0);
}
__device__ __forceinline__ void lds_fence() {
    asm volatile("s_waitcnt lgkmcnt(0)" ::: "memory");
    __builtin_amdgcn_sched_barrier(0);
}

// ---------------- split: fp32 -> bf16 hi (+optional lo) ----------------
__global__ void split_kernel(const float* __restrict__ in, u16* __restrict__ hi,
                             u16* __restrict__ lo, int n4)
{
    for (int i = blockIdx.x*blockDim.x + threadIdx.x; i < n4; i += gridDim.x*blockDim.x) {
        f32x4 v = ((const f32x4*)in)[i];
        ushort4 h4;
        h4.x = f2bf(v[0]); h4.y = f2bf(v[1]); h4.z = f2bf(v[2]); h4.w = f2bf(v[3]);
        ((ushort4*)hi)[i] = h4;
        if (lo) {
            ushort4 l4v;
            l4v.x = f2bf(v[0] - bf2f(h4.x)); l4v.y = f2bf(v[1] - bf2f(h4.y));
            l4v.z = f2bf(v[2] - bf2f(h4.z)); l4v.w = f2bf(v[3] - bf2f(h4.w));
            ((ushort4*)lo)[i] = l4v;
        }
    }
}

// ------- fused transpose+split for all 5 weights: W[k][n] -> WT hi (+opt lo) [n][k] -------
__global__ __launch_bounds__(256)
void tsplit5_kernel(const float* W0, u16* h0,
                    const float* W1, u16* h1,
                    const float* W2, u16* h2,
                    const float* W3, u16* h3,
                    const float* W4, u16* h4, u16* l4T)
{
    const float* W; u16* hT; u16* lT = nullptr;
    switch (blockIdx.z) {
        case 0: W = W0; hT = h0; break;
        case 1: W = W1; hT = h1; break;
        case 2: W = W2; hT = h2; break;
        case 3: W = W3; hT = h3; break;
        default: W = W4; hT = h4; lT = l4T; break;
    }
    __shared__ float tile[64][65];
    const int t  = threadIdx.x;
    const int k0 = blockIdx.y * 64, n0 = blockIdx.x * 64;
    const int r  = t >> 4, c4 = (t & 15) * 4;
    #pragma unroll
    for (int rr = 0; rr < 4; ++rr) {
        const int k = r + rr*16;
        f32x4 v = *(const f32x4*)&W[(size_t)(k0 + k)*1024 + n0 + c4];
        tile[k][c4+0] = v[0]; tile[k][c4+1] = v[1]; tile[k][c4+2] = v[2]; tile[k][c4+3] = v[3];
    }
    __syncthreads();
    #pragma unroll
    for (int rr = 0; rr < 4; ++rr) {
        const int nl = r + rr*16;
        ushort4 hh, ll;
        {
            float v;
            v = tile[c4+0][nl]; hh.x = f2bf(v); ll.x = f2bf(v - bf2f(hh.x));
            v = tile[c4+1][nl]; hh.y = f2bf(v); ll.y = f2bf(v - bf2f(hh.y));
            v = tile[c4+2][nl]; hh.z = f2bf(v); ll.z = f2bf(v - bf2f(hh.z));
            v = tile[c4+3][nl]; hh.w = f2bf(v); ll.w = f2bf(v - bf2f(hh.w));
        }
        *(ushort4*)&hT[(size_t)(n0 + nl)*1024 + k0 + c4] = hh;
        if (lT) *(ushort4*)&lT[(size_t)(n0 + nl)*1024 + k0 + c4] = ll;
    }
}

// ---------------- trust-affinity rank-1 constants ----------------
__global__ void tconst_kernel(const float* __restrict__ Wtp, const float* __restrict__ btp,
                              float* __restrict__ out3)
{
    const int l = threadIdx.x;   // 64 threads
    const float w = Wtp[l], b = btp[l];
    float a = w*w, m = w*b, c = b*b;
    #pragma unroll
    for (int s = 32; s; s >>= 1) {
        a += __shfl_down(a, s);
        m += __shfl_down(m, s);
        c += __shfl_down(c, s);
    }
    if (l == 0) { out3[0] = a; out3[1] = m; out3[2] = c; }
}

// ---------------- trust bias table, FRAGMENT-MAJOR ----------------
// T2[b][qt][kt][lane*4 + r] = bf16(0.1*sigmoid(ta)) for
// q = qt*16 + (lane>>4)*4 + r, k = kt*16 + (lane&15).
// attn loads one ushort4 per (wave,tt): 64 lanes x 8B = 512B contiguous.
__global__ __launch_bounds__(256)
void tbias_kernel(const float* __restrict__ trust, const float* __restrict__ tconst,
                  u16* __restrict__ T2)
{
    const int qt = blockIdx.x;      // 0..63
    const int b  = blockIdx.y;      // 0..3
    const int t  = threadIdx.x;
    const int lane = t & 63, grp = t >> 6;
    const int l15 = lane & 15, l4 = lane >> 4;
    const float c1 = tconst[0], c2 = tconst[1], c3 = tconst[2];
    float tq[4];
    #pragma unroll
    for (int r = 0; r < 4; ++r) tq[r] = trust[b*SS + qt*16 + l4*4 + r];
    for (int kt2 = 0; kt2 < 16; ++kt2) {
        const int kt = grp*16 + kt2;
        const float tk = trust[b*SS + kt*16 + l15];
        ushort4 o;
        #pragma unroll
        for (int r = 0; r < 4; ++r) {
            const float ta = c1*tq[r]*tk + c2*(tq[r] + tk) + c3;
            ((u16*)&o)[r] = f2bf(0.1f/(1.f + __expf(-ta)));
        }
        *(ushort4*)&T2[((((size_t)b*64 + qt)*64 + kt)*64 + lane)*4] = o;
    }
}

// ---------------- split-bf16 MFMA GEMM ----------------
// PASSES=3: AhBh + AhBl + AlBh ; PASSES=2: AhBh + AlBh ; PASSES=1: AhBh
// MODE 0: fp32 + bias[n].  MODE 1: gate fusion.  MODE 2: bf16 + bias[n].
// MODE 4: K fragment-major + bias[n].  MODE 5: V fragment-major + bias[m].
// MODE 6 (PASSES=1, N=2048): fused Q+K — n<1024: Q row-major (B=Bh, bias);
//                            n>=1024: K fragment-major (B=Bl, bias2=wlast).
template<int MODE, int PASSES>
__global__ __launch_bounds__(256)
void mgemm(const u16* __restrict__ Ah, const u16* __restrict__ Al,
           const u16* __restrict__ Bh, const u16* __restrict__ Bl,
           const float* __restrict__ bias,
           float* __restrict__ outF, u16* __restrict__ outH, u16* __restrict__ outL,
           int M, int N,
           const float* __restrict__ trust, const float* __restrict__ wlast,
           const u16* __restrict__ attH, const u16* __restrict__ attL)
{
    constexpr int NT   = (PASSES == 3) ? 4 : (PASSES == 2) ? 3 : 2;
    constexpr int BIDX = (PASSES == 1) ? 1 : 2;
    __shared__ u16 lds[2][NT][128*64];

    const int t    = threadIdx.x;
    const int lane = t & 63, wave = t >> 6;
    const int l15  = lane & 15, l4 = lane >> 4;
    const int wr   = wave >> 1, wc = wave & 1;
    const int w64  = wave << 6;
    const int m0   = blockIdx.y * 128, n0 = blockIdx.x * 128;

    const u16* srcs[NT];
    srcs[0] = Ah + (size_t)m0*1024;
    if (PASSES >= 2) srcs[1] = Al + (size_t)m0*1024;
    if (MODE == 6) {
        srcs[BIDX] = (n0 < 1024) ? Bh + (size_t)n0*1024
                                 : Bl + (size_t)(n0 - 1024)*1024;
    } else {
        srcs[BIDX] = Bh + (size_t)n0*1024;
    }
    if (PASSES == 3) srcs[3] = Bl + (size_t)n0*1024;

    f32x4 acc[4][4];
    #pragma unroll
    for (int i = 0; i < 4; ++i)
        #pragma unroll
        for (int j = 0; j < 4; ++j) acc[i][j] = (f32x4){0.f,0.f,0.f,0.f};

#define STAGE(BUF, KOFF) do {                                                  \
    _Pragma("unroll")                                                          \
    for (int tl_ = 0; tl_ < NT; ++tl_) {                                       \
        _Pragma("unroll")                                                      \
        for (int it_ = 0; it_ < 4; ++it_) {                                    \
            const int idx_ = it_*256 + t;                                      \
            const int row_ = idx_ >> 3;                                        \
            const int c_   = (idx_ & 7) ^ (row_ & 7);                          \
            gload16(srcs[tl_] + (KOFF) + (size_t)row_*1024 + c_*8,             \
                    &lds[BUF][tl_][(it_*256 + w64)*8]);                        \
        }                                                                      \
    }                                                                          \
} while(0)

#define COMPUTE(BUF) do {                                                      \
    _Pragma("unroll")                                                          \
    for (int kk_ = 0; kk_ < 2; ++kk_) {                                        \
        const int cb_ = (kk_<<2) + l4;                                         \
        bf16x8 ah_[4], al_[4];                                                 \
        _Pragma("unroll")                                                      \
        for (int i_ = 0; i_ < 4; ++i_) {                                       \
            const int row_ = (wr<<6) + (i_<<4) + l15;                          \
            const int off_ = (row_<<6) + ((cb_ ^ (row_&7)) << 3);              \
            ah_[i_] = *(const bf16x8*)&lds[BUF][0][off_];                      \
            if (PASSES >= 2) al_[i_] = *(const bf16x8*)&lds[BUF][1][off_];     \
        }                                                                      \
        _Pragma("unroll")                                                      \
        for (int j_ = 0; j_ < 4; ++j_) {                                       \
            const int row_ = (wc<<6) + (j_<<4) + l15;                          \
            const int off_ = (row_<<6) + ((cb_ ^ (row_&7)) << 3);              \
            bf16x8 bh_ = *(const bf16x8*)&lds[BUF][BIDX][off_];                \
            bf16x8 bl_;                                                        \
            if (PASSES == 3) bl_ = *(const bf16x8*)&lds[BUF][3][off_];         \
            _Pragma("unroll")                                                  \
            for (int i_ = 0; i_ < 4; ++i_) {                                   \
                acc[i_][j_] = mfma16(ah_[i_], bh_, acc[i_][j_]);               \
                if (PASSES == 3) acc[i_][j_] = mfma16(ah_[i_], bl_, acc[i_][j_]); \
                if (PASSES >= 2) acc[i_][j_] = mfma16(al_[i_], bh_, acc[i_][j_]); \
            }                                                                  \
        }                                                                      \
    }                                                                          \
} while(0)

    STAGE(0, 0);
    __syncthreads();
    int cur = 0;
    for (int s = 0; s < 15; ++s) {
        if (cur == 0) STAGE(1, (s+1)*64);
        else          STAGE(0, (s+1)*64);
        COMPUTE(cur);
        __syncthreads();
        cur ^= 1;
    }
    COMPUTE(cur);
#undef STAGE
#undef COMPUTE

    // ---- epilogue ----
    #pragma unroll
    for (int i = 0; i < 4; ++i)
        #pragma unroll
        for (int j = 0; j < 4; ++j)
            #pragma unroll
            for (int r = 0; r < 4; ++r) {
                const int m = m0 + (wr<<6) + (i<<4) + (l4<<2) + r;
                const int n = n0 + (wc<<6) + (j<<4) + l15;
                const float v = acc[i][j][r];
                if (MODE == 0) {
                    outF[(size_t)m*N + n] = v + bias[n];
                } else if (MODE == 2) {
                    outH[(size_t)m*N + n] = f2bf(v + bias[n]);
                } else if (MODE == 4) {
                    const size_t blk = (((size_t)((m >> 10)*16 + (n >> 6)))*64
                                        + ((m >> 4) & 63))*1024;
                    outH[blk + ((n & 63) >> 3)*128 + (m & 15)*8 + (n & 7)]
                        = f2bf(v + bias[n]);
                } else if (MODE == 5) {
                    const size_t blk = ((((size_t)((n >> 10)*16 + (m >> 6)))*32
                                        + ((n & 1023) >> 5))*4 + ((m & 63) >> 4))*512;
                    outH[blk + ((n & 31) >> 3)*128 + (m & 15)*8 + (n & 7)]
                        = f2bf(v + bias[m]);
                } else if (MODE == 6) {
                    if (n0 < 1024) {
                        outH[(size_t)m*1024 + n] = f2bf(v + bias[n]);
                    } else {
                        const int nk = n - 1024;   // d_glob
                        const size_t blk = (((size_t)((m >> 10)*16 + (nk >> 6)))*64
                                            + ((m >> 4) & 63))*1024;
                        outL[blk + ((nk & 63) >> 3)*128 + (m & 15)*8 + (nk & 7)]
                            = f2bf(v + wlast[nk]);
                    }
                } else { // MODE 1: gate fusion
                    const float pre = v + bias[n] + trust[m]*wlast[n];
                    const float g = 1.f/(1.f + __expf(-pre));
                    const float att = bf2f(attH[(size_t)m*N + n]) + bf2f(attL[(size_t)m*N + n]);
                    const float gated = att*g;
                    const unsigned short hb = f2bf(gated);
                    outH[(size_t)m*N + n] = hb;
                    outL[(size_t)m*N + n] = f2bf(gated - bf2f(hb));
                }
            }
}

// ---------------- Attention v11: fragment-major K/V/T, T-reuse XCD swizzle ----------------
// Same structure as v10 (3 block barriers); T now fragment-major (8x ushort4 loads,
// 512B/wave contiguous); swizzle keys b to XCD pairs so the 8 same-(b,q) panels on an
// XCD share the T slice and K/V panels stay L2-resident across the q sweep.
__global__ __launch_bounds__(512, 4)
void attn_kernel(const u16* __restrict__ Qb, const u16* __restrict__ Kf,
                 const u16* __restrict__ Vf, const u16* __restrict__ T,
                 const int* __restrict__ mask,
                 float* __restrict__ attnOut, u16* __restrict__ attH, u16* __restrict__ attL)
{
    __shared__ float Pw[8][16*68 + 16];   // 8 wave-private strips (also O-reduce alias)
    __shared__ float redA[8][16];
    __shared__ float redB[8][16];

    const int t    = threadIdx.x;
    const int lane = t & 63, wave = t >> 6;     // 8 waves
    const int l15  = lane & 15, l4 = lane >> 4;

    // T-reuse swizzle: bid = xcd + 8*(p3 + 8*q6); b = xcd>>1, h = ((xcd&1)<<3)+p3
    const int bid  = blockIdx.x;
    const int xcd  = bid & 7;
    const int idx0 = bid >> 3;
    const int p3   = idx0 & 7;
    const int q6   = idx0 >> 3;        // 0..63
    const int q0   = q6 * 16;
    const int b    = xcd >> 1;
    const int h    = ((xcd & 1) << 3) + p3;

    float* myP = Pw[wave];

    int mrow[4];
    #pragma unroll
    for (int r = 0; r < 4; ++r) mrow[r] = mask[b*SS + q0 + l4*4 + r];

    const u16* Qp = Qb + ((size_t)(b*SS + q0 + l15))*DD + h*HDD + l4*8;
    bf16x8 qf0 = *(const bf16x8*)Qp;
    bf16x8 qf1 = *(const bf16x8*)(Qp + 32);

    // ---- QK^T: wave's keys w*128 + tt*16 + l15, fragments straight from Kf ----
    f32x4 sacc[8];
    #pragma unroll
    for (int tt = 0; tt < 8; ++tt) sacc[tt] = (f32x4){0.f,0.f,0.f,0.f};

    const u16* Kbase = Kf + (((size_t)(b*16 + h))*64 + wave*8)*1024 + l4*128 + l15*8;
    #pragma unroll
    for (int tt = 0; tt < 8; ++tt) {
        bf16x8 kf0 = *(const bf16x8*)(Kbase + tt*1024);
        bf16x8 kf1 = *(const bf16x8*)(Kbase + tt*1024 + 512);
        sacc[tt] = mfma16(qf0, kf0, sacc[tt]);
        sacc[tt] = mfma16(qf1, kf1, sacc[tt]);
    }

    // ---- bias (fragment-major T) + mask + wave-local row-max ----
    const u16* Tb = T + ((((size_t)b*64 + q6)*64 + wave*8)*64 + lane)*4;
    float mx[4] = {-3e38f, -3e38f, -3e38f, -3e38f};
    #pragma unroll
    for (int tt = 0; tt < 8; ++tt) {
        ushort4 t4 = *(const ushort4*)(Tb + (size_t)tt*256);
        #pragma unroll
        for (int r = 0; r < 4; ++r) {
            const float bias = bf2f(((const u16*)&t4)[r]);
            float s = sacc[tt][r]*0.125f + bias;
            s = mrow[r] ? s : -1e9f;
            sacc[tt][r] = s;
            mx[r] = fmaxf(mx[r], s);
        }
    }
    #pragma unroll
    for (int r = 0; r < 4; ++r)
        #pragma unroll
        for (int xm = 1; xm < 16; xm <<= 1) mx[r] = fmaxf(mx[r], __shfl_xor(mx[r], xm));
    if (l15 == 0) {
        #pragma unroll
        for (int r = 0; r < 4; ++r) redA[wave][l4*4 + r] = mx[r];
    }
    __syncthreads();                                   // barrier 1

    float mxa[4];
    #pragma unroll
    for (int r = 0; r < 4; ++r) {
        const int row = l4*4 + r;
        float m = redA[0][row];
        #pragma unroll
        for (int w = 1; w < 8; ++w) m = fmaxf(m, redA[w][row]);
        mxa[r] = m;
    }

    // ---- exp in regs + row-sum ----
    float sum[4] = {0.f, 0.f, 0.f, 0.f};
    #pragma unroll
    for (int tt = 0; tt < 8; ++tt)
        #pragma unroll
        for (int r = 0; r < 4; ++r) {
            const float p = __expf(sacc[tt][r] - mxa[r]);
            sacc[tt][r] = p;
            sum[r] += p;
        }
    #pragma unroll
    for (int r = 0; r < 4; ++r)
        #pragma unroll
        for (int xm = 1; xm < 16; xm <<= 1) sum[r] += __shfl_xor(sum[r], xm);
    if (l15 == 0) {
        #pragma unroll
        for (int r = 0; r < 4; ++r) redB[wave][l4*4 + r] = sum[r];
    }
    __syncthreads();                                   // barrier 2

    float inv4[4];                                     // PV rows (l4*4+r)
    #pragma unroll
    for (int r = 0; r < 4; ++r) {
        const int row = l4*4 + r;
        float s8 = 0.f;
        #pragma unroll
        for (int w = 0; w < 8; ++w) s8 += redB[w][row];
        inv4[r] = 1.f / s8;
    }
    float wiv4[4];                                     // write rows (it*4 + l4)
    #pragma unroll
    for (int it = 0; it < 4; ++it) {
        const int row = it*4 + l4;
        float s8 = 0.f;
        #pragma unroll
        for (int w = 0; w < 8; ++w) s8 += redB[w][row];
        wiv4[it] = 1.f / s8;
    }

    float* gBase = attnOut + (((size_t)(b*HH + h))*SS + q0)*SS + wave*128;
    f32x4 pv[4];
    #pragma unroll
    for (int nt = 0; nt < 4; ++nt) pv[nt] = (f32x4){0.f,0.f,0.f,0.f};

    // ---- two wave-private halves: store P -> write attn -> PV, no s_barrier ----
    #pragma unroll
    for (int half = 0; half < 2; ++half) {
        #pragma unroll
        for (int t2 = 0; t2 < 4; ++t2)
            #pragma unroll
            for (int r = 0; r < 4; ++r)
                myP[(l4*4 + r)*68 + t2*16 + l15] = sacc[half*4 + t2][r];
        lds_fence();

        #pragma unroll
        for (int it = 0; it < 4; ++it) {
            const int row = it*4 + l4;
            f32x4 v = *(f32x4*)&myP[row*68 + l15*4];
            v *= wiv4[it];
            *(f32x4*)&gBase[(size_t)row*SS + half*64 + l15*4] = v;
        }

        #pragma unroll
        for (int kg = 0; kg < 2; ++kg) {
            const int c0 = kg*32 + l4*8;
            f32x4 a0 = *(f32x4*)&myP[l15*68 + c0];
            f32x4 a1 = *(f32x4*)&myP[l15*68 + c0 + 4];
            bf16x8 af;
            af[0] = (__bf16)a0[0]; af[1] = (__bf16)a0[1]; af[2] = (__bf16)a0[2]; af[3] = (__bf16)a0[3];
            af[4] = (__bf16)a1[0]; af[5] = (__bf16)a1[1]; af[6] = (__bf16)a1[2]; af[7] = (__bf16)a1[3];
            const int kc = wave*4 + half*2 + kg;
            const u16* Vp = Vf + (((size_t)(b*16 + h))*32 + kc)*2048 + l4*128 + l15*8;
            #pragma unroll
            for (int nt = 0; nt < 4; ++nt) {
                bf16x8 bf = *(const bf16x8*)(Vp + nt*512);
                pv[nt] = mfma16(af, bf, pv[nt]);
            }
        }
        lds_fence();
    }

    // ---- cross-wave O reduce (alias own strip, flat 1024 floats) ----
    #pragma unroll
    for (int nt = 0; nt < 4; ++nt)
        #pragma unroll
        for (int r = 0; r < 4; ++r)
            myP[(l4*4 + r)*64 + nt*16 + l15] = pv[nt][r] * inv4[r];
    __syncthreads();                                   // barrier 3

    {
        const int q = t >> 5, d0 = (t & 31)*2;
        float sx = 0.f, sy = 0.f;
        #pragma unroll
        for (int w = 0; w < 8; ++w) {
            float2 v = *(float2*)&Pw[w][q*64 + d0];
            sx += v.x; sy += v.y;
        }
        const size_t off = ((size_t)(b*SS + q0 + q))*DD + h*HDD + d0;
        const unsigned short h0 = f2bf(sx), h1 = f2bf(sy);
        ushort2 hh = {h0, h1};
        ushort2 ll = {f2bf(sx - bf2f(h0)), f2bf(sy - bf2f(h1))};
        *(ushort2*)&attH[off] = hh;
        *(ushort2*)&attL[off] = ll;
    }
}

extern "C" void kernel_launch(void* const* d_in, const int* in_sizes, int n_in,
                              void* d_out, int out_size, void* d_ws, size_t ws_size,
                              hipStream_t stream) {
    const float* x     = (const float*)d_in[0];
    const float* trust = (const float*)d_in[1];
    const int*   mask  = (const int*)  d_in[2];
    const float* Wq    = (const float*)d_in[3];
    const float* bq    = (const float*)d_in[4];
    const float* Wk    = (const float*)d_in[5];
    const float* bk    = (const float*)d_in[6];
    const float* Wv    = (const float*)d_in[7];
    const float* bv    = (const float*)d_in[8];
    const float* Wtp   = (const float*)d_in[9];
    const float* btp   = (const float*)d_in[10];
    const float* Wg    = (const float*)d_in[11];
    const float* bg    = (const float*)d_in[12];
    const float* Wo    = (const float*)d_in[13];
    const float* bo    = (const float*)d_in[14];

    float* out     = (float*)d_out;
    float* attnOut = out + (size_t)MTOT * DD;

    char* ws = (char*)d_ws;
    u16* xh   = (u16*)(ws + (size_t)0*MB);    // 8 MB -> attH later
    u16* attL = (u16*)(ws + (size_t)8*MB);    // 8 MB (lo of attended)
    u16* WqTh = (u16*)(ws + (size_t)16*MB);
    u16* WkTh = (u16*)(ws + (size_t)18*MB);
    u16* WvTh = (u16*)(ws + (size_t)20*MB);
    u16* WgTh = (u16*)(ws + (size_t)22*MB);
    u16* WoTh = (u16*)(ws + (size_t)24*MB);
    u16* WoTl = (u16*)(ws + (size_t)26*MB);
    u16* Qbf  = (u16*)(ws + (size_t)28*MB);   // 8 MB -> Gh later
    u16* Kfb  = (u16*)(ws + (size_t)36*MB);   // 8 MB fragment-major K -> Gl later
    u16* Vfb  = (u16*)(ws + (size_t)44*MB);   // 8 MB fragment-major V
    u16* Tb   = (u16*)(ws + (size_t)52*MB);   // 8 MB fragment-major trust-bias table
    float* tconst = (float*)(ws + (size_t)60*MB);
    u16* attH = xh;
    u16* Gh   = Qbf;
    u16* Gl   = Kfb;

    const dim3 blk(256);

    tconst_kernel<<<1, 64, 0, stream>>>(Wtp, btp, tconst);
    tbias_kernel<<<dim3(64, BB), blk, 0, stream>>>(trust, tconst, Tb);
    split_kernel<<<2048, blk, 0, stream>>>(x, xh, nullptr, MTOT*DD/4);
    tsplit5_kernel<<<dim3(16, 16, 5), blk, 0, stream>>>(
        Wq, WqTh, Wk, WkTh, Wv, WvTh, Wg, WgTh, Wo, WoTh, WoTl);

    // fused Q+K: 1-pass, N=2048; n<1024 -> Qbf row-major, n>=1024 -> Kfb fragment-major
    mgemm<6,1><<<dim3(2048/128, MTOT/128), blk, 0, stream>>>(
        xh, nullptr, WqTh, WkTh, bq, nullptr, Qbf, Kfb, MTOT, 2048,
        nullptr, bk, nullptr, nullptr);
    // V: 1-pass, fragment-major Vf (C = V^T, bias by m=d_glob)
    mgemm<5,1><<<dim3(MTOT/128, DD/128), blk, 0, stream>>>(
        WvTh, nullptr, xh, nullptr, bv, nullptr, Vfb, nullptr, DD, MTOT,
        nullptr, nullptr, nullptr, nullptr);

    attn_kernel<<<dim3(4096), dim3(512), 0, stream>>>(
        Qbf, Kfb, Vfb, Tb, mask, attnOut, attH, attL);

    // gate: 1-pass; gated = attended * sigmoid(attended@Wg[0:1024] + bg + trust*wlast)
    mgemm<1,1><<<dim3(DD/128, MTOT/128), blk, 0, stream>>>(
        attH, nullptr, WgTh, nullptr, bg, nullptr, Gh, Gl, MTOT, DD,
        trust, Wg + (size_t)DD*DD, attH, attL);
    // out = gated @ Wo + bo (fp32, 3-pass)
    mgemm<0,3><<<dim3(DD/128, MTOT/128), blk, 0, stream>>>(
        Gh, Gl, WoTh, WoTl, bo, out, nullptr, nullptr, MTOT, DD,
        nullptr, nullptr, nullptr, nullptr);
}

// Round 15
// 233.412 us; speedup vs baseline: 1.6016x; 1.0355x over previous
//
#include <hip/hip_runtime.h>
#include <math.h>

#define BB 4
#define SS 1024
#define DD 1024
#define HH 16
#define HDD 64
#define MTOT (BB*SS)   // 4096
#define MB (1024*1024)

typedef float  f32x4  __attribute__((ext_vector_type(4)));
typedef __bf16 bf16x8 __attribute__((ext_vector_type(8)));
typedef unsigned short u16;

__device__ __forceinline__ unsigned short f2bf(float f) {
    union { float f; unsigned u; } v; v.f = f;
    unsigned r = v.u + 0x7FFFu + ((v.u >> 16) & 1u);
    return (unsigned short)(r >> 16);
}
__device__ __forceinline__ float bf2f(unsigned short u) {
    union { unsigned u; float f; } v; v.u = ((unsigned)u) << 16;
    return v.f;
}
__device__ __forceinline__ f32x4 mfma16(bf16x8 a, bf16x8 b, f32x4 c) {
    return __builtin_amdgcn_mfma_f32_16x16x32_bf16(a, b, c, 0, 0, 0);
}
__device__ __forceinline__ void gload16(const void* g, void* l) {
    __builtin_amdgcn_global_load_lds(
        (const __attribute__((address_space(1))) void*)g,
        (__attribute__((address_space(3))) void*)l, 16, 0, 0);
}
__device__ __forceinline__ void lds_fence() {
    asm volatile("s_waitcnt lgkmcnt(0)" ::: "memory");
    __builtin_amdgcn_sched_barrier(0);
}

// ---------------- split: fp32 -> bf16 hi ----------------
__global__ void split_kernel(const float* __restrict__ in, u16* __restrict__ hi, int n4)
{
    for (int i = blockIdx.x*blockDim.x + threadIdx.x; i < n4; i += gridDim.x*blockDim.x) {
        f32x4 v = ((const f32x4*)in)[i];
        ushort4 h4;
        h4.x = f2bf(v[0]); h4.y = f2bf(v[1]); h4.z = f2bf(v[2]); h4.w = f2bf(v[3]);
        ((ushort4*)hi)[i] = h4;
    }
}

// ------- fused transpose for all 5 weights: W[k][n] fp32 -> WT bf16 [n][k] -------
__global__ __launch_bounds__(256)
void tsplit5_kernel(const float* W0, u16* h0,
                    const float* W1, u16* h1,
                    const float* W2, u16* h2,
                    const float* W3, u16* h3,
                    const float* W4, u16* h4)
{
    const float* W; u16* hT;
    switch (blockIdx.z) {
        case 0: W = W0; hT = h0; break;
        case 1: W = W1; hT = h1; break;
        case 2: W = W2; hT = h2; break;
        case 3: W = W3; hT = h3; break;
        default: W = W4; hT = h4; break;
    }
    __shared__ float tile[64][65];
    const int t  = threadIdx.x;
    const int k0 = blockIdx.y * 64, n0 = blockIdx.x * 64;
    const int r  = t >> 4, c4 = (t & 15) * 4;
    #pragma unroll
    for (int rr = 0; rr < 4; ++rr) {
        const int k = r + rr*16;
        f32x4 v = *(const f32x4*)&W[(size_t)(k0 + k)*1024 + n0 + c4];
        tile[k][c4+0] = v[0]; tile[k][c4+1] = v[1]; tile[k][c4+2] = v[2]; tile[k][c4+3] = v[3];
    }
    __syncthreads();
    #pragma unroll
    for (int rr = 0; rr < 4; ++rr) {
        const int nl = r + rr*16;
        ushort4 hh;
        hh.x = f2bf(tile[c4+0][nl]); hh.y = f2bf(tile[c4+1][nl]);
        hh.z = f2bf(tile[c4+2][nl]); hh.w = f2bf(tile[c4+3][nl]);
        *(ushort4*)&hT[(size_t)(n0 + nl)*1024 + k0 + c4] = hh;
    }
}

// ---------------- trust-affinity rank-1 constants ----------------
__global__ void tconst_kernel(const float* __restrict__ Wtp, const float* __restrict__ btp,
                              float* __restrict__ out3)
{
    const int l = threadIdx.x;   // 64 threads
    const float w = Wtp[l], b = btp[l];
    float a = w*w, m = w*b, c = b*b;
    #pragma unroll
    for (int s = 32; s; s >>= 1) {
        a += __shfl_down(a, s);
        m += __shfl_down(m, s);
        c += __shfl_down(c, s);
    }
    if (l == 0) { out3[0] = a; out3[1] = m; out3[2] = c; }
}

// ---------------- trust bias table, FRAGMENT-MAJOR ----------------
// T2[b][qt][kt][lane*4 + r] = bf16(0.1*sigmoid(ta)) for
// q = qt*16 + (lane>>4)*4 + r, k = kt*16 + (lane&15).
__global__ __launch_bounds__(256)
void tbias_kernel(const float* __restrict__ trust, const float* __restrict__ tconst,
                  u16* __restrict__ T2)
{
    const int qt = blockIdx.x;      // 0..63
    const int b  = blockIdx.y;      // 0..3
    const int t  = threadIdx.x;
    const int lane = t & 63, grp = t >> 6;
    const int l15 = lane & 15, l4 = lane >> 4;
    const float c1 = tconst[0], c2 = tconst[1], c3 = tconst[2];
    float tq[4];
    #pragma unroll
    for (int r = 0; r < 4; ++r) tq[r] = trust[b*SS + qt*16 + l4*4 + r];
    for (int kt2 = 0; kt2 < 16; ++kt2) {
        const int kt = grp*16 + kt2;
        const float tk = trust[b*SS + kt*16 + l15];
        ushort4 o;
        #pragma unroll
        for (int r = 0; r < 4; ++r) {
            const float ta = c1*tq[r]*tk + c2*(tq[r] + tk) + c3;
            ((u16*)&o)[r] = f2bf(0.1f/(1.f + __expf(-ta)));
        }
        *(ushort4*)&T2[((((size_t)b*64 + qt)*64 + kt)*64 + lane)*4] = o;
    }
}

// ---------------- bf16 MFMA GEMM ----------------
// MODE 0: fp32 + bias[n].  MODE 1: gate fusion (bf16 hi out only).
// MODE 7 (PASSES=1, N=3072): fused Q+K+V —
//   n<1024:  Q row-major (B=Bh, bias)          -> outH
//   <2048:   K fragment-major (B=Bl, trust=bk) -> outL
//   else:    V fragment-major (B=attH, wlast=bv, m=key/n=d) -> (u16*)outF
template<int MODE, int PASSES>
__global__ __launch_bounds__(256)
void mgemm(const u16* __restrict__ Ah, const u16* __restrict__ Al,
           const u16* __restrict__ Bh, const u16* __restrict__ Bl,
           const float* __restrict__ bias,
           float* __restrict__ outF, u16* __restrict__ outH, u16* __restrict__ outL,
           int M, int N,
           const float* __restrict__ trust, const float* __restrict__ wlast,
           const u16* __restrict__ attH)
{
    constexpr int NT   = (PASSES == 3) ? 4 : (PASSES == 2) ? 3 : 2;
    constexpr int BIDX = (PASSES == 1) ? 1 : 2;
    __shared__ u16 lds[2][NT][128*64];

    const int t    = threadIdx.x;
    const int lane = t & 63, wave = t >> 6;
    const int l15  = lane & 15, l4 = lane >> 4;
    const int wr   = wave >> 1, wc = wave & 1;
    const int w64  = wave << 6;
    const int m0   = blockIdx.y * 128, n0 = blockIdx.x * 128;

    const u16* srcs[NT];
    srcs[0] = Ah + (size_t)m0*1024;
    if (PASSES >= 2) srcs[1] = Al + (size_t)m0*1024;
    if (MODE == 7) {
        srcs[BIDX] = (n0 < 1024) ? Bh + (size_t)n0*1024
                   : (n0 < 2048) ? Bl + (size_t)(n0 - 1024)*1024
                                 : attH + (size_t)(n0 - 2048)*1024;
    } else {
        srcs[BIDX] = Bh + (size_t)n0*1024;
    }
    if (PASSES == 3) srcs[3] = Bl + (size_t)n0*1024;

    f32x4 acc[4][4];
    #pragma unroll
    for (int i = 0; i < 4; ++i)
        #pragma unroll
        for (int j = 0; j < 4; ++j) acc[i][j] = (f32x4){0.f,0.f,0.f,0.f};

#define STAGE(BUF, KOFF) do {                                                  \
    _Pragma("unroll")                                                          \
    for (int tl_ = 0; tl_ < NT; ++tl_) {                                       \
        _Pragma("unroll")                                                      \
        for (int it_ = 0; it_ < 4; ++it_) {                                    \
            const int idx_ = it_*256 + t;                                      \
            const int row_ = idx_ >> 3;                                        \
            const int c_   = (idx_ & 7) ^ (row_ & 7);                          \
            gload16(srcs[tl_] + (KOFF) + (size_t)row_*1024 + c_*8,             \
                    &lds[BUF][tl_][(it_*256 + w64)*8]);                        \
        }                                                                      \
    }                                                                          \
} while(0)

#define COMPUTE(BUF) do {                                                      \
    _Pragma("unroll")                                                          \
    for (int kk_ = 0; kk_ < 2; ++kk_) {                                        \
        const int cb_ = (kk_<<2) + l4;                                         \
        bf16x8 ah_[4], al_[4];                                                 \
        _Pragma("unroll")                                                      \
        for (int i_ = 0; i_ < 4; ++i_) {                                       \
            const int row_ = (wr<<6) + (i_<<4) + l15;                          \
            const int off_ = (row_<<6) + ((cb_ ^ (row_&7)) << 3);              \
            ah_[i_] = *(const bf16x8*)&lds[BUF][0][off_];                      \
            if (PASSES >= 2) al_[i_] = *(const bf16x8*)&lds[BUF][1][off_];     \
        }                                                                      \
        _Pragma("unroll")                                                      \
        for (int j_ = 0; j_ < 4; ++j_) {                                       \
            const int row_ = (wc<<6) + (j_<<4) + l15;                          \
            const int off_ = (row_<<6) + ((cb_ ^ (row_&7)) << 3);              \
            bf16x8 bh_ = *(const bf16x8*)&lds[BUF][BIDX][off_];                \
            bf16x8 bl_;                                                        \
            if (PASSES == 3) bl_ = *(const bf16x8*)&lds[BUF][3][off_];         \
            _Pragma("unroll")                                                  \
            for (int i_ = 0; i_ < 4; ++i_) {                                   \
                acc[i_][j_] = mfma16(ah_[i_], bh_, acc[i_][j_]);               \
                if (PASSES == 3) acc[i_][j_] = mfma16(ah_[i_], bl_, acc[i_][j_]); \
                if (PASSES >= 2) acc[i_][j_] = mfma16(al_[i_], bh_, acc[i_][j_]); \
            }                                                                  \
        }                                                                      \
    }                                                                          \
} while(0)

    STAGE(0, 0);
    __syncthreads();
    int cur = 0;
    for (int s = 0; s < 15; ++s) {
        if (cur == 0) STAGE(1, (s+1)*64);
        else          STAGE(0, (s+1)*64);
        COMPUTE(cur);
        __syncthreads();
        cur ^= 1;
    }
    COMPUTE(cur);
#undef STAGE
#undef COMPUTE

    // ---- epilogue ----
    #pragma unroll
    for (int i = 0; i < 4; ++i)
        #pragma unroll
        for (int j = 0; j < 4; ++j)
            #pragma unroll
            for (int r = 0; r < 4; ++r) {
                const int m = m0 + (wr<<6) + (i<<4) + (l4<<2) + r;
                const int n = n0 + (wc<<6) + (j<<4) + l15;
                const float v = acc[i][j][r];
                if (MODE == 0) {
                    outF[(size_t)m*N + n] = v + bias[n];
                } else if (MODE == 7) {
                    if (n < 1024) {
                        outH[(size_t)m*1024 + n] = f2bf(v + bias[n]);
                    } else if (n < 2048) {
                        const int nk = n - 1024;   // d_glob
                        const size_t blk = (((size_t)((m >> 10)*16 + (nk >> 6)))*64
                                            + ((m >> 4) & 63))*1024;
                        outL[blk + ((nk & 63) >> 3)*128 + (m & 15)*8 + (nk & 7)]
                            = f2bf(v + trust[nk]);
                    } else {
                        const int nv = n - 2048;   // d_glob; m = key
                        u16* outV = (u16*)outF;
                        const size_t blk = ((((size_t)((m >> 10)*16 + (nv >> 6)))*32
                                            + ((m & 1023) >> 5))*4 + ((nv & 63) >> 4))*512;
                        outV[blk + ((m & 31) >> 3)*128 + (nv & 15)*8 + (m & 7)]
                            = f2bf(v + wlast[nv]);
                    }
                } else { // MODE 1: gate fusion, bf16 hi out only
                    const float pre = v + bias[n] + trust[m]*wlast[n];
                    const float g = 1.f/(1.f + __expf(-pre));
                    const float att = bf2f(attH[(size_t)m*N + n]);
                    outH[(size_t)m*N + n] = f2bf(att*g);
                }
            }
}

// ---------------- Attention v12: fragment-major K/V/T, hi-only attended out ----------------
__global__ __launch_bounds__(512, 4)
void attn_kernel(const u16* __restrict__ Qb, const u16* __restrict__ Kf,
                 const u16* __restrict__ Vf, const u16* __restrict__ T,
                 const int* __restrict__ mask,
                 float* __restrict__ attnOut, u16* __restrict__ attH)
{
    __shared__ float Pw[8][16*68 + 16];   // 8 wave-private strips (also O-reduce alias)
    __shared__ float redA[8][16];
    __shared__ float redB[8][16];

    const int t    = threadIdx.x;
    const int lane = t & 63, wave = t >> 6;     // 8 waves
    const int l15  = lane & 15, l4 = lane >> 4;

    // T-reuse swizzle: bid = xcd + 8*(p3 + 8*q6); b = xcd>>1, h = ((xcd&1)<<3)+p3
    const int bid  = blockIdx.x;
    const int xcd  = bid & 7;
    const int idx0 = bid >> 3;
    const int p3   = idx0 & 7;
    const int q6   = idx0 >> 3;        // 0..63
    const int q0   = q6 * 16;
    const int b    = xcd >> 1;
    const int h    = ((xcd & 1) << 3) + p3;

    float* myP = Pw[wave];

    int mrow[4];
    #pragma unroll
    for (int r = 0; r < 4; ++r) mrow[r] = mask[b*SS + q0 + l4*4 + r];

    const u16* Qp = Qb + ((size_t)(b*SS + q0 + l15))*DD + h*HDD + l4*8;
    bf16x8 qf0 = *(const bf16x8*)Qp;
    bf16x8 qf1 = *(const bf16x8*)(Qp + 32);

    // ---- QK^T: wave's keys w*128 + tt*16 + l15, fragments straight from Kf ----
    f32x4 sacc[8];
    #pragma unroll
    for (int tt = 0; tt < 8; ++tt) sacc[tt] = (f32x4){0.f,0.f,0.f,0.f};

    const u16* Kbase = Kf + (((size_t)(b*16 + h))*64 + wave*8)*1024 + l4*128 + l15*8;
    #pragma unroll
    for (int tt = 0; tt < 8; ++tt) {
        bf16x8 kf0 = *(const bf16x8*)(Kbase + tt*1024);
        bf16x8 kf1 = *(const bf16x8*)(Kbase + tt*1024 + 512);
        sacc[tt] = mfma16(qf0, kf0, sacc[tt]);
        sacc[tt] = mfma16(qf1, kf1, sacc[tt]);
    }

    // ---- bias (fragment-major T) + mask + wave-local row-max ----
    const u16* Tb = T + ((((size_t)b*64 + q6)*64 + wave*8)*64 + lane)*4;
    float mx[4] = {-3e38f, -3e38f, -3e38f, -3e38f};
    #pragma unroll
    for (int tt = 0; tt < 8; ++tt) {
        ushort4 t4 = *(const ushort4*)(Tb + (size_t)tt*256);
        #pragma unroll
        for (int r = 0; r < 4; ++r) {
            const float bias = bf2f(((const u16*)&t4)[r]);
            float s = sacc[tt][r]*0.125f + bias;
            s = mrow[r] ? s : -1e9f;
            sacc[tt][r] = s;
            mx[r] = fmaxf(mx[r], s);
        }
    }
    #pragma unroll
    for (int r = 0; r < 4; ++r)
        #pragma unroll
        for (int xm = 1; xm < 16; xm <<= 1) mx[r] = fmaxf(mx[r], __shfl_xor(mx[r], xm));
    if (l15 == 0) {
        #pragma unroll
        for (int r = 0; r < 4; ++r) redA[wave][l4*4 + r] = mx[r];
    }
    __syncthreads();                                   // barrier 1

    float mxa[4];
    #pragma unroll
    for (int r = 0; r < 4; ++r) {
        const int row = l4*4 + r;
        float m = redA[0][row];
        #pragma unroll
        for (int w = 1; w < 8; ++w) m = fmaxf(m, redA[w][row]);
        mxa[r] = m;
    }

    // ---- exp in regs + row-sum ----
    float sum[4] = {0.f, 0.f, 0.f, 0.f};
    #pragma unroll
    for (int tt = 0; tt < 8; ++tt)
        #pragma unroll
        for (int r = 0; r < 4; ++r) {
            const float p = __expf(sacc[tt][r] - mxa[r]);
            sacc[tt][r] = p;
            sum[r] += p;
        }
    #pragma unroll
    for (int r = 0; r < 4; ++r)
        #pragma unroll
        for (int xm = 1; xm < 16; xm <<= 1) sum[r] += __shfl_xor(sum[r], xm);
    if (l15 == 0) {
        #pragma unroll
        for (int r = 0; r < 4; ++r) redB[wave][l4*4 + r] = sum[r];
    }
    __syncthreads();                                   // barrier 2

    float inv4[4];                                     // PV rows (l4*4+r)
    #pragma unroll
    for (int r = 0; r < 4; ++r) {
        const int row = l4*4 + r;
        float s8 = 0.f;
        #pragma unroll
        for (int w = 0; w < 8; ++w) s8 += redB[w][row];
        inv4[r] = 1.f / s8;
    }
    float wiv4[4];                                     // write rows (it*4 + l4)
    #pragma unroll
    for (int it = 0; it < 4; ++it) {
        const int row = it*4 + l4;
        float s8 = 0.f;
        #pragma unroll
        for (int w = 0; w < 8; ++w) s8 += redB[w][row];
        wiv4[it] = 1.f / s8;
    }

    float* gBase = attnOut + (((size_t)(b*HH + h))*SS + q0)*SS + wave*128;
    f32x4 pv[4];
    #pragma unroll
    for (int nt = 0; nt < 4; ++nt) pv[nt] = (f32x4){0.f,0.f,0.f,0.f};

    // ---- two wave-private halves: store P -> write attn -> PV, no s_barrier ----
    #pragma unroll
    for (int half = 0; half < 2; ++half) {
        #pragma unroll
        for (int t2 = 0; t2 < 4; ++t2)
            #pragma unroll
            for (int r = 0; r < 4; ++r)
                myP[(l4*4 + r)*68 + t2*16 + l15] = sacc[half*4 + t2][r];
        lds_fence();

        #pragma unroll
        for (int it = 0; it < 4; ++it) {
            const int row = it*4 + l4;
            f32x4 v = *(f32x4*)&myP[row*68 + l15*4];
            v *= wiv4[it];
            *(f32x4*)&gBase[(size_t)row*SS + half*64 + l15*4] = v;
        }

        #pragma unroll
        for (int kg = 0; kg < 2; ++kg) {
            const int c0 = kg*32 + l4*8;
            f32x4 a0 = *(f32x4*)&myP[l15*68 + c0];
            f32x4 a1 = *(f32x4*)&myP[l15*68 + c0 + 4];
            bf16x8 af;
            af[0] = (__bf16)a0[0]; af[1] = (__bf16)a0[1]; af[2] = (__bf16)a0[2]; af[3] = (__bf16)a0[3];
            af[4] = (__bf16)a1[0]; af[5] = (__bf16)a1[1]; af[6] = (__bf16)a1[2]; af[7] = (__bf16)a1[3];
            const int kc = wave*4 + half*2 + kg;
            const u16* Vp = Vf + (((size_t)(b*16 + h))*32 + kc)*2048 + l4*128 + l15*8;
            #pragma unroll
            for (int nt = 0; nt < 4; ++nt) {
                bf16x8 bf = *(const bf16x8*)(Vp + nt*512);
                pv[nt] = mfma16(af, bf, pv[nt]);
            }
        }
        lds_fence();
    }

    // ---- cross-wave O reduce (alias own strip, flat 1024 floats) ----
    #pragma unroll
    for (int nt = 0; nt < 4; ++nt)
        #pragma unroll
        for (int r = 0; r < 4; ++r)
            myP[(l4*4 + r)*64 + nt*16 + l15] = pv[nt][r] * inv4[r];
    __syncthreads();                                   // barrier 3

    {
        const int q = t >> 5, d0 = (t & 31)*2;
        float sx = 0.f, sy = 0.f;
        #pragma unroll
        for (int w = 0; w < 8; ++w) {
            float2 v = *(float2*)&Pw[w][q*64 + d0];
            sx += v.x; sy += v.y;
        }
        const size_t off = ((size_t)(b*SS + q0 + q))*DD + h*HDD + d0;
        ushort2 hh = {f2bf(sx), f2bf(sy)};
        *(ushort2*)&attH[off] = hh;
    }
}

extern "C" void kernel_launch(void* const* d_in, const int* in_sizes, int n_in,
                              void* d_out, int out_size, void* d_ws, size_t ws_size,
                              hipStream_t stream) {
    const float* x     = (const float*)d_in[0];
    const float* trust = (const float*)d_in[1];
    const int*   mask  = (const int*)  d_in[2];
    const float* Wq    = (const float*)d_in[3];
    const float* bq    = (const float*)d_in[4];
    const float* Wk    = (const float*)d_in[5];
    const float* bk    = (const float*)d_in[6];
    const float* Wv    = (const float*)d_in[7];
    const float* bv    = (const float*)d_in[8];
    const float* Wtp   = (const float*)d_in[9];
    const float* btp   = (const float*)d_in[10];
    const float* Wg    = (const float*)d_in[11];
    const float* bg    = (const float*)d_in[12];
    const float* Wo    = (const float*)d_in[13];
    const float* bo    = (const float*)d_in[14];

    float* out     = (float*)d_out;
    float* attnOut = out + (size_t)MTOT * DD;

    char* ws = (char*)d_ws;
    u16* xh   = (u16*)(ws + (size_t)0*MB);    // 8 MB -> attH later
    u16* WqTh = (u16*)(ws + (size_t)16*MB);
    u16* WkTh = (u16*)(ws + (size_t)18*MB);
    u16* WvTh = (u16*)(ws + (size_t)20*MB);
    u16* WgTh = (u16*)(ws + (size_t)22*MB);
    u16* WoTh = (u16*)(ws + (size_t)24*MB);
    u16* Qbf  = (u16*)(ws + (size_t)28*MB);   // 8 MB -> Gh later
    u16* Kfb  = (u16*)(ws + (size_t)36*MB);   // 8 MB fragment-major K
    u16* Vfb  = (u16*)(ws + (size_t)44*MB);   // 8 MB fragment-major V
    u16* Tb   = (u16*)(ws + (size_t)52*MB);   // 8 MB fragment-major trust-bias table
    float* tconst = (float*)(ws + (size_t)60*MB);
    u16* attH = xh;
    u16* Gh   = Qbf;

    const dim3 blk(256);

    tconst_kernel<<<1, 64, 0, stream>>>(Wtp, btp, tconst);
    tbias_kernel<<<dim3(64, BB), blk, 0, stream>>>(trust, tconst, Tb);
    split_kernel<<<2048, blk, 0, stream>>>(x, xh, MTOT*DD/4);
    tsplit5_kernel<<<dim3(16, 16, 5), blk, 0, stream>>>(
        Wq, WqTh, Wk, WkTh, Wv, WvTh, Wg, WgTh, Wo, WoTh);

    // fused Q+K+V: 1-pass, N=3072; Q row-major -> Qbf, K frag -> Kfb, V frag -> Vfb
    mgemm<7,1><<<dim3(3072/128, MTOT/128), blk, 0, stream>>>(
        xh, nullptr, WqTh, WkTh, bq, (float*)Vfb, Qbf, Kfb, MTOT, 3072,
        bk, bv, WvTh);

    attn_kernel<<<dim3(4096), dim3(512), 0, stream>>>(
        Qbf, Kfb, Vfb, Tb, mask, attnOut, attH);

    // gate: 1-pass; gated = bf16(attended) * sigmoid(attended@Wg[0:1024] + bg + trust*wlast)
    mgemm<1,1><<<dim3(DD/128, MTOT/128), blk, 0, stream>>>(
        attH, nullptr, WgTh, nullptr, bg, nullptr, Gh, nullptr, MTOT, DD,
        trust, Wg + (size_t)DD*DD, attH);
    // out = gated @ Wo + bo (fp32, 1-pass)
    mgemm<0,1><<<dim3(DD/128, MTOT/128), blk, 0, stream>>>(
        Gh, nullptr, WoTh, nullptr, bo, out, nullptr, nullptr, MTOT, DD,
        nullptr, nullptr, nullptr);
}

// Round 16
// 217.154 us; speedup vs baseline: 1.7215x; 1.0749x over previous
//
#include <hip/hip_runtime.h>
#include <math.h>

#define BB 4
#define SS 1024
#define DD 1024
#define HH 16
#define HDD 64
#define MTOT (BB*SS)   // 4096
#define MB (1024*1024)

typedef float  f32x4  __attribute__((ext_vector_type(4)));
typedef __bf16 bf16x8 __attribute__((ext_vector_type(8)));
typedef unsigned short u16;

__device__ __forceinline__ unsigned short f2bf(float f) {
    union { float f; unsigned u; } v; v.f = f;
    unsigned r = v.u + 0x7FFFu + ((v.u >> 16) & 1u);
    return (unsigned short)(r >> 16);
}
__device__ __forceinline__ float bf2f(unsigned short u) {
    union { unsigned u; float f; } v; v.u = ((unsigned)u) << 16;
    return v.f;
}
__device__ __forceinline__ f32x4 mfma16(bf16x8 a, bf16x8 b, f32x4 c) {
    return __builtin_amdgcn_mfma_f32_16x16x32_bf16(a, b, c, 0, 0, 0);
}
__device__ __forceinline__ void gload16(const void* g, void* l) {
    __builtin_amdgcn_global_load_lds(
        (const __attribute__((address_space(1))) void*)g,
        (__attribute__((address_space(3))) void*)l, 16, 0, 0);
}
__device__ __forceinline__ void lds_fence() {
    asm volatile("s_waitcnt lgkmcnt(0)" ::: "memory");
    __builtin_amdgcn_sched_barrier(0);
}
__device__ __forceinline__ void nt_store4(float* p, f32x4 v) {
    __builtin_nontemporal_store(v, (f32x4*)p);
}

// ---------------- split: fp32 -> bf16 hi ----------------
__global__ void split_kernel(const float* __restrict__ in, u16* __restrict__ hi, int n4)
{
    for (int i = blockIdx.x*blockDim.x + threadIdx.x; i < n4; i += gridDim.x*blockDim.x) {
        f32x4 v = ((const f32x4*)in)[i];
        ushort4 h4;
        h4.x = f2bf(v[0]); h4.y = f2bf(v[1]); h4.z = f2bf(v[2]); h4.w = f2bf(v[3]);
        ((ushort4*)hi)[i] = h4;
    }
}

// ------- fused transpose for all 5 weights: W[k][n] fp32 -> WT bf16 [n][k] -------
__global__ __launch_bounds__(256)
void tsplit5_kernel(const float* W0, u16* h0,
                    const float* W1, u16* h1,
                    const float* W2, u16* h2,
                    const float* W3, u16* h3,
                    const float* W4, u16* h4)
{
    const float* W; u16* hT;
    switch (blockIdx.z) {
        case 0: W = W0; hT = h0; break;
        case 1: W = W1; hT = h1; break;
        case 2: W = W2; hT = h2; break;
        case 3: W = W3; hT = h3; break;
        default: W = W4; hT = h4; break;
    }
    __shared__ float tile[64][65];
    const int t  = threadIdx.x;
    const int k0 = blockIdx.y * 64, n0 = blockIdx.x * 64;
    const int r  = t >> 4, c4 = (t & 15) * 4;
    #pragma unroll
    for (int rr = 0; rr < 4; ++rr) {
        const int k = r + rr*16;
        f32x4 v = *(const f32x4*)&W[(size_t)(k0 + k)*1024 + n0 + c4];
        tile[k][c4+0] = v[0]; tile[k][c4+1] = v[1]; tile[k][c4+2] = v[2]; tile[k][c4+3] = v[3];
    }
    __syncthreads();
    #pragma unroll
    for (int rr = 0; rr < 4; ++rr) {
        const int nl = r + rr*16;
        ushort4 hh;
        hh.x = f2bf(tile[c4+0][nl]); hh.y = f2bf(tile[c4+1][nl]);
        hh.z = f2bf(tile[c4+2][nl]); hh.w = f2bf(tile[c4+3][nl]);
        *(ushort4*)&hT[(size_t)(n0 + nl)*1024 + k0 + c4] = hh;
    }
}

// ---------------- trust-affinity rank-1 constants ----------------
__global__ void tconst_kernel(const float* __restrict__ Wtp, const float* __restrict__ btp,
                              float* __restrict__ out3)
{
    const int l = threadIdx.x;   // 64 threads
    const float w = Wtp[l], b = btp[l];
    float a = w*w, m = w*b, c = b*b;
    #pragma unroll
    for (int s = 32; s; s >>= 1) {
        a += __shfl_down(a, s);
        m += __shfl_down(m, s);
        c += __shfl_down(c, s);
    }
    if (l == 0) { out3[0] = a; out3[1] = m; out3[2] = c; }
}

// ---------------- trust bias table, FRAGMENT-MAJOR ----------------
// T2[b][qt][kt][lane*4 + r] = bf16(0.1*sigmoid(ta)) for
// q = qt*16 + (lane>>4)*4 + r, k = kt*16 + (lane&15).
__global__ __launch_bounds__(256)
void tbias_kernel(const float* __restrict__ trust, const float* __restrict__ tconst,
                  u16* __restrict__ T2)
{
    const int qt = blockIdx.x;      // 0..63
    const int b  = blockIdx.y;      // 0..3
    const int t  = threadIdx.x;
    const int lane = t & 63, grp = t >> 6;
    const int l15 = lane & 15, l4 = lane >> 4;
    const float c1 = tconst[0], c2 = tconst[1], c3 = tconst[2];
    float tq[4];
    #pragma unroll
    for (int r = 0; r < 4; ++r) tq[r] = trust[b*SS + qt*16 + l4*4 + r];
    for (int kt2 = 0; kt2 < 16; ++kt2) {
        const int kt = grp*16 + kt2;
        const float tk = trust[b*SS + kt*16 + l15];
        ushort4 o;
        #pragma unroll
        for (int r = 0; r < 4; ++r) {
            const float ta = c1*tq[r]*tk + c2*(tq[r] + tk) + c3;
            ((u16*)&o)[r] = f2bf(0.1f/(1.f + __expf(-ta)));
        }
        *(ushort4*)&T2[((((size_t)b*64 + qt)*64 + kt)*64 + lane)*4] = o;
    }
}

// ---------------- bf16 MFMA GEMM ----------------
// MODE 0: fp32 + bias[n] (nontemporal out).  MODE 1: gate fusion (bf16 hi out only).
// MODE 7 (PASSES=1, N=3072): fused Q+K+V —
//   n<1024:  Q row-major (B=Bh, bias)          -> outH
//   <2048:   K fragment-major (B=Bl, trust=bk) -> outL
//   else:    V fragment-major (B=attH, wlast=bv, m=key/n=d) -> (u16*)outF
template<int MODE, int PASSES>
__global__ __launch_bounds__(256)
void mgemm(const u16* __restrict__ Ah, const u16* __restrict__ Al,
           const u16* __restrict__ Bh, const u16* __restrict__ Bl,
           const float* __restrict__ bias,
           float* __restrict__ outF, u16* __restrict__ outH, u16* __restrict__ outL,
           int M, int N,
           const float* __restrict__ trust, const float* __restrict__ wlast,
           const u16* __restrict__ attH)
{
    constexpr int NT   = (PASSES == 3) ? 4 : (PASSES == 2) ? 3 : 2;
    constexpr int BIDX = (PASSES == 1) ? 1 : 2;
    __shared__ u16 lds[2][NT][128*64];

    const int t    = threadIdx.x;
    const int lane = t & 63, wave = t >> 6;
    const int l15  = lane & 15, l4 = lane >> 4;
    const int wr   = wave >> 1, wc = wave & 1;
    const int w64  = wave << 6;
    const int m0   = blockIdx.y * 128, n0 = blockIdx.x * 128;

    const u16* srcs[NT];
    srcs[0] = Ah + (size_t)m0*1024;
    if (PASSES >= 2) srcs[1] = Al + (size_t)m0*1024;
    if (MODE == 7) {
        srcs[BIDX] = (n0 < 1024) ? Bh + (size_t)n0*1024
                   : (n0 < 2048) ? Bl + (size_t)(n0 - 1024)*1024
                                 : attH + (size_t)(n0 - 2048)*1024;
    } else {
        srcs[BIDX] = Bh + (size_t)n0*1024;
    }
    if (PASSES == 3) srcs[3] = Bl + (size_t)n0*1024;

    f32x4 acc[4][4];
    #pragma unroll
    for (int i = 0; i < 4; ++i)
        #pragma unroll
        for (int j = 0; j < 4; ++j) acc[i][j] = (f32x4){0.f,0.f,0.f,0.f};

#define STAGE(BUF, KOFF) do {                                                  \
    _Pragma("unroll")                                                          \
    for (int tl_ = 0; tl_ < NT; ++tl_) {                                       \
        _Pragma("unroll")                                                      \
        for (int it_ = 0; it_ < 4; ++it_) {                                    \
            const int idx_ = it_*256 + t;                                      \
            const int row_ = idx_ >> 3;                                        \
            const int c_   = (idx_ & 7) ^ (row_ & 7);                          \
            gload16(srcs[tl_] + (KOFF) + (size_t)row_*1024 + c_*8,             \
                    &lds[BUF][tl_][(it_*256 + w64)*8]);                        \
        }                                                                      \
    }                                                                          \
} while(0)

#define COMPUTE(BUF) do {                                                      \
    _Pragma("unroll")                                                          \
    for (int kk_ = 0; kk_ < 2; ++kk_) {                                        \
        const int cb_ = (kk_<<2) + l4;                                         \
        bf16x8 ah_[4], al_[4];                                                 \
        _Pragma("unroll")                                                      \
        for (int i_ = 0; i_ < 4; ++i_) {                                       \
            const int row_ = (wr<<6) + (i_<<4) + l15;                          \
            const int off_ = (row_<<6) + ((cb_ ^ (row_&7)) << 3);              \
            ah_[i_] = *(const bf16x8*)&lds[BUF][0][off_];                      \
            if (PASSES >= 2) al_[i_] = *(const bf16x8*)&lds[BUF][1][off_];     \
        }                                                                      \
        _Pragma("unroll")                                                      \
        for (int j_ = 0; j_ < 4; ++j_) {                                       \
            const int row_ = (wc<<6) + (j_<<4) + l15;                          \
            const int off_ = (row_<<6) + ((cb_ ^ (row_&7)) << 3);              \
            bf16x8 bh_ = *(const bf16x8*)&lds[BUF][BIDX][off_];                \
            bf16x8 bl_;                                                        \
            if (PASSES == 3) bl_ = *(const bf16x8*)&lds[BUF][3][off_];         \
            _Pragma("unroll")                                                  \
            for (int i_ = 0; i_ < 4; ++i_) {                                   \
                acc[i_][j_] = mfma16(ah_[i_], bh_, acc[i_][j_]);               \
                if (PASSES == 3) acc[i_][j_] = mfma16(ah_[i_], bl_, acc[i_][j_]); \
                if (PASSES >= 2) acc[i_][j_] = mfma16(al_[i_], bh_, acc[i_][j_]); \
            }                                                                  \
        }                                                                      \
    }                                                                          \
} while(0)

    STAGE(0, 0);
    __syncthreads();
    int cur = 0;
    for (int s = 0; s < 15; ++s) {
        if (cur == 0) STAGE(1, (s+1)*64);
        else          STAGE(0, (s+1)*64);
        COMPUTE(cur);
        __syncthreads();
        cur ^= 1;
    }
    COMPUTE(cur);
#undef STAGE
#undef COMPUTE

    // ---- epilogue ----
    #pragma unroll
    for (int i = 0; i < 4; ++i)
        #pragma unroll
        for (int j = 0; j < 4; ++j)
            #pragma unroll
            for (int r = 0; r < 4; ++r) {
                const int m = m0 + (wr<<6) + (i<<4) + (l4<<2) + r;
                const int n = n0 + (wc<<6) + (j<<4) + l15;
                const float v = acc[i][j][r];
                if (MODE == 0) {
                    float* p = &outF[(size_t)m*N + n];
                    __builtin_nontemporal_store(v + bias[n], p);
                } else if (MODE == 7) {
                    if (n < 1024) {
                        outH[(size_t)m*1024 + n] = f2bf(v + bias[n]);
                    } else if (n < 2048) {
                        const int nk = n - 1024;   // d_glob
                        const size_t blk = (((size_t)((m >> 10)*16 + (nk >> 6)))*64
                                            + ((m >> 4) & 63))*1024;
                        outL[blk + ((nk & 63) >> 3)*128 + (m & 15)*8 + (nk & 7)]
                            = f2bf(v + trust[nk]);
                    } else {
                        const int nv = n - 2048;   // d_glob; m = key
                        u16* outV = (u16*)outF;
                        const size_t blk = ((((size_t)((m >> 10)*16 + (nv >> 6)))*32
                                            + ((m & 1023) >> 5))*4 + ((nv & 63) >> 4))*512;
                        outV[blk + ((m & 31) >> 3)*128 + (nv & 15)*8 + (m & 7)]
                            = f2bf(v + wlast[nv]);
                    }
                } else { // MODE 1: gate fusion, bf16 hi out only
                    const float pre = v + bias[n] + trust[m]*wlast[n];
                    const float g = 1.f/(1.f + __expf(-pre));
                    const float att = bf2f(attH[(size_t)m*N + n]);
                    outH[(size_t)m*N + n] = f2bf(att*g);
                }
            }
}

// ---------------- Attention v13: no-max softmax, 2 barriers, nontemporal attn writes ----
// Scores are bounded (|s| <~ 6): exp(s) is safe in fp32 without max-subtraction; the
// normalized result is mathematically identical. Masked rows set p=1.0 -> sum=1024.0
// exactly -> attn = 1/1024 exactly (matches reference uniform). Barriers: 1 sum-merge +
// 1 O-reduce. attnOut is write-only -> nontemporal stores keep it out of L2.
__global__ __launch_bounds__(512, 4)
void attn_kernel(const u16* __restrict__ Qb, const u16* __restrict__ Kf,
                 const u16* __restrict__ Vf, const u16* __restrict__ T,
                 const int* __restrict__ mask,
                 float* __restrict__ attnOut, u16* __restrict__ attH)
{
    __shared__ float Pw[8][16*68 + 16];   // 8 wave-private strips (also O-reduce alias)
    __shared__ float redB[8][16];

    const int t    = threadIdx.x;
    const int lane = t & 63, wave = t >> 6;     // 8 waves
    const int l15  = lane & 15, l4 = lane >> 4;

    // T-reuse swizzle: bid = xcd + 8*(p3 + 8*q6); b = xcd>>1, h = ((xcd&1)<<3)+p3
    const int bid  = blockIdx.x;
    const int xcd  = bid & 7;
    const int idx0 = bid >> 3;
    const int p3   = idx0 & 7;
    const int q6   = idx0 >> 3;        // 0..63
    const int q0   = q6 * 16;
    const int b    = xcd >> 1;
    const int h    = ((xcd & 1) << 3) + p3;

    float* myP = Pw[wave];

    int mrow[4];
    #pragma unroll
    for (int r = 0; r < 4; ++r) mrow[r] = mask[b*SS + q0 + l4*4 + r];

    const u16* Qp = Qb + ((size_t)(b*SS + q0 + l15))*DD + h*HDD + l4*8;
    bf16x8 qf0 = *(const bf16x8*)Qp;
    bf16x8 qf1 = *(const bf16x8*)(Qp + 32);

    // ---- QK^T: wave's keys w*128 + tt*16 + l15, fragments straight from Kf ----
    f32x4 sacc[8];
    #pragma unroll
    for (int tt = 0; tt < 8; ++tt) sacc[tt] = (f32x4){0.f,0.f,0.f,0.f};

    const u16* Kbase = Kf + (((size_t)(b*16 + h))*64 + wave*8)*1024 + l4*128 + l15*8;
    #pragma unroll
    for (int tt = 0; tt < 8; ++tt) {
        bf16x8 kf0 = *(const bf16x8*)(Kbase + tt*1024);
        bf16x8 kf1 = *(const bf16x8*)(Kbase + tt*1024 + 512);
        sacc[tt] = mfma16(qf0, kf0, sacc[tt]);
        sacc[tt] = mfma16(qf1, kf1, sacc[tt]);
    }

    // ---- bias (fragment-major T) + mask + exp (no max-subtraction) + row-sum ----
    const u16* Tb = T + ((((size_t)b*64 + q6)*64 + wave*8)*64 + lane)*4;
    float sum[4] = {0.f, 0.f, 0.f, 0.f};
    #pragma unroll
    for (int tt = 0; tt < 8; ++tt) {
        ushort4 t4 = *(const ushort4*)(Tb + (size_t)tt*256);
        #pragma unroll
        for (int r = 0; r < 4; ++r) {
            const float bias = bf2f(((const u16*)&t4)[r]);
            const float s = sacc[tt][r]*0.125f + bias;
            const float p = mrow[r] ? __expf(s) : 1.0f;
            sacc[tt][r] = p;
            sum[r] += p;
        }
    }
    #pragma unroll
    for (int r = 0; r < 4; ++r)
        #pragma unroll
        for (int xm = 1; xm < 16; xm <<= 1) sum[r] += __shfl_xor(sum[r], xm);
    if (l15 == 0) {
        #pragma unroll
        for (int r = 0; r < 4; ++r) redB[wave][l4*4 + r] = sum[r];
    }
    __syncthreads();                                   // barrier 1 (sum merge)

    float inv4[4];                                     // PV rows (l4*4+r)
    #pragma unroll
    for (int r = 0; r < 4; ++r) {
        const int row = l4*4 + r;
        float s8 = 0.f;
        #pragma unroll
        for (int w = 0; w < 8; ++w) s8 += redB[w][row];
        inv4[r] = 1.f / s8;
    }
    float wiv4[4];                                     // write rows (it*4 + l4)
    #pragma unroll
    for (int it = 0; it < 4; ++it) {
        const int row = it*4 + l4;
        float s8 = 0.f;
        #pragma unroll
        for (int w = 0; w < 8; ++w) s8 += redB[w][row];
        wiv4[it] = 1.f / s8;
    }

    float* gBase = attnOut + (((size_t)(b*HH + h))*SS + q0)*SS + wave*128;
    f32x4 pv[4];
    #pragma unroll
    for (int nt = 0; nt < 4; ++nt) pv[nt] = (f32x4){0.f,0.f,0.f,0.f};

    // ---- two wave-private halves: store P -> nt-write attn -> PV, no s_barrier ----
    #pragma unroll
    for (int half = 0; half < 2; ++half) {
        #pragma unroll
        for (int t2 = 0; t2 < 4; ++t2)
            #pragma unroll
            for (int r = 0; r < 4; ++r)
                myP[(l4*4 + r)*68 + t2*16 + l15] = sacc[half*4 + t2][r];
        lds_fence();

        #pragma unroll
        for (int it = 0; it < 4; ++it) {
            const int row = it*4 + l4;
            f32x4 v = *(f32x4*)&myP[row*68 + l15*4];
            v *= wiv4[it];
            nt_store4(&gBase[(size_t)row*SS + half*64 + l15*4], v);
        }

        #pragma unroll
        for (int kg = 0; kg < 2; ++kg) {
            const int c0 = kg*32 + l4*8;
            f32x4 a0 = *(f32x4*)&myP[l15*68 + c0];
            f32x4 a1 = *(f32x4*)&myP[l15*68 + c0 + 4];
            bf16x8 af;
            af[0] = (__bf16)a0[0]; af[1] = (__bf16)a0[1]; af[2] = (__bf16)a0[2]; af[3] = (__bf16)a0[3];
            af[4] = (__bf16)a1[0]; af[5] = (__bf16)a1[1]; af[6] = (__bf16)a1[2]; af[7] = (__bf16)a1[3];
            const int kc = wave*4 + half*2 + kg;
            const u16* Vp = Vf + (((size_t)(b*16 + h))*32 + kc)*2048 + l4*128 + l15*8;
            #pragma unroll
            for (int nt = 0; nt < 4; ++nt) {
                bf16x8 bf = *(const bf16x8*)(Vp + nt*512);
                pv[nt] = mfma16(af, bf, pv[nt]);
            }
        }
        lds_fence();
    }

    // ---- cross-wave O reduce (alias own strip, flat 1024 floats) ----
    #pragma unroll
    for (int nt = 0; nt < 4; ++nt)
        #pragma unroll
        for (int r = 0; r < 4; ++r)
            myP[(l4*4 + r)*64 + nt*16 + l15] = pv[nt][r] * inv4[r];
    __syncthreads();                                   // barrier 2 (O reduce)

    {
        const int q = t >> 5, d0 = (t & 31)*2;
        float sx = 0.f, sy = 0.f;
        #pragma unroll
        for (int w = 0; w < 8; ++w) {
            float2 v = *(float2*)&Pw[w][q*64 + d0];
            sx += v.x; sy += v.y;
        }
        const size_t off = ((size_t)(b*SS + q0 + q))*DD + h*HDD + d0;
        ushort2 hh = {f2bf(sx), f2bf(sy)};
        *(ushort2*)&attH[off] = hh;
    }
}

extern "C" void kernel_launch(void* const* d_in, const int* in_sizes, int n_in,
                              void* d_out, int out_size, void* d_ws, size_t ws_size,
                              hipStream_t stream) {
    const float* x     = (const float*)d_in[0];
    const float* trust = (const float*)d_in[1];
    const int*   mask  = (const int*)  d_in[2];
    const float* Wq    = (const float*)d_in[3];
    const float* bq    = (const float*)d_in[4];
    const float* Wk    = (const float*)d_in[5];
    const float* bk    = (const float*)d_in[6];
    const float* Wv    = (const float*)d_in[7];
    const float* bv    = (const float*)d_in[8];
    const float* Wtp   = (const float*)d_in[9];
    const float* btp   = (const float*)d_in[10];
    const float* Wg    = (const float*)d_in[11];
    const float* bg    = (const float*)d_in[12];
    const float* Wo    = (const float*)d_in[13];
    const float* bo    = (const float*)d_in[14];

    float* out     = (float*)d_out;
    float* attnOut = out + (size_t)MTOT * DD;

    char* ws = (char*)d_ws;
    u16* xh   = (u16*)(ws + (size_t)0*MB);    // 8 MB -> attH later
    u16* WqTh = (u16*)(ws + (size_t)16*MB);
    u16* WkTh = (u16*)(ws + (size_t)18*MB);
    u16* WvTh = (u16*)(ws + (size_t)20*MB);
    u16* WgTh = (u16*)(ws + (size_t)22*MB);
    u16* WoTh = (u16*)(ws + (size_t)24*MB);
    u16* Qbf  = (u16*)(ws + (size_t)28*MB);   // 8 MB -> Gh later
    u16* Kfb  = (u16*)(ws + (size_t)36*MB);   // 8 MB fragment-major K
    u16* Vfb  = (u16*)(ws + (size_t)44*MB);   // 8 MB fragment-major V
    u16* Tb   = (u16*)(ws + (size_t)52*MB);   // 8 MB fragment-major trust-bias table
    float* tconst = (float*)(ws + (size_t)60*MB);
    u16* attH = xh;
    u16* Gh   = Qbf;

    const dim3 blk(256);

    tconst_kernel<<<1, 64, 0, stream>>>(Wtp, btp, tconst);
    tbias_kernel<<<dim3(64, BB), blk, 0, stream>>>(trust, tconst, Tb);
    split_kernel<<<2048, blk, 0, stream>>>(x, xh, MTOT*DD/4);
    tsplit5_kernel<<<dim3(16, 16, 5), blk, 0, stream>>>(
        Wq, WqTh, Wk, WkTh, Wv, WvTh, Wg, WgTh, Wo, WoTh);

    // fused Q+K+V: 1-pass, N=3072; Q row-major -> Qbf, K frag -> Kfb, V frag -> Vfb
    mgemm<7,1><<<dim3(3072/128, MTOT/128), blk, 0, stream>>>(
        xh, nullptr, WqTh, WkTh, bq, (float*)Vfb, Qbf, Kfb, MTOT, 3072,
        bk, bv, WvTh);

    attn_kernel<<<dim3(4096), dim3(512), 0, stream>>>(
        Qbf, Kfb, Vfb, Tb, mask, attnOut, attH);

    // gate: 1-pass; gated = bf16(attended) * sigmoid(attended@Wg[0:1024] + bg + trust*wlast)
    mgemm<1,1><<<dim3(DD/128, MTOT/128), blk, 0, stream>>>(
        attH, nullptr, WgTh, nullptr, bg, nullptr, Gh, nullptr, MTOT, DD,
        trust, Wg + (size_t)DD*DD, attH);
    // out = gated @ Wo + bo (fp32, 1-pass, nontemporal)
    mgemm<0,1><<<dim3(DD/128, MTOT/128), blk, 0, stream>>>(
        Gh, nullptr, WoTh, nullptr, bo, out, nullptr, nullptr, MTOT, DD,
        nullptr, nullptr, nullptr);
}

// Round 17
// 213.688 us; speedup vs baseline: 1.7494x; 1.0162x over previous
//
#include <hip/hip_runtime.h>
#include <math.h>

#define BB 4
#define SS 1024
#define DD 1024
#define HH 16
#define HDD 64
#define MTOT (BB*SS)   // 4096
#define MB (1024*1024)

typedef float  f32x4  __attribute__((ext_vector_type(4)));
typedef __bf16 bf16x8 __attribute__((ext_vector_type(8)));
typedef unsigned short u16;

__device__ __forceinline__ unsigned short f2bf(float f) {
    union { float f; unsigned u; } v; v.f = f;
    unsigned r = v.u + 0x7FFFu + ((v.u >> 16) & 1u);
    return (unsigned short)(r >> 16);
}
__device__ __forceinline__ float bf2f(unsigned short u) {
    union { unsigned u; float f; } v; v.u = ((unsigned)u) << 16;
    return v.f;
}
__device__ __forceinline__ f32x4 mfma16(bf16x8 a, bf16x8 b, f32x4 c) {
    return __builtin_amdgcn_mfma_f32_16x16x32_bf16(a, b, c, 0, 0, 0);
}
__device__ __forceinline__ void gload16(const void* g, void* l) {
    __builtin_amdgcn_global_load_lds(
        (const __attribute__((address_space(1))) void*)g,
        (__attribute__((address_space(3))) void*)l, 16, 0, 0);
}
__device__ __forceinline__ void lds_fence() {
    asm volatile("s_waitcnt lgkmcnt(0)" ::: "memory");
    __builtin_amdgcn_sched_barrier(0);
}
__device__ __forceinline__ void nt_store4(float* p, f32x4 v) {
    __builtin_nontemporal_store(v, (f32x4*)p);
}

// -------- prep: z=0..4 weight transpose W[k][n] fp32 -> WT bf16 [n][k];
//          z=5: x fp32 -> bf16 split (256 xy-blocks x 16 rows) --------
__global__ __launch_bounds__(256)
void prep_kernel(const float* W0, u16* h0,
                 const float* W1, u16* h1,
                 const float* W2, u16* h2,
                 const float* W3, u16* h3,
                 const float* W4, u16* h4,
                 const float* x,  u16* xh)
{
    const int t = threadIdx.x;
    if (blockIdx.z == 5) {
        const int idx = blockIdx.y*16 + blockIdx.x;        // 0..255
        const float* src = x  + (size_t)idx*16*1024;
        u16*         dst = xh + (size_t)idx*16*1024;
        #pragma unroll
        for (int rr = 0; rr < 16; ++rr) {
            f32x4 v = *(const f32x4*)&src[rr*1024 + t*4];
            ushort4 h4;
            h4.x = f2bf(v[0]); h4.y = f2bf(v[1]); h4.z = f2bf(v[2]); h4.w = f2bf(v[3]);
            *(ushort4*)&dst[rr*1024 + t*4] = h4;
        }
        return;
    }
    const float* W; u16* hT;
    switch (blockIdx.z) {
        case 0: W = W0; hT = h0; break;
        case 1: W = W1; hT = h1; break;
        case 2: W = W2; hT = h2; break;
        case 3: W = W3; hT = h3; break;
        default: W = W4; hT = h4; break;
    }
    __shared__ float tile[64][65];
    const int k0 = blockIdx.y * 64, n0 = blockIdx.x * 64;
    const int r  = t >> 4, c4 = (t & 15) * 4;
    #pragma unroll
    for (int rr = 0; rr < 4; ++rr) {
        const int k = r + rr*16;
        f32x4 v = *(const f32x4*)&W[(size_t)(k0 + k)*1024 + n0 + c4];
        tile[k][c4+0] = v[0]; tile[k][c4+1] = v[1]; tile[k][c4+2] = v[2]; tile[k][c4+3] = v[3];
    }
    __syncthreads();
    #pragma unroll
    for (int rr = 0; rr < 4; ++rr) {
        const int nl = r + rr*16;
        ushort4 hh;
        hh.x = f2bf(tile[c4+0][nl]); hh.y = f2bf(tile[c4+1][nl]);
        hh.z = f2bf(tile[c4+2][nl]); hh.w = f2bf(tile[c4+3][nl]);
        *(ushort4*)&hT[(size_t)(n0 + nl)*1024 + k0 + c4] = hh;
    }
}

// ---------------- trust bias table, FRAGMENT-MAJOR, inline rank-1 constants ------------
// T2[b][qt][kt][lane*4 + r] = bf16(0.1*sigmoid(c1*tq*tk + c2*(tq+tk) + c3)) for
// q = qt*16 + (lane>>4)*4 + r, k = kt*16 + (lane&15).
__global__ __launch_bounds__(256)
void tbias_kernel(const float* __restrict__ trust,
                  const float* __restrict__ Wtp, const float* __restrict__ btp,
                  u16* __restrict__ T2)
{
    const int qt = blockIdx.x;      // 0..63
    const int b  = blockIdx.y;      // 0..3
    const int t  = threadIdx.x;
    const int lane = t & 63, grp = t >> 6;
    const int l15 = lane & 15, l4 = lane >> 4;

    // rank-1 constants: per-wave 64-lane butterfly (all lanes converge)
    const float w = Wtp[lane], bt = btp[lane];
    float c1 = w*w, c2 = w*bt, c3 = bt*bt;
    #pragma unroll
    for (int xm = 1; xm < 64; xm <<= 1) {
        c1 += __shfl_xor(c1, xm);
        c2 += __shfl_xor(c2, xm);
        c3 += __shfl_xor(c3, xm);
    }

    float tq[4];
    #pragma unroll
    for (int r = 0; r < 4; ++r) tq[r] = trust[b*SS + qt*16 + l4*4 + r];
    for (int kt2 = 0; kt2 < 16; ++kt2) {
        const int kt = grp*16 + kt2;
        const float tk = trust[b*SS + kt*16 + l15];
        ushort4 o;
        #pragma unroll
        for (int r = 0; r < 4; ++r) {
            const float ta = c1*tq[r]*tk + c2*(tq[r] + tk) + c3;
            ((u16*)&o)[r] = f2bf(0.1f/(1.f + __expf(-ta)));
        }
        *(ushort4*)&T2[((((size_t)b*64 + qt)*64 + kt)*64 + lane)*4] = o;
    }
}

// ---------------- bf16 MFMA GEMM ----------------
// MODE 0: fp32 + bias[n] (nontemporal out).  MODE 1: gate fusion (bf16 hi out only).
// MODE 7 (PASSES=1, N=3072): fused Q+K+V —
//   n<1024:  Q row-major (B=Bh, bias)          -> outH
//   <2048:   K fragment-major (B=Bl, trust=bk) -> outL
//   else:    V fragment-major (B=attH, wlast=bv, m=key/n=d) -> (u16*)outF
template<int MODE, int PASSES>
__global__ __launch_bounds__(256)
void mgemm(const u16* __restrict__ Ah, const u16* __restrict__ Al,
           const u16* __restrict__ Bh, const u16* __restrict__ Bl,
           const float* __restrict__ bias,
           float* __restrict__ outF, u16* __restrict__ outH, u16* __restrict__ outL,
           int M, int N,
           const float* __restrict__ trust, const float* __restrict__ wlast,
           const u16* __restrict__ attH)
{
    constexpr int NT   = (PASSES == 3) ? 4 : (PASSES == 2) ? 3 : 2;
    constexpr int BIDX = (PASSES == 1) ? 1 : 2;
    __shared__ u16 lds[2][NT][128*64];

    const int t    = threadIdx.x;
    const int lane = t & 63, wave = t >> 6;
    const int l15  = lane & 15, l4 = lane >> 4;
    const int wr   = wave >> 1, wc = wave & 1;
    const int w64  = wave << 6;
    const int m0   = blockIdx.y * 128, n0 = blockIdx.x * 128;

    const u16* srcs[NT];
    srcs[0] = Ah + (size_t)m0*1024;
    if (PASSES >= 2) srcs[1] = Al + (size_t)m0*1024;
    if (MODE == 7) {
        srcs[BIDX] = (n0 < 1024) ? Bh + (size_t)n0*1024
                   : (n0 < 2048) ? Bl + (size_t)(n0 - 1024)*1024
                                 : attH + (size_t)(n0 - 2048)*1024;
    } else {
        srcs[BIDX] = Bh + (size_t)n0*1024;
    }
    if (PASSES == 3) srcs[3] = Bl + (size_t)n0*1024;

    f32x4 acc[4][4];
    #pragma unroll
    for (int i = 0; i < 4; ++i)
        #pragma unroll
        for (int j = 0; j < 4; ++j) acc[i][j] = (f32x4){0.f,0.f,0.f,0.f};

#define STAGE(BUF, KOFF) do {                                                  \
    _Pragma("unroll")                                                          \
    for (int tl_ = 0; tl_ < NT; ++tl_) {                                       \
        _Pragma("unroll")                                                      \
        for (int it_ = 0; it_ < 4; ++it_) {                                    \
            const int idx_ = it_*256 + t;                                      \
            const int row_ = idx_ >> 3;                                        \
            const int c_   = (idx_ & 7) ^ (row_ & 7);                          \
            gload16(srcs[tl_] + (KOFF) + (size_t)row_*1024 + c_*8,             \
                    &lds[BUF][tl_][(it_*256 + w64)*8]);                        \
        }                                                                      \
    }                                                                          \
} while(0)

#define COMPUTE(BUF) do {                                                      \
    _Pragma("unroll")                                                          \
    for (int kk_ = 0; kk_ < 2; ++kk_) {                                        \
        const int cb_ = (kk_<<2) + l4;                                         \
        bf16x8 ah_[4], al_[4];                                                 \
        _Pragma("unroll")                                                      \
        for (int i_ = 0; i_ < 4; ++i_) {                                       \
            const int row_ = (wr<<6) + (i_<<4) + l15;                          \
            const int off_ = (row_<<6) + ((cb_ ^ (row_&7)) << 3);              \
            ah_[i_] = *(const bf16x8*)&lds[BUF][0][off_];                      \
            if (PASSES >= 2) al_[i_] = *(const bf16x8*)&lds[BUF][1][off_];     \
        }                                                                      \
        _Pragma("unroll")                                                      \
        for (int j_ = 0; j_ < 4; ++j_) {                                       \
            const int row_ = (wc<<6) + (j_<<4) + l15;                          \
            const int off_ = (row_<<6) + ((cb_ ^ (row_&7)) << 3);              \
            bf16x8 bh_ = *(const bf16x8*)&lds[BUF][BIDX][off_];                \
            bf16x8 bl_;                                                        \
            if (PASSES == 3) bl_ = *(const bf16x8*)&lds[BUF][3][off_];         \
            _Pragma("unroll")                                                  \
            for (int i_ = 0; i_ < 4; ++i_) {                                   \
                acc[i_][j_] = mfma16(ah_[i_], bh_, acc[i_][j_]);               \
                if (PASSES == 3) acc[i_][j_] = mfma16(ah_[i_], bl_, acc[i_][j_]); \
                if (PASSES >= 2) acc[i_][j_] = mfma16(al_[i_], bh_, acc[i_][j_]); \
            }                                                                  \
        }                                                                      \
    }                                                                          \
} while(0)

    STAGE(0, 0);
    __syncthreads();
    int cur = 0;
    for (int s = 0; s < 15; ++s) {
        if (cur == 0) STAGE(1, (s+1)*64);
        else          STAGE(0, (s+1)*64);
        COMPUTE(cur);
        __syncthreads();
        cur ^= 1;
    }
    COMPUTE(cur);
#undef STAGE
#undef COMPUTE

    // ---- epilogue ----
    #pragma unroll
    for (int i = 0; i < 4; ++i)
        #pragma unroll
        for (int j = 0; j < 4; ++j)
            #pragma unroll
            for (int r = 0; r < 4; ++r) {
                const int m = m0 + (wr<<6) + (i<<4) + (l4<<2) + r;
                const int n = n0 + (wc<<6) + (j<<4) + l15;
                const float v = acc[i][j][r];
                if (MODE == 0) {
                    float* p = &outF[(size_t)m*N + n];
                    __builtin_nontemporal_store(v + bias[n], p);
                } else if (MODE == 7) {
                    if (n < 1024) {
                        outH[(size_t)m*1024 + n] = f2bf(v + bias[n]);
                    } else if (n < 2048) {
                        const int nk = n - 1024;   // d_glob
                        const size_t blk = (((size_t)((m >> 10)*16 + (nk >> 6)))*64
                                            + ((m >> 4) & 63))*1024;
                        outL[blk + ((nk & 63) >> 3)*128 + (m & 15)*8 + (nk & 7)]
                            = f2bf(v + trust[nk]);
                    } else {
                        const int nv = n - 2048;   // d_glob; m = key
                        u16* outV = (u16*)outF;
                        const size_t blk = ((((size_t)((m >> 10)*16 + (nv >> 6)))*32
                                            + ((m & 1023) >> 5))*4 + ((nv & 63) >> 4))*512;
                        outV[blk + ((m & 31) >> 3)*128 + (nv & 15)*8 + (m & 7)]
                            = f2bf(v + wlast[nv]);
                    }
                } else { // MODE 1: gate fusion, bf16 hi out only
                    const float pre = v + bias[n] + trust[m]*wlast[n];
                    const float g = 1.f/(1.f + __expf(-pre));
                    const float att = bf2f(attH[(size_t)m*N + n]);
                    outH[(size_t)m*N + n] = f2bf(att*g);
                }
            }
}

// ---------------- Attention v13: no-max softmax, 2 barriers, nontemporal attn writes ----
__global__ __launch_bounds__(512, 4)
void attn_kernel(const u16* __restrict__ Qb, const u16* __restrict__ Kf,
                 const u16* __restrict__ Vf, const u16* __restrict__ T,
                 const int* __restrict__ mask,
                 float* __restrict__ attnOut, u16* __restrict__ attH)
{
    __shared__ float Pw[8][16*68 + 16];   // 8 wave-private strips (also O-reduce alias)
    __shared__ float redB[8][16];

    const int t    = threadIdx.x;
    const int lane = t & 63, wave = t >> 6;     // 8 waves
    const int l15  = lane & 15, l4 = lane >> 4;

    // T-reuse swizzle: bid = xcd + 8*(p3 + 8*q6); b = xcd>>1, h = ((xcd&1)<<3)+p3
    const int bid  = blockIdx.x;
    const int xcd  = bid & 7;
    const int idx0 = bid >> 3;
    const int p3   = idx0 & 7;
    const int q6   = idx0 >> 3;        // 0..63
    const int q0   = q6 * 16;
    const int b    = xcd >> 1;
    const int h    = ((xcd & 1) << 3) + p3;

    float* myP = Pw[wave];

    int mrow[4];
    #pragma unroll
    for (int r = 0; r < 4; ++r) mrow[r] = mask[b*SS + q0 + l4*4 + r];

    const u16* Qp = Qb + ((size_t)(b*SS + q0 + l15))*DD + h*HDD + l4*8;
    bf16x8 qf0 = *(const bf16x8*)Qp;
    bf16x8 qf1 = *(const bf16x8*)(Qp + 32);

    // ---- QK^T: wave's keys w*128 + tt*16 + l15, fragments straight from Kf ----
    f32x4 sacc[8];
    #pragma unroll
    for (int tt = 0; tt < 8; ++tt) sacc[tt] = (f32x4){0.f,0.f,0.f,0.f};

    const u16* Kbase = Kf + (((size_t)(b*16 + h))*64 + wave*8)*1024 + l4*128 + l15*8;
    #pragma unroll
    for (int tt = 0; tt < 8; ++tt) {
        bf16x8 kf0 = *(const bf16x8*)(Kbase + tt*1024);
        bf16x8 kf1 = *(const bf16x8*)(Kbase + tt*1024 + 512);
        sacc[tt] = mfma16(qf0, kf0, sacc[tt]);
        sacc[tt] = mfma16(qf1, kf1, sacc[tt]);
    }

    // ---- bias (fragment-major T) + mask + exp (no max-subtraction) + row-sum ----
    const u16* Tb = T + ((((size_t)b*64 + q6)*64 + wave*8)*64 + lane)*4;
    float sum[4] = {0.f, 0.f, 0.f, 0.f};
    #pragma unroll
    for (int tt = 0; tt < 8; ++tt) {
        ushort4 t4 = *(const ushort4*)(Tb + (size_t)tt*256);
        #pragma unroll
        for (int r = 0; r < 4; ++r) {
            const float bias = bf2f(((const u16*)&t4)[r]);
            const float s = sacc[tt][r]*0.125f + bias;
            const float p = mrow[r] ? __expf(s) : 1.0f;
            sacc[tt][r] = p;
            sum[r] += p;
        }
    }
    #pragma unroll
    for (int r = 0; r < 4; ++r)
        #pragma unroll
        for (int xm = 1; xm < 16; xm <<= 1) sum[r] += __shfl_xor(sum[r], xm);
    if (l15 == 0) {
        #pragma unroll
        for (int r = 0; r < 4; ++r) redB[wave][l4*4 + r] = sum[r];
    }
    __syncthreads();                                   // barrier 1 (sum merge)

    float inv4[4];                                     // PV rows (l4*4+r)
    #pragma unroll
    for (int r = 0; r < 4; ++r) {
        const int row = l4*4 + r;
        float s8 = 0.f;
        #pragma unroll
        for (int w = 0; w < 8; ++w) s8 += redB[w][row];
        inv4[r] = 1.f / s8;
    }
    float wiv4[4];                                     // write rows (it*4 + l4)
    #pragma unroll
    for (int it = 0; it < 4; ++it) {
        const int row = it*4 + l4;
        float s8 = 0.f;
        #pragma unroll
        for (int w = 0; w < 8; ++w) s8 += redB[w][row];
        wiv4[it] = 1.f / s8;
    }

    float* gBase = attnOut + (((size_t)(b*HH + h))*SS + q0)*SS + wave*128;
    f32x4 pv[4];
    #pragma unroll
    for (int nt = 0; nt < 4; ++nt) pv[nt] = (f32x4){0.f,0.f,0.f,0.f};

    // ---- two wave-private halves: store P -> nt-write attn -> PV, no s_barrier ----
    #pragma unroll
    for (int half = 0; half < 2; ++half) {
        #pragma unroll
        for (int t2 = 0; t2 < 4; ++t2)
            #pragma unroll
            for (int r = 0; r < 4; ++r)
                myP[(l4*4 + r)*68 + t2*16 + l15] = sacc[half*4 + t2][r];
        lds_fence();

        #pragma unroll
        for (int it = 0; it < 4; ++it) {
            const int row = it*4 + l4;
            f32x4 v = *(f32x4*)&myP[row*68 + l15*4];
            v *= wiv4[it];
            nt_store4(&gBase[(size_t)row*SS + half*64 + l15*4], v);
        }

        #pragma unroll
        for (int kg = 0; kg < 2; ++kg) {
            const int c0 = kg*32 + l4*8;
            f32x4 a0 = *(f32x4*)&myP[l15*68 + c0];
            f32x4 a1 = *(f32x4*)&myP[l15*68 + c0 + 4];
            bf16x8 af;
            af[0] = (__bf16)a0[0]; af[1] = (__bf16)a0[1]; af[2] = (__bf16)a0[2]; af[3] = (__bf16)a0[3];
            af[4] = (__bf16)a1[0]; af[5] = (__bf16)a1[1]; af[6] = (__bf16)a1[2]; af[7] = (__bf16)a1[3];
            const int kc = wave*4 + half*2 + kg;
            const u16* Vp = Vf + (((size_t)(b*16 + h))*32 + kc)*2048 + l4*128 + l15*8;
            #pragma unroll
            for (int nt = 0; nt < 4; ++nt) {
                bf16x8 bf = *(const bf16x8*)(Vp + nt*512);
                pv[nt] = mfma16(af, bf, pv[nt]);
            }
        }
        lds_fence();
    }

    // ---- cross-wave O reduce (alias own strip, flat 1024 floats) ----
    #pragma unroll
    for (int nt = 0; nt < 4; ++nt)
        #pragma unroll
        for (int r = 0; r < 4; ++r)
            myP[(l4*4 + r)*64 + nt*16 + l15] = pv[nt][r] * inv4[r];
    __syncthreads();                                   // barrier 2 (O reduce)

    {
        const int q = t >> 5, d0 = (t & 31)*2;
        float sx = 0.f, sy = 0.f;
        #pragma unroll
        for (int w = 0; w < 8; ++w) {
            float2 v = *(float2*)&Pw[w][q*64 + d0];
            sx += v.x; sy += v.y;
        }
        const size_t off = ((size_t)(b*SS + q0 + q))*DD + h*HDD + d0;
        ushort2 hh = {f2bf(sx), f2bf(sy)};
        *(ushort2*)&attH[off] = hh;
    }
}

extern "C" void kernel_launch(void* const* d_in, const int* in_sizes, int n_in,
                              void* d_out, int out_size, void* d_ws, size_t ws_size,
                              hipStream_t stream) {
    const float* x     = (const float*)d_in[0];
    const float* trust = (const float*)d_in[1];
    const int*   mask  = (const int*)  d_in[2];
    const float* Wq    = (const float*)d_in[3];
    const float* bq    = (const float*)d_in[4];
    const float* Wk    = (const float*)d_in[5];
    const float* bk    = (const float*)d_in[6];
    const float* Wv    = (const float*)d_in[7];
    const float* bv    = (const float*)d_in[8];
    const float* Wtp   = (const float*)d_in[9];
    const float* btp   = (const float*)d_in[10];
    const float* Wg    = (const float*)d_in[11];
    const float* bg    = (const float*)d_in[12];
    const float* Wo    = (const float*)d_in[13];
    const float* bo    = (const float*)d_in[14];

    float* out     = (float*)d_out;
    float* attnOut = out + (size_t)MTOT * DD;

    char* ws = (char*)d_ws;
    u16* xh   = (u16*)(ws + (size_t)0*MB);    // 8 MB -> attH later
    u16* WqTh = (u16*)(ws + (size_t)16*MB);
    u16* WkTh = (u16*)(ws + (size_t)18*MB);
    u16* WvTh = (u16*)(ws + (size_t)20*MB);
    u16* WgTh = (u16*)(ws + (size_t)22*MB);
    u16* WoTh = (u16*)(ws + (size_t)24*MB);
    u16* Qbf  = (u16*)(ws + (size_t)28*MB);   // 8 MB -> Gh later
    u16* Kfb  = (u16*)(ws + (size_t)36*MB);   // 8 MB fragment-major K
    u16* Vfb  = (u16*)(ws + (size_t)44*MB);   // 8 MB fragment-major V
    u16* Tb   = (u16*)(ws + (size_t)52*MB);   // 8 MB fragment-major trust-bias table
    u16* attH = xh;
    u16* Gh   = Qbf;

    const dim3 blk(256);

    // prep: 5 weight transposes + x split in one launch
    prep_kernel<<<dim3(16, 16, 6), blk, 0, stream>>>(
        Wq, WqTh, Wk, WkTh, Wv, WvTh, Wg, WgTh, Wo, WoTh, x, xh);
    // trust-bias table (rank-1 constants computed inline per wave)
    tbias_kernel<<<dim3(64, BB), blk, 0, stream>>>(trust, Wtp, btp, Tb);

    // fused Q+K+V: 1-pass, N=3072; Q row-major -> Qbf, K frag -> Kfb, V frag -> Vfb
    mgemm<7,1><<<dim3(3072/128, MTOT/128), blk, 0, stream>>>(
        xh, nullptr, WqTh, WkTh, bq, (float*)Vfb, Qbf, Kfb, MTOT, 3072,
        bk, bv, WvTh);

    attn_kernel<<<dim3(4096), dim3(512), 0, stream>>>(
        Qbf, Kfb, Vfb, Tb, mask, attnOut, attH);

    // gate: 1-pass; gated = bf16(attended) * sigmoid(attended@Wg[0:1024] + bg + trust*wlast)
    mgemm<1,1><<<dim3(DD/128, MTOT/128), blk, 0, stream>>>(
        attH, nullptr, WgTh, nullptr, bg, nullptr, Gh, nullptr, MTOT, DD,
        trust, Wg + (size_t)DD*DD, attH);
    // out = gated @ Wo + bo (fp32, 1-pass, nontemporal)
    mgemm<0,1><<<dim3(DD/128, MTOT/128), blk, 0, stream>>>(
        Gh, nullptr, WoTh, nullptr, bo, out, nullptr, nullptr, MTOT, DD,
        nullptr, nullptr, nullptr);
}